// Round 1
// baseline (446.281 us; speedup 1.0000x reference)
//
#include <hip/hip_runtime.h>
#include <math.h>

typedef __bf16 bf16x8 __attribute__((ext_vector_type(8)));
typedef __bf16 bf16x4 __attribute__((ext_vector_type(4)));
typedef float  f32x4  __attribute__((ext_vector_type(4)));

// N=2, Q=1600, K=100 (pad 112), C=256, h=8, d=32.
// bias: transposed MFMA GEMM, Qb=4/block, grid 800. attn: Qb=4/block.

// ---- workspace layout (float offsets), total 2,073,376 f32 = 8.29 MB ----
#define WS_KH    0u        // [200][256] f32 k projection                 -> 51200
#define WS_VH    51200u    // [200][256] f32 v projection                 -> 102400
#define WS_EWP   102400u   // [256][260] f32 embed_w padded rows          -> 168960
#define WS_QHB   168960u   // bf16 [3200][256] scaled q projection        -> 578560
#define WS_BIASB 578560u   // bf16 [3200][112][8] rel-pos bias            -> 2012160
#define WS_KEB   2012160u  // bf16 [200][264] key sin/cos table (pad 264) -> 2038560
#define WS_W1B   2038560u  // bf16 [256][256] pos_w1                      -> 2071328
#define WS_W2PB  2071328u  // bf16 [16][256] pos_w2 padded                -> 2073376

__device__ __forceinline__ float rdlane(float v, int l) {
  return __uint_as_float(__builtin_amdgcn_readlane(__float_as_uint(v), l));
}

__device__ __forceinline__ unsigned packbf(float a, float b) {
  unsigned short ua = __builtin_bit_cast(unsigned short, (__bf16)a);
  unsigned short ub = __builtin_bit_cast(unsigned short, (__bf16)b);
  return (unsigned)ua | ((unsigned)ub << 16);
}

// ---------------------------------------------------------------------------
// prep: keb table + bf16 casts + embed_w pad + q/k/v projections (fused)
__global__ __launch_bounds__(256, 2) void prep_kernel(
    const float* __restrict__ qfeat, const float* __restrict__ kfeat,
    const float* __restrict__ kpos,
    const float* __restrict__ ipw, const float* __restrict__ ipb,
    const float* __restrict__ pos_w1, const float* __restrict__ pos_w2,
    const float* __restrict__ embed_w, float* __restrict__ ws)
{
  __shared__ float x[8 * 256];
  int bid = blockIdx.x, t = threadIdx.x;

  if (bid < 50) {
    int r = bid * 4 + (t >> 6);
    int u = t & 63;
    float p0 = kpos[r * 2 + 0], p1 = kpos[r * 2 + 1];
    __bf16* keb = (__bf16*)(ws + WS_KEB);
    bf16x4 o;
#pragma unroll
    for (int j = 0; j < 4; j++) {
      int col = u * 4 + j;
      int c = col >> 7, i = (col & 127) >> 1;
      float p = c ? p1 : p0;
      float inv = exp2f((float)i * (-13.287712379549449f / 64.0f));
      float v = p * inv;
      o[j] = (__bf16)((col & 1) ? __cosf(v) : __sinf(v));
    }
    *(bf16x4*)(keb + r * 264 + u * 4) = o;
  } else if (bid < 114) {
    int idx = (bid - 50) * 1024 + t * 4;
    float4 v = *(const float4*)(pos_w1 + idx);
    bf16x4 o; o[0] = (__bf16)v.x; o[1] = (__bf16)v.y; o[2] = (__bf16)v.z; o[3] = (__bf16)v.w;
    *(bf16x4*)((__bf16*)(ws + WS_W1B) + idx) = o;
  } else if (bid == 114) {
    __bf16* w2pb = (__bf16*)(ws + WS_W2PB);
    for (int i = 0; i < 16; i++) {
      int idx = t * 16 + i;
      w2pb[idx] = (idx < 2048) ? (__bf16)pos_w2[idx] : (__bf16)0.0f;
    }
  } else if (bid < 147) {
    int r0 = (bid - 115) * 8;
    for (int rr = 0; rr < 8; rr++) {
      int r = r0 + rr;
      for (int j = t; j < 260; j += 256)
        ws[WS_EWP + r * 260 + j] = (j < 258) ? embed_w[r * 258 + j] : 0.0f;
    }
  } else if (bid < 547) {
    int r0 = (bid - 147) * 8;
    for (int i = t; i < 2048; i += 256) x[i] = qfeat[(unsigned)r0 * 256u + i];
    __syncthreads();
    float acc[8]; float bq = ipb[t];
#pragma unroll
    for (int rr = 0; rr < 8; rr++) acc[rr] = bq;
    const float* wrow = ipw + (unsigned)t * 256u;
    for (int j = 0; j < 256; j += 4) {
      float4 w4 = *(const float4*)(wrow + j);
#pragma unroll
      for (int rr = 0; rr < 8; rr++) {
        float4 x4 = *(const float4*)(x + rr * 256 + j);
        acc[rr] = fmaf(x4.x, w4.x, fmaf(x4.y, w4.y, fmaf(x4.z, w4.z, fmaf(x4.w, w4.w, acc[rr]))));
      }
    }
    __bf16* qhb = (__bf16*)(ws + WS_QHB);
#pragma unroll
    for (int rr = 0; rr < 8; rr++)
      qhb[(unsigned)(r0 + rr) * 256u + t] = (__bf16)(acc[rr] * 0.17677669529663687f);
  } else {
    int b2 = bid - 547; int n = b2 >> 4, tile = b2 & 15;
    int r0l = tile * 7; int cnt = 100 - r0l; if (cnt > 7) cnt = 7; if (cnt <= 0) return;
    int r0 = n * 100 + r0l;
    for (int i = t; i < cnt * 256; i += 256) x[i] = kfeat[(unsigned)r0 * 256u + i];
    __syncthreads();
    float ak[7], av[7]; float bk = ipb[256 + t], bv = ipb[512 + t];
#pragma unroll
    for (int rr = 0; rr < 7; rr++) { ak[rr] = bk; av[rr] = bv; }
    const float* wkr = ipw + (unsigned)(256 + t) * 256u;
    const float* wvr = ipw + (unsigned)(512 + t) * 256u;
    for (int j = 0; j < 256; j += 4) {
      float4 wk4 = *(const float4*)(wkr + j);
      float4 wv4 = *(const float4*)(wvr + j);
#pragma unroll
      for (int rr = 0; rr < 7; rr++) {
        float4 x4 = *(const float4*)(x + rr * 256 + j);
        ak[rr] = fmaf(x4.x, wk4.x, fmaf(x4.y, wk4.y, fmaf(x4.z, wk4.z, fmaf(x4.w, wk4.w, ak[rr]))));
        av[rr] = fmaf(x4.x, wv4.x, fmaf(x4.y, wv4.y, fmaf(x4.z, wv4.z, fmaf(x4.w, wv4.w, av[rr]))));
      }
    }
    for (int rr = 0; rr < 7; rr++) {
      if (rr < cnt) {
        ws[WS_KH + (unsigned)(r0 + rr) * 256u + t] = ak[rr];
        ws[WS_VH + (unsigned)(r0 + rr) * 256u + t] = av[rr];
      }
    }
  }
}

// ---------------------------------------------------------------------------
// bias kernel v5: per block = 4 queries, 512 threads (8 waves), grid 800.
// GEMM1: D1[c][key] = sum_k W1[c][k]*pe[key][k]; A=W1 frags streamed from L2
// (same addresses every q/block -> L2-hot), B=pe via LDS (XOR bank-swizzled).
// GEMM2: fully in-wave. Wave w owns c-chunk [32w,32w+32): quad-permute shfl
// reshapes acc into a 16x16x32 A-frag (rows=key), one MFMA per mt gives
// partial D2[key][h]; 8-way cross-wave sum via LDS atomicAdd into a 3.5KB
// buffer (double-buffered over q). Finalize+store folded into next q's p0.
// LDS: peA dbuf [2][896 frags]@0 (28672) + qe bf16[4][256]@28672 (2048)
//      + red f32[2][896] (7168) = 37888 B.  launch_bounds(512,4) pins regs
//      <=128 unified -> 2 blocks/CU (vs 1 before: wfrag's 64 VGPR + 56 AGPR
//      acc pushed total regs to ~160 -> 3 waves/SIMD -> occupancy 17%).
__global__ __launch_bounds__(512, 4) void bias_kernel(
    const float* __restrict__ qpos,
    const float* __restrict__ pos_b1, const float* __restrict__ pos_b2,
    float* __restrict__ ws)
{
  __shared__ __align__(16) char smem[30720];
  __shared__ float red_s[2][896];   // [2][7mt][16key][8h]
  __bf16* qe_s = (__bf16*)(smem + 28672);

  int bid = blockIdx.x;          // 0..799 -> q rows bid*4 .. bid*4+3
  int n = bid / 400;
  int q0 = bid * 4;
  int t = threadIdx.x;
  int lane = t & 63, w = t >> 6;
  int l15 = lane & 15, quad = lane >> 4;

  const __bf16* keb = (const __bf16*)(ws + WS_KEB) + (unsigned)(n * 100) * 264u;
  const __bf16* w1b = (const __bf16*)(ws + WS_W1B);
  const __bf16* w2pb = (const __bf16*)(ws + WS_W2PB);
  __bf16* biasb = (__bf16*)(ws + WS_BIASB);

  // zero the reduce buffers (first atomics are many barriers away)
  for (int i = t; i < 1792; i += 512) ((float*)red_s)[i] = 0.f;

  // qe for the block's 4 queries: thread computes one sin/cos pair
  {
    int idx = t * 2;
    int q = idx >> 8, u = idx & 255;
    int c = u >> 7, i = (u & 127) >> 1;
    float p = qpos[(q0 + q) * 2 + c];
    float inv = exp2f((float)i * (-13.287712379549449f / 64.0f));
    float v = p * inv;
    qe_s[idx]     = (__bf16)__sinf(v);
    qe_s[idx + 1] = (__bf16)__cosf(v);
  }

  // W2 B-frag (resident, 4 regs): W2[h=l15][c = w*32 + quad*8 + j]
  bf16x8 w2f = *(const bf16x8*)(w2pb + (unsigned)l15 * 256u + w * 32 + quad * 8);

  // pe generator: one kc-PAIR per call, XOR bank-swizzle on low 4 idx bits.
  auto gen = [&](int q, int pair, int buf) {
    if (t < 448) {
      int key = t >> 2, sub = t & 3;
      int cb = pair * 64 + sub * 16;
      bf16x8 fr0, fr1;
      const __bf16* qp = qe_s + q * 256 + cb;
      bf16x8 q0f = *(const bf16x8*)qp;
      bf16x8 q1f = *(const bf16x8*)(qp + 8);
      if (key < 100) {
        const __bf16* kp = keb + (unsigned)key * 264u + cb;
        bf16x8 k0f = *(const bf16x8*)kp;
        bf16x8 k1f = *(const bf16x8*)(kp + 8);
#pragma unroll
        for (int jj = 0; jj < 4; jj++) {
          float sk = (float)k0f[2 * jj], ck = (float)k0f[2 * jj + 1];
          float sq = (float)q0f[2 * jj], cq = (float)q0f[2 * jj + 1];
          fr0[2 * jj]     = (__bf16)(sk * cq - ck * sq);
          fr0[2 * jj + 1] = (__bf16)(ck * cq + sk * sq);
          float sk1 = (float)k1f[2 * jj], ck1 = (float)k1f[2 * jj + 1];
          float sq1 = (float)q1f[2 * jj], cq1 = (float)q1f[2 * jj + 1];
          fr1[2 * jj]     = (__bf16)(sk1 * cq1 - ck1 * sq1);
          fr1[2 * jj + 1] = (__bf16)(ck1 * cq1 + sk1 * sq1);
        }
      } else {
#pragma unroll
        for (int jj = 0; jj < 8; jj++) { fr0[jj] = (__bf16)0.f; fr1[jj] = (__bf16)0.f; }
      }
      int mt = key >> 4, kl = key & 15;
      int kcl = sub >> 1;
      int qd0 = (sub & 1) * 2;
      bf16x8* base = (bf16x8*)smem + buf * 896 + kcl * 448 + mt * 64;
      base[qd0 * 16 + (kl ^ (qd0 * 2 + kcl))]             = fr0;
      base[(qd0 + 1) * 16 + (kl ^ (qd0 * 2 + 2 + kcl))]   = fr1;
    }
  };

  f32x4 zero4; zero4[0] = 0.f; zero4[1] = 0.f; zero4[2] = 0.f; zero4[3] = 0.f;

  __syncthreads();           // qe_s ready
  gen(0, 0, 0);
  __syncthreads();

  for (int q = 0; q < 4; q++) {
    f32x4 acc[2][7];
#pragma unroll
    for (int ct = 0; ct < 2; ct++)
#pragma unroll
      for (int mt = 0; mt < 7; mt++) acc[ct][mt] = zero4;

    for (int p = 0; p < 4; p++) {
      // W1 A-frags for this kc pair, streamed from L2 (hot: shared by all
      // blocks & re-read each q). Issued early; gen covers the latency.
      bf16x8 wf[2][2];   // [kh][ct]
#pragma unroll
      for (int ct = 0; ct < 2; ct++) {
        const __bf16* wr = w1b + (unsigned)(w * 32 + ct * 16 + l15) * 256u + p * 64 + quad * 8;
        wf[0][ct] = *(const bf16x8*)wr;
        wf[1][ct] = *(const bf16x8*)(wr + 32);
      }

      if (p < 3) gen(q, p + 1, (p + 1) & 1);
      else if (q < 3) gen(q + 1, 0, 0);

      if (p == 0 && q > 0) {
        // finalize q-1: read reduce buffer, add b2, store bias, re-zero.
        int pb_ = (q - 1) & 1;
        for (int i2 = t; i2 < 896; i2 += 512) {
          int key = i2 >> 3, h = i2 & 7;
          float v = red_s[pb_][i2] + pos_b2[h];
          biasb[((unsigned)(q0 + q - 1) * 112u + key) * 8u + h] = (__bf16)v;
          red_s[pb_][i2] = 0.f;
        }
      }

      const bf16x8* pbuf = (const bf16x8*)smem + (p & 1) * 896;
#pragma unroll
      for (int kh = 0; kh < 2; kh++) {
#pragma unroll
        for (int mt = 0; mt < 7; mt++) {
          bf16x8 pf = pbuf[kh * 448 + mt * 64 + quad * 16 + (l15 ^ (quad * 2 + kh))];
          acc[0][mt] = __builtin_amdgcn_mfma_f32_16x16x32_bf16(wf[kh][0], pf, acc[0][mt], 0, 0, 0);
          acc[1][mt] = __builtin_amdgcn_mfma_f32_16x16x32_bf16(wf[kh][1], pf, acc[1][mt], 0, 0, 0);
        }
      }
      __syncthreads();
    }

    // hid = relu(D1 + b1) in regs (lane: c=32w+ct*16+quad*4+r, key=mt*16+l15)
    {
      float b1a[2][4];
#pragma unroll
      for (int ct = 0; ct < 2; ct++)
#pragma unroll
        for (int r = 0; r < 4; r++) b1a[ct][r] = pos_b1[w * 32 + ct * 16 + quad * 4 + r];
#pragma unroll
      for (int ct = 0; ct < 2; ct++)
#pragma unroll
        for (int mt = 0; mt < 7; mt++)
#pragma unroll
          for (int r = 0; r < 4; r++)
            acc[ct][mt][r] = fmaxf(acc[ct][mt][r] + b1a[ct][r], 0.0f);
    }

    // GEMM2 in-wave: reshape acc -> A-frag (rows=key, k=c-local) via quad
    // permutation, one MFMA per mt, 8-way cross-wave sum via LDS atomics.
    {
      int qa = (quad & 1) * 2;
      int s0 = qa * 16 + l15, s1 = s0 + 16;
      bool hi = (quad >= 2);      // target ct = quad>>1
      int rb = q & 1;
#pragma unroll
      for (int mt = 0; mt < 7; mt++) {
        unsigned a0 = packbf(acc[0][mt][0], acc[0][mt][1]);
        unsigned a1 = packbf(acc[0][mt][2], acc[0][mt][3]);
        unsigned b0 = packbf(acc[1][mt][0], acc[1][mt][1]);
        unsigned b1_ = packbf(acc[1][mt][2], acc[1][mt][3]);
        unsigned w0a = __shfl(a0, s0), w1a = __shfl(a1, s0);
        unsigned w2a = __shfl(a0, s1), w3a = __shfl(a1, s1);
        unsigned w0b = __shfl(b0, s0), w1b_ = __shfl(b1_, s0);
        unsigned w2b = __shfl(b0, s1), w3b = __shfl(b1_, s1);
        union { unsigned u[4]; bf16x8 v; } fb;
        fb.u[0] = hi ? w0b : w0a;
        fb.u[1] = hi ? w1b_ : w1a;
        fb.u[2] = hi ? w2b : w2a;
        fb.u[3] = hi ? w3b : w3a;
        f32x4 d2 = __builtin_amdgcn_mfma_f32_16x16x32_bf16(fb.v, w2f, zero4, 0, 0, 0);
        if (l15 < 8) {
#pragma unroll
          for (int r = 0; r < 4; r++)
            atomicAdd(&red_s[rb][(mt * 16 + quad * 4 + r) * 8 + l15], d2[r]);
        }
      }
    }
    __syncthreads();   // atomics visible; next q's p0 finalizes this buffer
  }

  // finalize q=3
  for (int i2 = t; i2 < 896; i2 += 512) {
    int key = i2 >> 3, h = i2 & 7;
    float v = red_s[1][i2] + pos_b2[h];
    biasb[((unsigned)(q0 + 3) * 112u + key) * 8u + h] = (__bf16)v;
  }
}

// ---------------------------------------------------------------------------
// attn kernel: per block = 4 queries. scores -> softmax -> ctx/aw -> out_proj
// -> cat_pos -> embed. 256 threads.
__global__ __launch_bounds__(256, 4) void attn_kernel(
    const float* __restrict__ qfeat, const float* __restrict__ qpos,
    const float* __restrict__ kpos,
    const float* __restrict__ out_w, const float* __restrict__ out_b,
    const float* __restrict__ embed_b, const float* __restrict__ ptw,
    const float* __restrict__ ws, float* __restrict__ out)
{
  __shared__ float qh_s[4 * 8 * 36];
  __shared__ float attn_s[4 * 8 * 116];
  __shared__ float ctx_s[4 * 264];
  __shared__ float cat_s[4 * 264];
  __shared__ float aw_s[4 * 104];

  int bid = blockIdx.x;
  int qg0 = bid * 4;
  int n = bid / 400;
  int t = threadIdx.x;

  const __bf16* qhb = (const __bf16*)(ws + WS_QHB);
  const __bf16* biasb = (const __bf16*)(ws + WS_BIASB);
  const float* kh = ws + WS_KH;
  const float* vh = ws + WS_VH;
  const float* ewp = ws + WS_EWP;

  for (int i = t; i < 1024; i += 256) {
    int q = i >> 8, c = i & 255;
    qh_s[(q * 8 + (c >> 5)) * 36 + (c & 31)] = (float)qhb[(unsigned)(qg0 + q) * 256u + c];
  }
  __syncthreads();

  for (int i = 0; i < 4; i++) {
    int p = t + i * 256;
    if (p < 800) {
      int k = p >> 3, h = p & 7;
      const float4* kf = (const float4*)(kh + (unsigned)(n * 100 + k) * 256u + h * 32);
      float4 kv[8];
#pragma unroll
      for (int dd = 0; dd < 8; dd++) kv[dd] = kf[dd];
#pragma unroll
      for (int q = 0; q < 4; q++) {
        const float4* qf = (const float4*)(qh_s + (q * 8 + h) * 36);
        float s = (float)biasb[((unsigned)(qg0 + q) * 112u + k) * 8u + h];
#pragma unroll
        for (int dd = 0; dd < 8; dd++) {
          float4 qv = qf[dd];
          s += kv[dd].x * qv.x + kv[dd].y * qv.y + kv[dd].z * qv.z + kv[dd].w * qv.w;
        }
        attn_s[(q * 8 + h) * 116 + k] = s;
      }
    }
  }
  __syncthreads();

  {
    int q = t >> 6, h = (t >> 3) & 7, j = t & 7;
    float* row = attn_s + (q * 8 + h) * 116;
    float mx = -1e30f;
    for (int k = j; k < 100; k += 8) mx = fmaxf(mx, row[k]);
    mx = fmaxf(mx, __shfl_xor(mx, 1, 8));
    mx = fmaxf(mx, __shfl_xor(mx, 2, 8));
    mx = fmaxf(mx, __shfl_xor(mx, 4, 8));
    float sum = 0.f;
    for (int k = j; k < 100; k += 8) { float e = __expf(row[k] - mx); row[k] = e; sum += e; }
    sum += __shfl_xor(sum, 1, 8);
    sum += __shfl_xor(sum, 2, 8);
    sum += __shfl_xor(sum, 4, 8);
    float inv = 1.0f / sum;
    for (int k = j; k < 100; k += 8) row[k] *= inv;
  }
  __syncthreads();

  for (int p = t; p < 416; p += 256) {
    int q = p / 104, k = p % 104;
    if (k < 100) {
      float s = 0.f;
#pragma unroll
      for (int h = 0; h < 8; h++) s += attn_s[(q * 8 + h) * 116 + k];
      aw_s[q * 104 + k] = s * 0.125f;
    }
  }
  {
    int c = t, h = c >> 5;
    float a0 = 0.f, a1 = 0.f, a2 = 0.f, a3 = 0.f;
    const float* vp = vh + (unsigned)(n * 100) * 256u + c;
    const float* r0 = attn_s + (0 * 8 + h) * 116;
    const float* r1 = attn_s + (1 * 8 + h) * 116;
    const float* r2 = attn_s + (2 * 8 + h) * 116;
    const float* r3 = attn_s + (3 * 8 + h) * 116;
#pragma unroll 4
    for (int k = 0; k < 100; k++) {
      float vv = vp[(unsigned)k * 256u];
      a0 = fmaf(r0[k], vv, a0);
      a1 = fmaf(r1[k], vv, a1);
      a2 = fmaf(r2[k], vv, a2);
      a3 = fmaf(r3[k], vv, a3);
    }
    ctx_s[0 * 264 + c] = a0; ctx_s[1 * 264 + c] = a1;
    ctx_s[2 * 264 + c] = a2; ctx_s[3 * 264 + c] = a3;
  }
  __syncthreads();

  if (t < 8) {
    int q = t >> 1, cd = t & 1;
    float qp = qpos[(qg0 + q) * 2 + cd];
    float s = 0.f;
    for (int k = 0; k < 100; k++)
      s = fmaf(aw_s[q * 104 + k], kpos[(n * 100 + k) * 2 + cd] - qp, s);
    float so = __shfl_xor(s, 1, 2);
    if (cd == 0) cat_s[q * 264 + 256] = ptw[0] * s + ptw[1] * so;
    else         cat_s[q * 264 + 257] = ptw[2] * so + ptw[3] * s;
  }

  {
    int c = t, lane = t & 63;
    float ob = out_b[c];
    float acc0 = ob, acc1 = ob, acc2 = ob, acc3 = ob;
    const float* wr = out_w + (unsigned)c * 256u;
    for (int ch = 0; ch < 4; ch++) {
      float v0 = ctx_s[0 * 264 + ch * 64 + lane];
      float v1 = ctx_s[1 * 264 + ch * 64 + lane];
      float v2 = ctx_s[2 * 264 + ch * 64 + lane];
      float v3 = ctx_s[3 * 264 + ch * 64 + lane];
      const float* wp = wr + ch * 64;
#pragma unroll 4
      for (int j4 = 0; j4 < 16; j4++) {
        float4 w4 = *(const float4*)(wp + j4 * 4);
        int jb = j4 * 4;
        acc0 = fmaf(rdlane(v0, jb + 0), w4.x, acc0);
        acc1 = fmaf(rdlane(v1, jb + 0), w4.x, acc1);
        acc2 = fmaf(rdlane(v2, jb + 0), w4.x, acc2);
        acc3 = fmaf(rdlane(v3, jb + 0), w4.x, acc3);
        acc0 = fmaf(rdlane(v0, jb + 1), w4.y, acc0);
        acc1 = fmaf(rdlane(v1, jb + 1), w4.y, acc1);
        acc2 = fmaf(rdlane(v2, jb + 1), w4.y, acc2);
        acc3 = fmaf(rdlane(v3, jb + 1), w4.y, acc3);
        acc0 = fmaf(rdlane(v0, jb + 2), w4.z, acc0);
        acc1 = fmaf(rdlane(v1, jb + 2), w4.z, acc1);
        acc2 = fmaf(rdlane(v2, jb + 2), w4.z, acc2);
        acc3 = fmaf(rdlane(v3, jb + 2), w4.z, acc3);
        acc0 = fmaf(rdlane(v0, jb + 3), w4.w, acc0);
        acc1 = fmaf(rdlane(v1, jb + 3), w4.w, acc1);
        acc2 = fmaf(rdlane(v2, jb + 3), w4.w, acc2);
        acc3 = fmaf(rdlane(v3, jb + 3), w4.w, acc3);
      }
    }
    cat_s[0 * 264 + c] = fmaxf(qfeat[(unsigned)(qg0 + 0) * 256u + c] + acc0, 0.f);
    cat_s[1 * 264 + c] = fmaxf(qfeat[(unsigned)(qg0 + 1) * 256u + c] + acc1, 0.f);
    cat_s[2 * 264 + c] = fmaxf(qfeat[(unsigned)(qg0 + 2) * 256u + c] + acc2, 0.f);
    cat_s[3 * 264 + c] = fmaxf(qfeat[(unsigned)(qg0 + 3) * 256u + c] + acc3, 0.f);
  }
  __syncthreads();

  {
    int c = t, lane = t & 63;
    float eb = embed_b[c];
    float acc0 = eb, acc1 = eb, acc2 = eb, acc3 = eb;
    const float* er = ewp + (unsigned)c * 260u;
    for (int ch = 0; ch < 4; ch++) {
      float v0 = cat_s[0 * 264 + ch * 64 + lane];
      float v1 = cat_s[1 * 264 + ch * 64 + lane];
      float v2 = cat_s[2 * 264 + ch * 64 + lane];
      float v3 = cat_s[3 * 264 + ch * 64 + lane];
      const float* wp = er + ch * 64;
#pragma unroll 4
      for (int j4 = 0; j4 < 16; j4++) {
        float4 w4 = *(const float4*)(wp + j4 * 4);
        int jb = j4 * 4;
        acc0 = fmaf(rdlane(v0, jb + 0), w4.x, acc0);
        acc1 = fmaf(rdlane(v1, jb + 0), w4.x, acc1);
        acc2 = fmaf(rdlane(v2, jb + 0), w4.x, acc2);
        acc3 = fmaf(rdlane(v3, jb + 0), w4.x, acc3);
        acc0 = fmaf(rdlane(v0, jb + 1), w4.y, acc0);
        acc1 = fmaf(rdlane(v1, jb + 1), w4.y, acc1);
        acc2 = fmaf(rdlane(v2, jb + 1), w4.y, acc2);
        acc3 = fmaf(rdlane(v3, jb + 1), w4.y, acc3);
        acc0 = fmaf(rdlane(v0, jb + 2), w4.z, acc0);
        acc1 = fmaf(rdlane(v1, jb + 2), w4.z, acc1);
        acc2 = fmaf(rdlane(v2, jb + 2), w4.z, acc2);
        acc3 = fmaf(rdlane(v3, jb + 2), w4.z, acc3);
        acc0 = fmaf(rdlane(v0, jb + 3), w4.w, acc0);
        acc1 = fmaf(rdlane(v1, jb + 3), w4.w, acc1);
        acc2 = fmaf(rdlane(v2, jb + 3), w4.w, acc2);
        acc3 = fmaf(rdlane(v3, jb + 3), w4.w, acc3);
      }
    }
    float4 wt = *(const float4*)(er + 256);
    acc0 += cat_s[0 * 264 + 256] * wt.x + cat_s[0 * 264 + 257] * wt.y;
    acc1 += cat_s[1 * 264 + 256] * wt.x + cat_s[1 * 264 + 257] * wt.y;
    acc2 += cat_s[2 * 264 + 256] * wt.x + cat_s[2 * 264 + 257] * wt.y;
    acc3 += cat_s[3 * 264 + 256] * wt.x + cat_s[3 * 264 + 257] * wt.y;
    out[(unsigned)(qg0 + 0) * 256u + c] = fmaxf(acc0, 0.f);
    out[(unsigned)(qg0 + 1) * 256u + c] = fmaxf(acc1, 0.f);
    out[(unsigned)(qg0 + 2) * 256u + c] = fmaxf(acc2, 0.f);
    out[(unsigned)(qg0 + 3) * 256u + c] = fmaxf(acc3, 0.f);
  }
}

// ---------------------------------------------------------------------------
extern "C" void kernel_launch(void* const* d_in, const int* in_sizes, int n_in,
                              void* d_out, int out_size, void* d_ws, size_t ws_size,
                              hipStream_t stream)
{
  const float* query_feature  = (const float*)d_in[0];
  const float* query_position = (const float*)d_in[1];
  const float* key_feature    = (const float*)d_in[2];
  const float* key_position   = (const float*)d_in[3];
  const float* in_proj_w      = (const float*)d_in[4];
  const float* in_proj_b      = (const float*)d_in[5];
  const float* out_proj_w     = (const float*)d_in[6];
  const float* out_proj_b     = (const float*)d_in[7];
  const float* pos_w1         = (const float*)d_in[8];
  const float* pos_b1         = (const float*)d_in[9];
  const float* pos_w2         = (const float*)d_in[10];
  const float* pos_b2         = (const float*)d_in[11];
  const float* pos_trans_w    = (const float*)d_in[12];
  const float* embed_w        = (const float*)d_in[13];
  const float* embed_b        = (const float*)d_in[14];
  float* ws  = (float*)d_ws;
  float* out = (float*)d_out;

  hipLaunchKernelGGL(prep_kernel, dim3(579), dim3(256), 0, stream,
                     query_feature, key_feature, key_position,
                     in_proj_w, in_proj_b, pos_w1, pos_w2, embed_w, ws);
  hipLaunchKernelGGL(bias_kernel, dim3(800), dim3(512), 0, stream,
                     query_position, pos_b1, pos_b2, ws);
  hipLaunchKernelGGL(attn_kernel, dim3(800), dim3(256), 0, stream,
                     query_feature, query_position, key_position,
                     out_proj_w, out_proj_b, embed_b, pos_trans_w,
                     ws, out);
}

// Round 3
// 337.232 us; speedup vs baseline: 1.3234x; 1.3234x over previous
//
#include <hip/hip_runtime.h>
#include <math.h>

typedef __bf16 bf16x8 __attribute__((ext_vector_type(8)));
typedef __bf16 bf16x4 __attribute__((ext_vector_type(4)));
typedef float  f32x4  __attribute__((ext_vector_type(4)));

// N=2, Q=1600, K=100 (pad 112), C=256, h=8, d=32.

// ---- workspace layout (float offsets), total 2,073,376 f32 = 8.29 MB ----
#define WS_KH    0u        // [200][256] f32 k projection                 -> 51200
#define WS_VH    51200u    // [200][256] f32 v projection                 -> 102400
#define WS_EWP   102400u   // [256][260] f32 embed_w padded rows          -> 168960
#define WS_QHB   168960u   // bf16 [3200][256] scaled q projection        -> 578560
#define WS_BIASB 578560u   // bf16 [3200][112][8] rel-pos bias            -> 2012160
#define WS_KEB   2012160u  // bf16 [200][264] key sin/cos table (pad 264) -> 2038560
#define WS_W1B   2038560u  // bf16 [256][256] pos_w1                      -> 2071328
#define WS_W2PB  2071328u  // bf16 [16][256] pos_w2 padded                -> 2073376

__device__ __forceinline__ float rdlane(float v, int l) {
  return __uint_as_float(__builtin_amdgcn_readlane(__float_as_uint(v), l));
}

__device__ __forceinline__ unsigned packbf(float a, float b) {
  unsigned short ua = __builtin_bit_cast(unsigned short, (__bf16)a);
  unsigned short ub = __builtin_bit_cast(unsigned short, (__bf16)b);
  return (unsigned)ua | ((unsigned)ub << 16);
}

// ---------------------------------------------------------------------------
// prep: keb table + bf16 casts + embed_w pad + q/k/v projections (fused)
__global__ __launch_bounds__(256, 2) void prep_kernel(
    const float* __restrict__ qfeat, const float* __restrict__ kfeat,
    const float* __restrict__ kpos,
    const float* __restrict__ ipw, const float* __restrict__ ipb,
    const float* __restrict__ pos_w1, const float* __restrict__ pos_w2,
    const float* __restrict__ embed_w, float* __restrict__ ws)
{
  __shared__ float x[8 * 256];
  int bid = blockIdx.x, t = threadIdx.x;

  if (bid < 50) {
    int r = bid * 4 + (t >> 6);
    int u = t & 63;
    float p0 = kpos[r * 2 + 0], p1 = kpos[r * 2 + 1];
    __bf16* keb = (__bf16*)(ws + WS_KEB);
    bf16x4 o;
#pragma unroll
    for (int j = 0; j < 4; j++) {
      int col = u * 4 + j;
      int c = col >> 7, i = (col & 127) >> 1;
      float p = c ? p1 : p0;
      float inv = exp2f((float)i * (-13.287712379549449f / 64.0f));
      float v = p * inv;
      o[j] = (__bf16)((col & 1) ? __cosf(v) : __sinf(v));
    }
    *(bf16x4*)(keb + r * 264 + u * 4) = o;
  } else if (bid < 114) {
    int idx = (bid - 50) * 1024 + t * 4;
    float4 v = *(const float4*)(pos_w1 + idx);
    bf16x4 o; o[0] = (__bf16)v.x; o[1] = (__bf16)v.y; o[2] = (__bf16)v.z; o[3] = (__bf16)v.w;
    *(bf16x4*)((__bf16*)(ws + WS_W1B) + idx) = o;
  } else if (bid == 114) {
    __bf16* w2pb = (__bf16*)(ws + WS_W2PB);
    for (int i = 0; i < 16; i++) {
      int idx = t * 16 + i;
      w2pb[idx] = (idx < 2048) ? (__bf16)pos_w2[idx] : (__bf16)0.0f;
    }
  } else if (bid < 147) {
    int r0 = (bid - 115) * 8;
    for (int rr = 0; rr < 8; rr++) {
      int r = r0 + rr;
      for (int j = t; j < 260; j += 256)
        ws[WS_EWP + r * 260 + j] = (j < 258) ? embed_w[r * 258 + j] : 0.0f;
    }
  } else if (bid < 547) {
    int r0 = (bid - 147) * 8;
    for (int i = t; i < 2048; i += 256) x[i] = qfeat[(unsigned)r0 * 256u + i];
    __syncthreads();
    float acc[8]; float bq = ipb[t];
#pragma unroll
    for (int rr = 0; rr < 8; rr++) acc[rr] = bq;
    const float* wrow = ipw + (unsigned)t * 256u;
    for (int j = 0; j < 256; j += 4) {
      float4 w4 = *(const float4*)(wrow + j);
#pragma unroll
      for (int rr = 0; rr < 8; rr++) {
        float4 x4 = *(const float4*)(x + rr * 256 + j);
        acc[rr] = fmaf(x4.x, w4.x, fmaf(x4.y, w4.y, fmaf(x4.z, w4.z, fmaf(x4.w, w4.w, acc[rr]))));
      }
    }
    __bf16* qhb = (__bf16*)(ws + WS_QHB);
#pragma unroll
    for (int rr = 0; rr < 8; rr++)
      qhb[(unsigned)(r0 + rr) * 256u + t] = (__bf16)(acc[rr] * 0.17677669529663687f);
  } else {
    int b2 = bid - 547; int n = b2 >> 4, tile = b2 & 15;
    int r0l = tile * 7; int cnt = 100 - r0l; if (cnt > 7) cnt = 7; if (cnt <= 0) return;
    int r0 = n * 100 + r0l;
    for (int i = t; i < cnt * 256; i += 256) x[i] = kfeat[(unsigned)r0 * 256u + i];
    __syncthreads();
    float ak[7], av[7]; float bk = ipb[256 + t], bv = ipb[512 + t];
#pragma unroll
    for (int rr = 0; rr < 7; rr++) { ak[rr] = bk; av[rr] = bv; }
    const float* wkr = ipw + (unsigned)(256 + t) * 256u;
    const float* wvr = ipw + (unsigned)(512 + t) * 256u;
    for (int j = 0; j < 256; j += 4) {
      float4 wk4 = *(const float4*)(wkr + j);
      float4 wv4 = *(const float4*)(wvr + j);
#pragma unroll
      for (int rr = 0; rr < 7; rr++) {
        float4 x4 = *(const float4*)(x + rr * 256 + j);
        ak[rr] = fmaf(x4.x, wk4.x, fmaf(x4.y, wk4.y, fmaf(x4.z, wk4.z, fmaf(x4.w, wk4.w, ak[rr]))));
        av[rr] = fmaf(x4.x, wv4.x, fmaf(x4.y, wv4.y, fmaf(x4.z, wv4.z, fmaf(x4.w, wv4.w, av[rr]))));
      }
    }
    for (int rr = 0; rr < 7; rr++) {
      if (rr < cnt) {
        ws[WS_KH + (unsigned)(r0 + rr) * 256u + t] = ak[rr];
        ws[WS_VH + (unsigned)(r0 + rr) * 256u + t] = av[rr];
      }
    }
  }
}

// ---------------------------------------------------------------------------
// bias kernel v6: rotated-A formulation. D1[q] = A'_q @ keb^T where A'_q is
// W1 with the query rotation folded in (per sin/cos pair):
//   A'[c,2m]   =  W1[c,2m]*cq_m + W1[c,2m+1]*sq_m
//   A'[c,2m+1] =  W1[c,2m+1]*cq_m - W1[c,2m]*sq_m
// B (=keb) is STATIC across q -> staged once per block in LDS, XOR-swizzled
// (byte ^= (row&7)<<4) so the strided ds_read_b128 B-frag reads are
// conflict-free. No pe generation, no double-buffer, zero barriers in GEMM1.
// Block = 256 thr / 4 waves, Qb=4, grid 800. Wave w owns c-rows
// [64w,64w+64) = 4 ct tiles -> each keb read feeds 4 MFMAs (2x fewer LDS
// reads/query than the 2-ct layout). W1 A-frags streamed from L2 (q-invariant
// addresses, L2-hot) with 1-ahead prefetch; rotation -> af in regs.
// GEMM2 in-wave (shfl reshape, validated r1) over 2 c-chunks of 32,
// cross-wave sum via LDS atomicAdd into red_s (3.5KB), finalize per q.
// LDS: keb 57344 + qe 2048 + red 3584 = 62976 B. Regs ~215 < 256 (no spill;
// r1 lesson: launch_bounds(512,4) forced a 64/64 unified split -> scratch).
__global__ __launch_bounds__(256, 2) void bias_kernel(
    const float* __restrict__ qpos,
    const float* __restrict__ pos_b1, const float* __restrict__ pos_b2,
    float* __restrict__ ws)
{
  __shared__ __align__(16) char keb_smem[57344];   // [112 rows][512 B] swizzled
  __shared__ __align__(16) __bf16 qe_s[1024];      // [4 q][256]
  __shared__ float red_s[896];                     // [112 key][8 h]

  int bid = blockIdx.x;          // 0..799 -> q rows bid*4 .. bid*4+3
  int n = bid / 400;
  int q0 = bid * 4;
  int t = threadIdx.x;
  int lane = t & 63, w = t >> 6;
  int l15 = lane & 15, quad = lane >> 4;

  const __bf16* keb = (const __bf16*)(ws + WS_KEB) + (unsigned)(n * 100) * 264u;
  const __bf16* w1b = (const __bf16*)(ws + WS_W1B);
  const __bf16* w2pb = (const __bf16*)(ws + WS_W2PB);
  __bf16* biasb = (__bf16*)(ws + WS_BIASB);

  // zero reduce buffer
  for (int i = t; i < 896; i += 256) red_s[i] = 0.f;

  // qe for the block's 4 queries (layout: [q][coord*128 + 2m]=sin, +1=cos)
  for (int ii = t; ii < 512; ii += 256) {
    int idx = ii * 2;
    int q = idx >> 8, u = idx & 255;
    int c = u >> 7, i = (u & 127) >> 1;
    float p = qpos[(q0 + q) * 2 + c];
    float inv = exp2f((float)i * (-13.287712379549449f / 64.0f));
    float v = p * inv;
    qe_s[idx]     = (__bf16)__sinf(v);
    qe_s[idx + 1] = (__bf16)__cosf(v);
  }

  // stage keb into LDS, rows 100..111 zero, XOR bank-swizzle per 16B chunk
  for (int rr = t; rr < 448; rr += 256) {
    int r = rr >> 2, sub = rr & 3;
    char* dst = keb_smem + r * 512;
    int swz = (r & 7) << 4;
    if (r < 100) {
      const __bf16* src = keb + (unsigned)r * 264u + sub * 64;
#pragma unroll
      for (int u = 0; u < 8; u++) {
        bf16x8 v = *(const bf16x8*)(src + u * 8);
        int cb2 = sub * 128 + u * 16;
        *(bf16x8*)(dst + (cb2 ^ swz)) = v;
      }
    } else {
      bf16x8 z;
#pragma unroll
      for (int j = 0; j < 8; j++) z[j] = (__bf16)0.f;
#pragma unroll
      for (int u = 0; u < 8; u++) {
        int cb2 = sub * 128 + u * 16;
        *(bf16x8*)(dst + (cb2 ^ swz)) = z;
      }
    }
  }

  // resident small operands
  bf16x8 w2f[2];
#pragma unroll
  for (int ch = 0; ch < 2; ch++)
    w2f[ch] = *(const bf16x8*)(w2pb + (unsigned)l15 * 256u + w * 64 + ch * 32 + quad * 8);
  float b1a[4][4];
#pragma unroll
  for (int ct = 0; ct < 4; ct++)
#pragma unroll
    for (int r = 0; r < 4; r++) b1a[ct][r] = pos_b1[w * 64 + ct * 16 + quad * 4 + r];

  // per-lane constant addressing
  int xm = (l15 & 7) << 4;
  int colx[8];
#pragma unroll
  for (int kc = 0; kc < 8; kc++) colx[kc] = ((kc * 64 + quad * 16) ^ xm);
  const char* kbase = keb_smem + l15 * 512;                 // + mt*8192 + colx[kc]
  const __bf16* w1p = w1b + (unsigned)(w * 64 + l15) * 256u + quad * 8;

  f32x4 zero4; zero4[0] = 0.f; zero4[1] = 0.f; zero4[2] = 0.f; zero4[3] = 0.f;

  auto rot = [&](bf16x8 w8, bf16x8 qe8) {
    bf16x8 a;
#pragma unroll
    for (int t2 = 0; t2 < 4; t2++) {
      float we = (float)w8[2 * t2], wo = (float)w8[2 * t2 + 1];
      float sq = (float)qe8[2 * t2], cq = (float)qe8[2 * t2 + 1];
      a[2 * t2]     = (__bf16)fmaf(we, cq,  wo * sq);
      a[2 * t2 + 1] = (__bf16)fmaf(wo, cq, -we * sq);
    }
    return a;
  };

  __syncthreads();           // keb_smem + qe_s ready

  // W1 frags for kc=0 (carried across q; addresses are q-invariant)
  bf16x8 wc[4];
#pragma unroll
  for (int ct = 0; ct < 4; ct++) wc[ct] = *(const bf16x8*)(w1p + ct * 4096);

  for (int q = 0; q < 4; q++) {
    f32x4 acc[4][7];
#pragma unroll
    for (int ct = 0; ct < 4; ct++)
#pragma unroll
      for (int mt = 0; mt < 7; mt++) acc[ct][mt] = zero4;

    const __bf16* qrow = qe_s + q * 256 + quad * 8;

#pragma unroll
    for (int kc = 0; kc < 8; kc++) {
      // prefetch next kc's W1 frags (kc=7 prefetches kc=0 for the next q)
      bf16x8 wn[4];
      int kcn = (kc + 1) & 7;
#pragma unroll
      for (int ct = 0; ct < 4; ct++)
        wn[ct] = *(const bf16x8*)(w1p + ct * 4096 + kcn * 32);

      bf16x8 qe8 = *(const bf16x8*)(qrow + kc * 32);
      bf16x8 af0 = rot(wc[0], qe8);
      bf16x8 af1 = rot(wc[1], qe8);
      bf16x8 af2 = rot(wc[2], qe8);
      bf16x8 af3 = rot(wc[3], qe8);

#pragma unroll
      for (int mt = 0; mt < 7; mt++) {
        bf16x8 pf = *(const bf16x8*)(kbase + mt * 8192 + colx[kc]);
        acc[0][mt] = __builtin_amdgcn_mfma_f32_16x16x32_bf16(af0, pf, acc[0][mt], 0, 0, 0);
        acc[1][mt] = __builtin_amdgcn_mfma_f32_16x16x32_bf16(af1, pf, acc[1][mt], 0, 0, 0);
        acc[2][mt] = __builtin_amdgcn_mfma_f32_16x16x32_bf16(af2, pf, acc[2][mt], 0, 0, 0);
        acc[3][mt] = __builtin_amdgcn_mfma_f32_16x16x32_bf16(af3, pf, acc[3][mt], 0, 0, 0);
      }
#pragma unroll
      for (int ct = 0; ct < 4; ct++) wc[ct] = wn[ct];
    }

    // hid = relu(D1 + b1): lane holds c = 64w + ct*16 + quad*4 + r, key = mt*16 + l15
#pragma unroll
    for (int ct = 0; ct < 4; ct++)
#pragma unroll
      for (int mt = 0; mt < 7; mt++)
#pragma unroll
        for (int r = 0; r < 4; r++)
          acc[ct][mt][r] = fmaxf(acc[ct][mt][r] + b1a[ct][r], 0.0f);

    // GEMM2 in-wave: quad-permute reshape -> A-frag (rows=key, k=c-local),
    // 2 chunks of 32 c, accumulate; cross-wave sum via LDS atomics.
    {
      int qa = (quad & 1) * 2;
      int s0 = qa * 16 + l15, s1 = s0 + 16;
      bool hi = (quad >= 2);
#pragma unroll
      for (int mt = 0; mt < 7; mt++) {
        f32x4 d2 = zero4;
#pragma unroll
        for (int ch = 0; ch < 2; ch++) {
          unsigned a0 = packbf(acc[ch * 2][mt][0], acc[ch * 2][mt][1]);
          unsigned a1 = packbf(acc[ch * 2][mt][2], acc[ch * 2][mt][3]);
          unsigned b0 = packbf(acc[ch * 2 + 1][mt][0], acc[ch * 2 + 1][mt][1]);
          unsigned b1_ = packbf(acc[ch * 2 + 1][mt][2], acc[ch * 2 + 1][mt][3]);
          unsigned w0a = __shfl(a0, s0), w1a = __shfl(a1, s0);
          unsigned w2a = __shfl(a0, s1), w3a = __shfl(a1, s1);
          unsigned w0b = __shfl(b0, s0), w1b2 = __shfl(b1_, s0);
          unsigned w2b = __shfl(b0, s1), w3b = __shfl(b1_, s1);
          union { unsigned u[4]; bf16x8 v; } fb;
          fb.u[0] = hi ? w0b : w0a;
          fb.u[1] = hi ? w1b2 : w1a;
          fb.u[2] = hi ? w2b : w2a;
          fb.u[3] = hi ? w3b : w3a;
          d2 = __builtin_amdgcn_mfma_f32_16x16x32_bf16(fb.v, w2f[ch], d2, 0, 0, 0);
        }
        if (l15 < 8) {
#pragma unroll
          for (int r = 0; r < 4; r++)
            atomicAdd(&red_s[(mt * 16 + quad * 4 + r) * 8 + l15], d2[r]);
        }
      }
    }
    __syncthreads();   // all waves' atomics done

    // finalize: bias = red + b2 -> biasb (coalesced: i2 = key*8+h), rezero
    for (int i2 = t; i2 < 896; i2 += 256) {
      float v = red_s[i2] + pos_b2[i2 & 7];
      biasb[(unsigned)(q0 + q) * 896u + i2] = (__bf16)v;
      red_s[i2] = 0.f;
    }
    __syncthreads();   // rezero visible before next q's atomics
  }
}

// ---------------------------------------------------------------------------
// attn kernel: per block = 4 queries. scores -> softmax -> ctx/aw -> out_proj
// -> cat_pos -> embed. 256 threads.
__global__ __launch_bounds__(256, 4) void attn_kernel(
    const float* __restrict__ qfeat, const float* __restrict__ qpos,
    const float* __restrict__ kpos,
    const float* __restrict__ out_w, const float* __restrict__ out_b,
    const float* __restrict__ embed_b, const float* __restrict__ ptw,
    const float* __restrict__ ws, float* __restrict__ out)
{
  __shared__ float qh_s[4 * 8 * 36];
  __shared__ float attn_s[4 * 8 * 116];
  __shared__ float ctx_s[4 * 264];
  __shared__ float cat_s[4 * 264];
  __shared__ float aw_s[4 * 104];

  int bid = blockIdx.x;
  int qg0 = bid * 4;
  int n = bid / 400;
  int t = threadIdx.x;

  const __bf16* qhb = (const __bf16*)(ws + WS_QHB);
  const __bf16* biasb = (const __bf16*)(ws + WS_BIASB);
  const float* kh = ws + WS_KH;
  const float* vh = ws + WS_VH;
  const float* ewp = ws + WS_EWP;

  for (int i = t; i < 1024; i += 256) {
    int q = i >> 8, c = i & 255;
    qh_s[(q * 8 + (c >> 5)) * 36 + (c & 31)] = (float)qhb[(unsigned)(qg0 + q) * 256u + c];
  }
  __syncthreads();

  for (int i = 0; i < 4; i++) {
    int p = t + i * 256;
    if (p < 800) {
      int k = p >> 3, h = p & 7;
      const float4* kf = (const float4*)(kh + (unsigned)(n * 100 + k) * 256u + h * 32);
      float4 kv[8];
#pragma unroll
      for (int dd = 0; dd < 8; dd++) kv[dd] = kf[dd];
#pragma unroll
      for (int q = 0; q < 4; q++) {
        const float4* qf = (const float4*)(qh_s + (q * 8 + h) * 36);
        float s = (float)biasb[((unsigned)(qg0 + q) * 112u + k) * 8u + h];
#pragma unroll
        for (int dd = 0; dd < 8; dd++) {
          float4 qv = qf[dd];
          s += kv[dd].x * qv.x + kv[dd].y * qv.y + kv[dd].z * qv.z + kv[dd].w * qv.w;
        }
        attn_s[(q * 8 + h) * 116 + k] = s;
      }
    }
  }
  __syncthreads();

  {
    int q = t >> 6, h = (t >> 3) & 7, j = t & 7;
    float* row = attn_s + (q * 8 + h) * 116;
    float mx = -1e30f;
    for (int k = j; k < 100; k += 8) mx = fmaxf(mx, row[k]);
    mx = fmaxf(mx, __shfl_xor(mx, 1, 8));
    mx = fmaxf(mx, __shfl_xor(mx, 2, 8));
    mx = fmaxf(mx, __shfl_xor(mx, 4, 8));
    float sum = 0.f;
    for (int k = j; k < 100; k += 8) { float e = __expf(row[k] - mx); row[k] = e; sum += e; }
    sum += __shfl_xor(sum, 1, 8);
    sum += __shfl_xor(sum, 2, 8);
    sum += __shfl_xor(sum, 4, 8);
    float inv = 1.0f / sum;
    for (int k = j; k < 100; k += 8) row[k] *= inv;
  }
  __syncthreads();

  for (int p = t; p < 416; p += 256) {
    int q = p / 104, k = p % 104;
    if (k < 100) {
      float s = 0.f;
#pragma unroll
      for (int h = 0; h < 8; h++) s += attn_s[(q * 8 + h) * 116 + k];
      aw_s[q * 104 + k] = s * 0.125f;
    }
  }
  {
    int c = t, h = c >> 5;
    float a0 = 0.f, a1 = 0.f, a2 = 0.f, a3 = 0.f;
    const float* vp = vh + (unsigned)(n * 100) * 256u + c;
    const float* r0 = attn_s + (0 * 8 + h) * 116;
    const float* r1 = attn_s + (1 * 8 + h) * 116;
    const float* r2 = attn_s + (2 * 8 + h) * 116;
    const float* r3 = attn_s + (3 * 8 + h) * 116;
#pragma unroll 4
    for (int k = 0; k < 100; k++) {
      float vv = vp[(unsigned)k * 256u];
      a0 = fmaf(r0[k], vv, a0);
      a1 = fmaf(r1[k], vv, a1);
      a2 = fmaf(r2[k], vv, a2);
      a3 = fmaf(r3[k], vv, a3);
    }
    ctx_s[0 * 264 + c] = a0; ctx_s[1 * 264 + c] = a1;
    ctx_s[2 * 264 + c] = a2; ctx_s[3 * 264 + c] = a3;
  }
  __syncthreads();

  if (t < 8) {
    int q = t >> 1, cd = t & 1;
    float qp = qpos[(qg0 + q) * 2 + cd];
    float s = 0.f;
    for (int k = 0; k < 100; k++)
      s = fmaf(aw_s[q * 104 + k], kpos[(n * 100 + k) * 2 + cd] - qp, s);
    float so = __shfl_xor(s, 1, 2);
    if (cd == 0) cat_s[q * 264 + 256] = ptw[0] * s + ptw[1] * so;
    else         cat_s[q * 264 + 257] = ptw[2] * so + ptw[3] * s;
  }

  {
    int c = t, lane = t & 63;
    float ob = out_b[c];
    float acc0 = ob, acc1 = ob, acc2 = ob, acc3 = ob;
    const float* wr = out_w + (unsigned)c * 256u;
    for (int ch = 0; ch < 4; ch++) {
      float v0 = ctx_s[0 * 264 + ch * 64 + lane];
      float v1 = ctx_s[1 * 264 + ch * 64 + lane];
      float v2 = ctx_s[2 * 264 + ch * 64 + lane];
      float v3 = ctx_s[3 * 264 + ch * 64 + lane];
      const float* wp = wr + ch * 64;
#pragma unroll 4
      for (int j4 = 0; j4 < 16; j4++) {
        float4 w4 = *(const float4*)(wp + j4 * 4);
        int jb = j4 * 4;
        acc0 = fmaf(rdlane(v0, jb + 0), w4.x, acc0);
        acc1 = fmaf(rdlane(v1, jb + 0), w4.x, acc1);
        acc2 = fmaf(rdlane(v2, jb + 0), w4.x, acc2);
        acc3 = fmaf(rdlane(v3, jb + 0), w4.x, acc3);
        acc0 = fmaf(rdlane(v0, jb + 1), w4.y, acc0);
        acc1 = fmaf(rdlane(v1, jb + 1), w4.y, acc1);
        acc2 = fmaf(rdlane(v2, jb + 1), w4.y, acc2);
        acc3 = fmaf(rdlane(v3, jb + 1), w4.y, acc3);
        acc0 = fmaf(rdlane(v0, jb + 2), w4.z, acc0);
        acc1 = fmaf(rdlane(v1, jb + 2), w4.z, acc1);
        acc2 = fmaf(rdlane(v2, jb + 2), w4.z, acc2);
        acc3 = fmaf(rdlane(v3, jb + 2), w4.z, acc3);
        acc0 = fmaf(rdlane(v0, jb + 3), w4.w, acc0);
        acc1 = fmaf(rdlane(v1, jb + 3), w4.w, acc1);
        acc2 = fmaf(rdlane(v2, jb + 3), w4.w, acc2);
        acc3 = fmaf(rdlane(v3, jb + 3), w4.w, acc3);
      }
    }
    cat_s[0 * 264 + c] = fmaxf(qfeat[(unsigned)(qg0 + 0) * 256u + c] + acc0, 0.f);
    cat_s[1 * 264 + c] = fmaxf(qfeat[(unsigned)(qg0 + 1) * 256u + c] + acc1, 0.f);
    cat_s[2 * 264 + c] = fmaxf(qfeat[(unsigned)(qg0 + 2) * 256u + c] + acc2, 0.f);
    cat_s[3 * 264 + c] = fmaxf(qfeat[(unsigned)(qg0 + 3) * 256u + c] + acc3, 0.f);
  }
  __syncthreads();

  {
    int c = t, lane = t & 63;
    float eb = embed_b[c];
    float acc0 = eb, acc1 = eb, acc2 = eb, acc3 = eb;
    const float* er = ewp + (unsigned)c * 260u;
    for (int ch = 0; ch < 4; ch++) {
      float v0 = cat_s[0 * 264 + ch * 64 + lane];
      float v1 = cat_s[1 * 264 + ch * 64 + lane];
      float v2 = cat_s[2 * 264 + ch * 64 + lane];
      float v3 = cat_s[3 * 264 + ch * 64 + lane];
      const float* wp = er + ch * 64;
#pragma unroll 4
      for (int j4 = 0; j4 < 16; j4++) {
        float4 w4 = *(const float4*)(wp + j4 * 4);
        int jb = j4 * 4;
        acc0 = fmaf(rdlane(v0, jb + 0), w4.x, acc0);
        acc1 = fmaf(rdlane(v1, jb + 0), w4.x, acc1);
        acc2 = fmaf(rdlane(v2, jb + 0), w4.x, acc2);
        acc3 = fmaf(rdlane(v3, jb + 0), w4.x, acc3);
        acc0 = fmaf(rdlane(v0, jb + 1), w4.y, acc0);
        acc1 = fmaf(rdlane(v1, jb + 1), w4.y, acc1);
        acc2 = fmaf(rdlane(v2, jb + 1), w4.y, acc2);
        acc3 = fmaf(rdlane(v3, jb + 1), w4.y, acc3);
        acc0 = fmaf(rdlane(v0, jb + 2), w4.z, acc0);
        acc1 = fmaf(rdlane(v1, jb + 2), w4.z, acc1);
        acc2 = fmaf(rdlane(v2, jb + 2), w4.z, acc2);
        acc3 = fmaf(rdlane(v3, jb + 2), w4.z, acc3);
        acc0 = fmaf(rdlane(v0, jb + 3), w4.w, acc0);
        acc1 = fmaf(rdlane(v1, jb + 3), w4.w, acc1);
        acc2 = fmaf(rdlane(v2, jb + 3), w4.w, acc2);
        acc3 = fmaf(rdlane(v3, jb + 3), w4.w, acc3);
      }
    }
    float4 wt = *(const float4*)(er + 256);
    acc0 += cat_s[0 * 264 + 256] * wt.x + cat_s[0 * 264 + 257] * wt.y;
    acc1 += cat_s[1 * 264 + 256] * wt.x + cat_s[1 * 264 + 257] * wt.y;
    acc2 += cat_s[2 * 264 + 256] * wt.x + cat_s[2 * 264 + 257] * wt.y;
    acc3 += cat_s[3 * 264 + 256] * wt.x + cat_s[3 * 264 + 257] * wt.y;
    out[(unsigned)(qg0 + 0) * 256u + c] = fmaxf(acc0, 0.f);
    out[(unsigned)(qg0 + 1) * 256u + c] = fmaxf(acc1, 0.f);
    out[(unsigned)(qg0 + 2) * 256u + c] = fmaxf(acc2, 0.f);
    out[(unsigned)(qg0 + 3) * 256u + c] = fmaxf(acc3, 0.f);
  }
}

// ---------------------------------------------------------------------------
extern "C" void kernel_launch(void* const* d_in, const int* in_sizes, int n_in,
                              void* d_out, int out_size, void* d_ws, size_t ws_size,
                              hipStream_t stream)
{
  const float* query_feature  = (const float*)d_in[0];
  const float* query_position = (const float*)d_in[1];
  const float* key_feature    = (const float*)d_in[2];
  const float* key_position   = (const float*)d_in[3];
  const float* in_proj_w      = (const float*)d_in[4];
  const float* in_proj_b      = (const float*)d_in[5];
  const float* out_proj_w     = (const float*)d_in[6];
  const float* out_proj_b     = (const float*)d_in[7];
  const float* pos_w1         = (const float*)d_in[8];
  const float* pos_b1         = (const float*)d_in[9];
  const float* pos_w2         = (const float*)d_in[10];
  const float* pos_b2         = (const float*)d_in[11];
  const float* pos_trans_w    = (const float*)d_in[12];
  const float* embed_w        = (const float*)d_in[13];
  const float* embed_b        = (const float*)d_in[14];
  float* ws  = (float*)d_ws;
  float* out = (float*)d_out;

  hipLaunchKernelGGL(prep_kernel, dim3(579), dim3(256), 0, stream,
                     query_feature, key_feature, key_position,
                     in_proj_w, in_proj_b, pos_w1, pos_w2, embed_w, ws);
  hipLaunchKernelGGL(bias_kernel, dim3(800), dim3(256), 0, stream,
                     query_position, pos_b1, pos_b2, ws);
  hipLaunchKernelGGL(attn_kernel, dim3(800), dim3(256), 0, stream,
                     query_feature, query_position, key_position,
                     out_proj_w, out_proj_b, embed_b, pos_trans_w,
                     ws, out);
}

// Round 4
// 300.090 us; speedup vs baseline: 1.4872x; 1.1238x over previous
//
#include <hip/hip_runtime.h>
#include <math.h>

typedef __bf16 bf16x8 __attribute__((ext_vector_type(8)));
typedef __bf16 bf16x4 __attribute__((ext_vector_type(4)));
typedef float  f32x4  __attribute__((ext_vector_type(4)));

// N=2, Q=1600, K=100 (pad 112), C=256, h=8, d=32.

// ---- workspace layout (float offsets), total 2,482,976 f32 = 9.93 MB ----
#define WS_KH    0u        // [200][256] f32 k projection                 -> 51200
#define WS_VH    51200u    // [200][256] f32 v projection                 -> 102400
#define WS_EWP   102400u   // [256][260] f32 embed_w padded rows          -> 168960
#define WS_QHB   168960u   // bf16 [3200][256] scaled q projection        -> 578560
#define WS_BIASB 578560u   // bf16 [3200][112][8] rel-pos bias            -> 2012160
#define WS_KEB   2012160u  // bf16 [200][264] key sin/cos table (pad 264) -> 2038560
#define WS_W1B   2038560u  // bf16 [256][256] pos_w1                      -> 2071328
#define WS_W2PB  2071328u  // bf16 [16][256] pos_w2 padded                -> 2073376
#define WS_QEB   2073376u  // bf16 [3200][256] query sin/cos table        -> 2482976

__device__ __forceinline__ float rdlane(float v, int l) {
  return __uint_as_float(__builtin_amdgcn_readlane(__float_as_uint(v), l));
}

__device__ __forceinline__ unsigned packbf(float a, float b) {
  unsigned short ua = __builtin_bit_cast(unsigned short, (__bf16)a);
  unsigned short ub = __builtin_bit_cast(unsigned short, (__bf16)b);
  return (unsigned)ua | ((unsigned)ub << 16);
}

// ---------------------------------------------------------------------------
// prep: keb/qe tables + bf16 casts + embed_w pad + q/k/v projections (fused)
__global__ __launch_bounds__(256, 2) void prep_kernel(
    const float* __restrict__ qfeat, const float* __restrict__ kfeat,
    const float* __restrict__ kpos, const float* __restrict__ qpos,
    const float* __restrict__ ipw, const float* __restrict__ ipb,
    const float* __restrict__ pos_w1, const float* __restrict__ pos_w2,
    const float* __restrict__ embed_w, float* __restrict__ ws)
{
  __shared__ float x[8 * 256];
  int bid = blockIdx.x, t = threadIdx.x;

  if (bid < 50) {
    int r = bid * 4 + (t >> 6);
    int u = t & 63;
    float p0 = kpos[r * 2 + 0], p1 = kpos[r * 2 + 1];
    __bf16* keb = (__bf16*)(ws + WS_KEB);
    bf16x4 o;
#pragma unroll
    for (int j = 0; j < 4; j++) {
      int col = u * 4 + j;
      int c = col >> 7, i = (col & 127) >> 1;
      float p = c ? p1 : p0;
      float inv = exp2f((float)i * (-13.287712379549449f / 64.0f));
      float v = p * inv;
      o[j] = (__bf16)((col & 1) ? __cosf(v) : __sinf(v));
    }
    *(bf16x4*)(keb + r * 264 + u * 4) = o;
  } else if (bid < 114) {
    int idx = (bid - 50) * 1024 + t * 4;
    float4 v = *(const float4*)(pos_w1 + idx);
    bf16x4 o; o[0] = (__bf16)v.x; o[1] = (__bf16)v.y; o[2] = (__bf16)v.z; o[3] = (__bf16)v.w;
    *(bf16x4*)((__bf16*)(ws + WS_W1B) + idx) = o;
  } else if (bid == 114) {
    __bf16* w2pb = (__bf16*)(ws + WS_W2PB);
    for (int i = 0; i < 16; i++) {
      int idx = t * 16 + i;
      w2pb[idx] = (idx < 2048) ? (__bf16)pos_w2[idx] : (__bf16)0.0f;
    }
  } else if (bid < 147) {
    int r0 = (bid - 115) * 8;
    for (int rr = 0; rr < 8; rr++) {
      int r = r0 + rr;
      for (int j = t; j < 260; j += 256)
        ws[WS_EWP + r * 260 + j] = (j < 258) ? embed_w[r * 258 + j] : 0.0f;
    }
  } else if (bid < 547) {
    int r0 = (bid - 147) * 8;
    for (int i = t; i < 2048; i += 256) x[i] = qfeat[(unsigned)r0 * 256u + i];
    __syncthreads();
    float acc[8]; float bq = ipb[t];
#pragma unroll
    for (int rr = 0; rr < 8; rr++) acc[rr] = bq;
    const float* wrow = ipw + (unsigned)t * 256u;
    for (int j = 0; j < 256; j += 4) {
      float4 w4 = *(const float4*)(wrow + j);
#pragma unroll
      for (int rr = 0; rr < 8; rr++) {
        float4 x4 = *(const float4*)(x + rr * 256 + j);
        acc[rr] = fmaf(x4.x, w4.x, fmaf(x4.y, w4.y, fmaf(x4.z, w4.z, fmaf(x4.w, w4.w, acc[rr]))));
      }
    }
    __bf16* qhb = (__bf16*)(ws + WS_QHB);
#pragma unroll
    for (int rr = 0; rr < 8; rr++)
      qhb[(unsigned)(r0 + rr) * 256u + t] = (__bf16)(acc[rr] * 0.17677669529663687f);
  } else if (bid < 579) {
    int b2 = bid - 547; int n = b2 >> 4, tile = b2 & 15;
    int r0l = tile * 7; int cnt = 100 - r0l; if (cnt > 7) cnt = 7; if (cnt <= 0) return;
    int r0 = n * 100 + r0l;
    for (int i = t; i < cnt * 256; i += 256) x[i] = kfeat[(unsigned)r0 * 256u + i];
    __syncthreads();
    float ak[7], av[7]; float bk = ipb[256 + t], bv = ipb[512 + t];
#pragma unroll
    for (int rr = 0; rr < 7; rr++) { ak[rr] = bk; av[rr] = bv; }
    const float* wkr = ipw + (unsigned)(256 + t) * 256u;
    const float* wvr = ipw + (unsigned)(512 + t) * 256u;
    for (int j = 0; j < 256; j += 4) {
      float4 wk4 = *(const float4*)(wkr + j);
      float4 wv4 = *(const float4*)(wvr + j);
#pragma unroll
      for (int rr = 0; rr < 7; rr++) {
        float4 x4 = *(const float4*)(x + rr * 256 + j);
        ak[rr] = fmaf(x4.x, wk4.x, fmaf(x4.y, wk4.y, fmaf(x4.z, wk4.z, fmaf(x4.w, wk4.w, ak[rr]))));
        av[rr] = fmaf(x4.x, wv4.x, fmaf(x4.y, wv4.y, fmaf(x4.z, wv4.z, fmaf(x4.w, wv4.w, av[rr]))));
      }
    }
    for (int rr = 0; rr < 7; rr++) {
      if (rr < cnt) {
        ws[WS_KH + (unsigned)(r0 + rr) * 256u + t] = ak[rr];
        ws[WS_VH + (unsigned)(r0 + rr) * 256u + t] = av[rr];
      }
    }
  } else {
    // qe table: rows 0..3199, 4 rows per block (mirrors keb section)
    int r = (bid - 579) * 4 + (t >> 6);
    int u = t & 63;
    float p0 = qpos[r * 2 + 0], p1 = qpos[r * 2 + 1];
    __bf16* qeb = (__bf16*)(ws + WS_QEB);
    bf16x4 o;
#pragma unroll
    for (int j = 0; j < 4; j++) {
      int col = u * 4 + j;
      int c = col >> 7, i = (col & 127) >> 1;
      float p = c ? p1 : p0;
      float inv = exp2f((float)i * (-13.287712379549449f / 64.0f));
      float v = p * inv;
      o[j] = (__bf16)((col & 1) ? __cosf(v) : __sinf(v));
    }
    *(bf16x4*)(qeb + r * 256 + u * 4) = o;
  }
}

// ---------------------------------------------------------------------------
// bias kernel v7: KEY-side fold. hid[q,k,c] = sum_j PQ_k[c,j] * qe_q[j],
//   PQ_k[c,2m]   = W1[c,2m+1]*sk_m - W1[c,2m]*ck_m   (coeff of sin(aq))
//   PQ_k[c,2m+1] = W1[c,2m]*sk_m   + W1[c,2m+1]*ck_m (coeff of cos(aq))
// -> per (n,k): one clean GEMM [256c x 256j] @ [256j x 1600q]. Block = one
// (n,k) x 64-q tile, grid 5000, 256 thr / 4 waves. B (=qe tile, 32KB) staged
// once in LDS, XOR-swizzled (r3-validated pattern); A = W1 frags streamed
// from L2 with 1-ahead prefetch, rotated by the block's KEY angles in regs —
// rot cost amortizes over 64 queries (r3 paid it per query). Zero barriers
// in the k-loop. Epilogue: relu+b1 in regs -> hid bf16 into the SAME 32KB
// LDS buffer (qe dead after k-loop) -> GEMM2 [16x256]@[256x64] from LDS
// (8 MFMA/wave) -> bias + b2 store. No shfl reshape, no LDS atomics.
// LDS 33KB; regs ~105 VGPR + 64 acc ~ 170 unified -> 3 waves/SIMD.
__global__ __launch_bounds__(256, 2) void bias_kernel(
    const float* __restrict__ pos_b1, const float* __restrict__ pos_b2,
    float* __restrict__ ws)
{
  __shared__ __align__(16) char qe_smem[32768];   // [64 q][512B] swizzled; reused for hid
  __shared__ __align__(16) __bf16 keb_s[256];

  int bid = blockIdx.x;          // 0..4999 = (nk 0..199) x (qt 0..24)
  int nk = bid / 25;
  int qt = bid - nk * 25;
  int n  = nk / 100;
  int k  = nk - n * 100;
  int q0 = n * 1600 + qt * 64;   // first global q row of this tile
  int t = threadIdx.x;
  int lane = t & 63, w = t >> 6;
  int l15 = lane & 15, quad = lane >> 4;

  const __bf16* keb = (const __bf16*)(ws + WS_KEB) + (unsigned)nk * 264u;
  const __bf16* qeb = (const __bf16*)(ws + WS_QEB);
  const __bf16* w1b = (const __bf16*)(ws + WS_W1B);
  const __bf16* w2pb = (const __bf16*)(ws + WS_W2PB);
  __bf16* biasb = (__bf16*)(ws + WS_BIASB);

  // stage key sin/cos row (512B)
  if (t < 32) *(bf16x8*)(keb_s + t * 8) = *(const bf16x8*)(keb + t * 8);

  // stage qe tile [64 rows][512B], XOR swizzle byte ^= (row&7)<<4
  {
    int r = t >> 2, sub = t & 3;
    const __bf16* src = qeb + (unsigned)(q0 + r) * 256u + sub * 64;
    char* dst = qe_smem + r * 512;
    int swz = (r & 7) << 4;
#pragma unroll
    for (int u = 0; u < 8; u++) {
      bf16x8 v = *(const bf16x8*)(src + u * 8);
      int cb = sub * 128 + u * 16;
      *(bf16x8*)(dst + (cb ^ swz)) = v;
    }
  }

  // per-lane constant addressing (r3-validated swizzled read pattern)
  int xm = (l15 & 7) << 4;
  int colx[8];
#pragma unroll
  for (int kc = 0; kc < 8; kc++) colx[kc] = ((kc * 64 + quad * 16) ^ xm);
  const __bf16* w1p = w1b + (unsigned)(w * 64 + l15) * 256u + quad * 8;

  f32x4 zero4; zero4[0] = 0.f; zero4[1] = 0.f; zero4[2] = 0.f; zero4[3] = 0.f;

  // key-side rotation of a W1 A-frag
  auto rotk = [&](bf16x8 w8, bf16x8 ke) {
    bf16x8 a;
#pragma unroll
    for (int p2 = 0; p2 < 4; p2++) {
      float we = (float)w8[2 * p2], wo = (float)w8[2 * p2 + 1];
      float sk = (float)ke[2 * p2], ck = (float)ke[2 * p2 + 1];
      a[2 * p2]     = (__bf16)fmaf(wo, sk, -(we * ck));
      a[2 * p2 + 1] = (__bf16)fmaf(we, sk, wo * ck);
    }
    return a;
  };

  f32x4 acc[4][4];
#pragma unroll
  for (int ct = 0; ct < 4; ct++)
#pragma unroll
    for (int nt = 0; nt < 4; nt++) acc[ct][nt] = zero4;

  // W1 frags for kc=0
  bf16x8 wc[4];
#pragma unroll
  for (int ct = 0; ct < 4; ct++) wc[ct] = *(const bf16x8*)(w1p + ct * 4096);

  __syncthreads();   // qe_smem + keb_s ready

  // GEMM1 k-loop: barrier-free. Wave w owns c-rows [64w, 64w+64).
#pragma unroll
  for (int kc = 0; kc < 8; kc++) {
    bf16x8 wn[4];
    int kcn = (kc + 1) & 7;
#pragma unroll
    for (int ct = 0; ct < 4; ct++)
      wn[ct] = *(const bf16x8*)(w1p + ct * 4096 + kcn * 32);

    bf16x8 ke8 = *(const bf16x8*)(keb_s + kc * 32 + quad * 8);
    bf16x8 af0 = rotk(wc[0], ke8);
    bf16x8 af1 = rotk(wc[1], ke8);
    bf16x8 af2 = rotk(wc[2], ke8);
    bf16x8 af3 = rotk(wc[3], ke8);

#pragma unroll
    for (int nt = 0; nt < 4; nt++) {
      bf16x8 qf = *(const bf16x8*)(qe_smem + (nt * 16 + l15) * 512 + colx[kc]);
      acc[0][nt] = __builtin_amdgcn_mfma_f32_16x16x32_bf16(af0, qf, acc[0][nt], 0, 0, 0);
      acc[1][nt] = __builtin_amdgcn_mfma_f32_16x16x32_bf16(af1, qf, acc[1][nt], 0, 0, 0);
      acc[2][nt] = __builtin_amdgcn_mfma_f32_16x16x32_bf16(af2, qf, acc[2][nt], 0, 0, 0);
      acc[3][nt] = __builtin_amdgcn_mfma_f32_16x16x32_bf16(af3, qf, acc[3][nt], 0, 0, 0);
    }
#pragma unroll
    for (int ct = 0; ct < 4; ct++) wc[ct] = wn[ct];
  }

  // epilogue operands (loaded after k-loop to keep loop pressure down)
  float b1a[4][4];
#pragma unroll
  for (int ct = 0; ct < 4; ct++)
#pragma unroll
    for (int r = 0; r < 4; r++) b1a[ct][r] = pos_b1[w * 64 + ct * 16 + quad * 4 + r];
  bf16x8 w2f[8];
#pragma unroll
  for (int kc = 0; kc < 8; kc++)
    w2f[kc] = *(const bf16x8*)(w2pb + (unsigned)l15 * 256u + kc * 32 + quad * 8);

  __syncthreads();   // all waves done reading qe_smem

  // hid = relu(D1 + b1) -> bf16, written into qe_smem as [q][c] swizzled.
  // C-frag lane mapping: col(q within ntile)=l15, row(c within mtile)=quad*4+r.
#pragma unroll
  for (int ct = 0; ct < 4; ct++) {
#pragma unroll
    for (int nt = 0; nt < 4; nt++) {
      int q = nt * 16 + l15;
      unsigned lo = packbf(fmaxf(acc[ct][nt][0] + b1a[ct][0], 0.f),
                           fmaxf(acc[ct][nt][1] + b1a[ct][1], 0.f));
      unsigned hi = packbf(fmaxf(acc[ct][nt][2] + b1a[ct][2], 0.f),
                           fmaxf(acc[ct][nt][3] + b1a[ct][3], 0.f));
      int cbyte = w * 128 + ct * 32 + quad * 8;    // (c index)*2 bytes
      char* p = qe_smem + q * 512 + (cbyte ^ ((q & 7) << 4));
      unsigned long long v = (unsigned long long)lo | ((unsigned long long)hi << 32);
      *(unsigned long long*)p = v;
    }
  }
  __syncthreads();   // hid ready

  // GEMM2: bias[h, q] = W2pad[16x256] @ hid[256 x 64]. Wave w -> q rows
  // [16w, 16w+16). 8 MFMAs. Output D: col=q=l15, row=h=quad*4+r (quad<2 real).
  {
    int row = w * 16 + l15;
    const char* hbase = qe_smem + row * 512;
    int hxm = (l15 & 7) << 4;
    f32x4 acc2 = zero4;
#pragma unroll
    for (int kc = 0; kc < 8; kc++) {
      bf16x8 hf = *(const bf16x8*)(hbase + ((kc * 64 + quad * 16) ^ hxm));
      acc2 = __builtin_amdgcn_mfma_f32_16x16x32_bf16(w2f[kc], hf, acc2, 0, 0, 0);
    }
    if (quad < 2) {
      int qg = q0 + row;
      bf16x4 o;
#pragma unroll
      for (int r = 0; r < 4; r++) o[r] = (__bf16)(acc2[r] + pos_b2[quad * 4 + r]);
      *(bf16x4*)(biasb + (unsigned)qg * 896u + (unsigned)k * 8u + quad * 4) = o;
    }
  }
}

// ---------------------------------------------------------------------------
// attn kernel: per block = 4 queries. scores -> softmax -> ctx/aw -> out_proj
// -> cat_pos -> embed. 256 threads.
__global__ __launch_bounds__(256, 4) void attn_kernel(
    const float* __restrict__ qfeat, const float* __restrict__ qpos,
    const float* __restrict__ kpos,
    const float* __restrict__ out_w, const float* __restrict__ out_b,
    const float* __restrict__ embed_b, const float* __restrict__ ptw,
    const float* __restrict__ ws, float* __restrict__ out)
{
  __shared__ float qh_s[4 * 8 * 36];
  __shared__ float attn_s[4 * 8 * 116];
  __shared__ float ctx_s[4 * 264];
  __shared__ float cat_s[4 * 264];
  __shared__ float aw_s[4 * 104];

  int bid = blockIdx.x;
  int qg0 = bid * 4;
  int n = bid / 400;
  int t = threadIdx.x;

  const __bf16* qhb = (const __bf16*)(ws + WS_QHB);
  const __bf16* biasb = (const __bf16*)(ws + WS_BIASB);
  const float* kh = ws + WS_KH;
  const float* vh = ws + WS_VH;
  const float* ewp = ws + WS_EWP;

  for (int i = t; i < 1024; i += 256) {
    int q = i >> 8, c = i & 255;
    qh_s[(q * 8 + (c >> 5)) * 36 + (c & 31)] = (float)qhb[(unsigned)(qg0 + q) * 256u + c];
  }
  __syncthreads();

  for (int i = 0; i < 4; i++) {
    int p = t + i * 256;
    if (p < 800) {
      int k = p >> 3, h = p & 7;
      const float4* kf = (const float4*)(kh + (unsigned)(n * 100 + k) * 256u + h * 32);
      float4 kv[8];
#pragma unroll
      for (int dd = 0; dd < 8; dd++) kv[dd] = kf[dd];
#pragma unroll
      for (int q = 0; q < 4; q++) {
        const float4* qf = (const float4*)(qh_s + (q * 8 + h) * 36);
        float s = (float)biasb[((unsigned)(qg0 + q) * 112u + k) * 8u + h];
#pragma unroll
        for (int dd = 0; dd < 8; dd++) {
          float4 qv = qf[dd];
          s += kv[dd].x * qv.x + kv[dd].y * qv.y + kv[dd].z * qv.z + kv[dd].w * qv.w;
        }
        attn_s[(q * 8 + h) * 116 + k] = s;
      }
    }
  }
  __syncthreads();

  {
    int q = t >> 6, h = (t >> 3) & 7, j = t & 7;
    float* row = attn_s + (q * 8 + h) * 116;
    float mx = -1e30f;
    for (int k = j; k < 100; k += 8) mx = fmaxf(mx, row[k]);
    mx = fmaxf(mx, __shfl_xor(mx, 1, 8));
    mx = fmaxf(mx, __shfl_xor(mx, 2, 8));
    mx = fmaxf(mx, __shfl_xor(mx, 4, 8));
    float sum = 0.f;
    for (int k = j; k < 100; k += 8) { float e = __expf(row[k] - mx); row[k] = e; sum += e; }
    sum += __shfl_xor(sum, 1, 8);
    sum += __shfl_xor(sum, 2, 8);
    sum += __shfl_xor(sum, 4, 8);
    float inv = 1.0f / sum;
    for (int k = j; k < 100; k += 8) row[k] *= inv;
  }
  __syncthreads();

  for (int p = t; p < 416; p += 256) {
    int q = p / 104, k = p % 104;
    if (k < 100) {
      float s = 0.f;
#pragma unroll
      for (int h = 0; h < 8; h++) s += attn_s[(q * 8 + h) * 116 + k];
      aw_s[q * 104 + k] = s * 0.125f;
    }
  }
  {
    int c = t, h = c >> 5;
    float a0 = 0.f, a1 = 0.f, a2 = 0.f, a3 = 0.f;
    const float* vp = vh + (unsigned)(n * 100) * 256u + c;
    const float* r0 = attn_s + (0 * 8 + h) * 116;
    const float* r1 = attn_s + (1 * 8 + h) * 116;
    const float* r2 = attn_s + (2 * 8 + h) * 116;
    const float* r3 = attn_s + (3 * 8 + h) * 116;
#pragma unroll 4
    for (int k = 0; k < 100; k++) {
      float vv = vp[(unsigned)k * 256u];
      a0 = fmaf(r0[k], vv, a0);
      a1 = fmaf(r1[k], vv, a1);
      a2 = fmaf(r2[k], vv, a2);
      a3 = fmaf(r3[k], vv, a3);
    }
    ctx_s[0 * 264 + c] = a0; ctx_s[1 * 264 + c] = a1;
    ctx_s[2 * 264 + c] = a2; ctx_s[3 * 264 + c] = a3;
  }
  __syncthreads();

  if (t < 8) {
    int q = t >> 1, cd = t & 1;
    float qp = qpos[(qg0 + q) * 2 + cd];
    float s = 0.f;
    for (int k = 0; k < 100; k++)
      s = fmaf(aw_s[q * 104 + k], kpos[(n * 100 + k) * 2 + cd] - qp, s);
    float so = __shfl_xor(s, 1, 2);
    if (cd == 0) cat_s[q * 264 + 256] = ptw[0] * s + ptw[1] * so;
    else         cat_s[q * 264 + 257] = ptw[2] * so + ptw[3] * s;
  }

  {
    int c = t, lane = t & 63;
    float ob = out_b[c];
    float acc0 = ob, acc1 = ob, acc2 = ob, acc3 = ob;
    const float* wr = out_w + (unsigned)c * 256u;
    for (int ch = 0; ch < 4; ch++) {
      float v0 = ctx_s[0 * 264 + ch * 64 + lane];
      float v1 = ctx_s[1 * 264 + ch * 64 + lane];
      float v2 = ctx_s[2 * 264 + ch * 64 + lane];
      float v3 = ctx_s[3 * 264 + ch * 64 + lane];
      const float* wp = wr + ch * 64;
#pragma unroll 4
      for (int j4 = 0; j4 < 16; j4++) {
        float4 w4 = *(const float4*)(wp + j4 * 4);
        int jb = j4 * 4;
        acc0 = fmaf(rdlane(v0, jb + 0), w4.x, acc0);
        acc1 = fmaf(rdlane(v1, jb + 0), w4.x, acc1);
        acc2 = fmaf(rdlane(v2, jb + 0), w4.x, acc2);
        acc3 = fmaf(rdlane(v3, jb + 0), w4.x, acc3);
        acc0 = fmaf(rdlane(v0, jb + 1), w4.y, acc0);
        acc1 = fmaf(rdlane(v1, jb + 1), w4.y, acc1);
        acc2 = fmaf(rdlane(v2, jb + 1), w4.y, acc2);
        acc3 = fmaf(rdlane(v3, jb + 1), w4.y, acc3);
        acc0 = fmaf(rdlane(v0, jb + 2), w4.z, acc0);
        acc1 = fmaf(rdlane(v1, jb + 2), w4.z, acc1);
        acc2 = fmaf(rdlane(v2, jb + 2), w4.z, acc2);
        acc3 = fmaf(rdlane(v3, jb + 2), w4.z, acc3);
        acc0 = fmaf(rdlane(v0, jb + 3), w4.w, acc0);
        acc1 = fmaf(rdlane(v1, jb + 3), w4.w, acc1);
        acc2 = fmaf(rdlane(v2, jb + 3), w4.w, acc2);
        acc3 = fmaf(rdlane(v3, jb + 3), w4.w, acc3);
      }
    }
    cat_s[0 * 264 + c] = fmaxf(qfeat[(unsigned)(qg0 + 0) * 256u + c] + acc0, 0.f);
    cat_s[1 * 264 + c] = fmaxf(qfeat[(unsigned)(qg0 + 1) * 256u + c] + acc1, 0.f);
    cat_s[2 * 264 + c] = fmaxf(qfeat[(unsigned)(qg0 + 2) * 256u + c] + acc2, 0.f);
    cat_s[3 * 264 + c] = fmaxf(qfeat[(unsigned)(qg0 + 3) * 256u + c] + acc3, 0.f);
  }
  __syncthreads();

  {
    int c = t, lane = t & 63;
    float eb = embed_b[c];
    float acc0 = eb, acc1 = eb, acc2 = eb, acc3 = eb;
    const float* er = ewp + (unsigned)c * 260u;
    for (int ch = 0; ch < 4; ch++) {
      float v0 = cat_s[0 * 264 + ch * 64 + lane];
      float v1 = cat_s[1 * 264 + ch * 64 + lane];
      float v2 = cat_s[2 * 264 + ch * 64 + lane];
      float v3 = cat_s[3 * 264 + ch * 64 + lane];
      const float* wp = er + ch * 64;
#pragma unroll 4
      for (int j4 = 0; j4 < 16; j4++) {
        float4 w4 = *(const float4*)(wp + j4 * 4);
        int jb = j4 * 4;
        acc0 = fmaf(rdlane(v0, jb + 0), w4.x, acc0);
        acc1 = fmaf(rdlane(v1, jb + 0), w4.x, acc1);
        acc2 = fmaf(rdlane(v2, jb + 0), w4.x, acc2);
        acc3 = fmaf(rdlane(v3, jb + 0), w4.x, acc3);
        acc0 = fmaf(rdlane(v0, jb + 1), w4.y, acc0);
        acc1 = fmaf(rdlane(v1, jb + 1), w4.y, acc1);
        acc2 = fmaf(rdlane(v2, jb + 1), w4.y, acc2);
        acc3 = fmaf(rdlane(v3, jb + 1), w4.y, acc3);
        acc0 = fmaf(rdlane(v0, jb + 2), w4.z, acc0);
        acc1 = fmaf(rdlane(v1, jb + 2), w4.z, acc1);
        acc2 = fmaf(rdlane(v2, jb + 2), w4.z, acc2);
        acc3 = fmaf(rdlane(v3, jb + 2), w4.z, acc3);
        acc0 = fmaf(rdlane(v0, jb + 3), w4.w, acc0);
        acc1 = fmaf(rdlane(v1, jb + 3), w4.w, acc1);
        acc2 = fmaf(rdlane(v2, jb + 3), w4.w, acc2);
        acc3 = fmaf(rdlane(v3, jb + 3), w4.w, acc3);
      }
    }
    float4 wt = *(const float4*)(er + 256);
    acc0 += cat_s[0 * 264 + 256] * wt.x + cat_s[0 * 264 + 257] * wt.y;
    acc1 += cat_s[1 * 264 + 256] * wt.x + cat_s[1 * 264 + 257] * wt.y;
    acc2 += cat_s[2 * 264 + 256] * wt.x + cat_s[2 * 264 + 257] * wt.y;
    acc3 += cat_s[3 * 264 + 256] * wt.x + cat_s[3 * 264 + 257] * wt.y;
    out[(unsigned)(qg0 + 0) * 256u + c] = fmaxf(acc0, 0.f);
    out[(unsigned)(qg0 + 1) * 256u + c] = fmaxf(acc1, 0.f);
    out[(unsigned)(qg0 + 2) * 256u + c] = fmaxf(acc2, 0.f);
    out[(unsigned)(qg0 + 3) * 256u + c] = fmaxf(acc3, 0.f);
  }
}

// ---------------------------------------------------------------------------
extern "C" void kernel_launch(void* const* d_in, const int* in_sizes, int n_in,
                              void* d_out, int out_size, void* d_ws, size_t ws_size,
                              hipStream_t stream)
{
  const float* query_feature  = (const float*)d_in[0];
  const float* query_position = (const float*)d_in[1];
  const float* key_feature    = (const float*)d_in[2];
  const float* key_position   = (const float*)d_in[3];
  const float* in_proj_w      = (const float*)d_in[4];
  const float* in_proj_b      = (const float*)d_in[5];
  const float* out_proj_w     = (const float*)d_in[6];
  const float* out_proj_b     = (const float*)d_in[7];
  const float* pos_w1         = (const float*)d_in[8];
  const float* pos_b1         = (const float*)d_in[9];
  const float* pos_w2         = (const float*)d_in[10];
  const float* pos_b2         = (const float*)d_in[11];
  const float* pos_trans_w    = (const float*)d_in[12];
  const float* embed_w        = (const float*)d_in[13];
  const float* embed_b        = (const float*)d_in[14];
  float* ws  = (float*)d_ws;
  float* out = (float*)d_out;

  hipLaunchKernelGGL(prep_kernel, dim3(1379), dim3(256), 0, stream,
                     query_feature, key_feature, key_position, query_position,
                     in_proj_w, in_proj_b, pos_w1, pos_w2, embed_w, ws);
  hipLaunchKernelGGL(bias_kernel, dim3(5000), dim3(256), 0, stream,
                     pos_b1, pos_b2, ws);
  hipLaunchKernelGGL(attn_kernel, dim3(800), dim3(256), 0, stream,
                     query_feature, query_position, key_position,
                     out_proj_w, out_proj_b, embed_b, pos_trans_w,
                     ws, out);
}

// Round 5
// 296.498 us; speedup vs baseline: 1.5052x; 1.0121x over previous
//
#include <hip/hip_runtime.h>
#include <math.h>

typedef __bf16 bf16x8 __attribute__((ext_vector_type(8)));
typedef __bf16 bf16x4 __attribute__((ext_vector_type(4)));
typedef float  f32x4  __attribute__((ext_vector_type(4)));

// N=2, Q=1600, K=100 (pad 112), C=256, h=8, d=32.

// ---- workspace layout (float offsets), total 2,482,976 f32 = 9.93 MB ----
#define WS_KH    0u        // [200][256] f32 k projection                 -> 51200
#define WS_VH    51200u    // [200][256] f32 v projection                 -> 102400
#define WS_EWP   102400u   // [256][260] f32 embed_w padded rows          -> 168960
#define WS_QHB   168960u   // bf16 [3200][256] scaled q projection        -> 578560
#define WS_BIASB 578560u   // bf16 [3200][112][8] rel-pos bias            -> 2012160
#define WS_KEB   2012160u  // bf16 [200][264] key sin/cos table (pad 264) -> 2038560
#define WS_W1B   2038560u  // bf16 [256][256] pos_w1                      -> 2071328
#define WS_W2PB  2071328u  // bf16 [16][256] pos_w2 padded                -> 2073376
#define WS_QEB   2073376u  // bf16 [3200][256] query sin/cos table        -> 2482976

__device__ __forceinline__ float rdlane(float v, int l) {
  return __uint_as_float(__builtin_amdgcn_readlane(__float_as_uint(v), l));
}

__device__ __forceinline__ unsigned packbf(float a, float b) {
  unsigned short ua = __builtin_bit_cast(unsigned short, (__bf16)a);
  unsigned short ub = __builtin_bit_cast(unsigned short, (__bf16)b);
  return (unsigned)ua | ((unsigned)ub << 16);
}

// ---------------------------------------------------------------------------
// prep: keb/qe tables + bf16 casts + embed_w pad + q/k/v projections (fused)
__global__ __launch_bounds__(256, 2) void prep_kernel(
    const float* __restrict__ qfeat, const float* __restrict__ kfeat,
    const float* __restrict__ kpos, const float* __restrict__ qpos,
    const float* __restrict__ ipw, const float* __restrict__ ipb,
    const float* __restrict__ pos_w1, const float* __restrict__ pos_w2,
    const float* __restrict__ embed_w, float* __restrict__ ws)
{
  __shared__ float x[8 * 256];
  int bid = blockIdx.x, t = threadIdx.x;

  if (bid < 50) {
    int r = bid * 4 + (t >> 6);
    int u = t & 63;
    float p0 = kpos[r * 2 + 0], p1 = kpos[r * 2 + 1];
    __bf16* keb = (__bf16*)(ws + WS_KEB);
    bf16x4 o;
#pragma unroll
    for (int j = 0; j < 4; j++) {
      int col = u * 4 + j;
      int c = col >> 7, i = (col & 127) >> 1;
      float p = c ? p1 : p0;
      float inv = exp2f((float)i * (-13.287712379549449f / 64.0f));
      float v = p * inv;
      o[j] = (__bf16)((col & 1) ? __cosf(v) : __sinf(v));
    }
    *(bf16x4*)(keb + r * 264 + u * 4) = o;
  } else if (bid < 114) {
    int idx = (bid - 50) * 1024 + t * 4;
    float4 v = *(const float4*)(pos_w1 + idx);
    bf16x4 o; o[0] = (__bf16)v.x; o[1] = (__bf16)v.y; o[2] = (__bf16)v.z; o[3] = (__bf16)v.w;
    *(bf16x4*)((__bf16*)(ws + WS_W1B) + idx) = o;
  } else if (bid == 114) {
    __bf16* w2pb = (__bf16*)(ws + WS_W2PB);
    for (int i = 0; i < 16; i++) {
      int idx = t * 16 + i;
      w2pb[idx] = (idx < 2048) ? (__bf16)pos_w2[idx] : (__bf16)0.0f;
    }
  } else if (bid < 147) {
    int r0 = (bid - 115) * 8;
    for (int rr = 0; rr < 8; rr++) {
      int r = r0 + rr;
      for (int j = t; j < 260; j += 256)
        ws[WS_EWP + r * 260 + j] = (j < 258) ? embed_w[r * 258 + j] : 0.0f;
    }
  } else if (bid < 547) {
    int r0 = (bid - 147) * 8;
    for (int i = t; i < 2048; i += 256) x[i] = qfeat[(unsigned)r0 * 256u + i];
    __syncthreads();
    float acc[8]; float bq = ipb[t];
#pragma unroll
    for (int rr = 0; rr < 8; rr++) acc[rr] = bq;
    const float* wrow = ipw + (unsigned)t * 256u;
    for (int j = 0; j < 256; j += 4) {
      float4 w4 = *(const float4*)(wrow + j);
#pragma unroll
      for (int rr = 0; rr < 8; rr++) {
        float4 x4 = *(const float4*)(x + rr * 256 + j);
        acc[rr] = fmaf(x4.x, w4.x, fmaf(x4.y, w4.y, fmaf(x4.z, w4.z, fmaf(x4.w, w4.w, acc[rr]))));
      }
    }
    __bf16* qhb = (__bf16*)(ws + WS_QHB);
#pragma unroll
    for (int rr = 0; rr < 8; rr++)
      qhb[(unsigned)(r0 + rr) * 256u + t] = (__bf16)(acc[rr] * 0.17677669529663687f);
  } else if (bid < 579) {
    int b2 = bid - 547; int n = b2 >> 4, tile = b2 & 15;
    int r0l = tile * 7; int cnt = 100 - r0l; if (cnt > 7) cnt = 7; if (cnt <= 0) return;
    int r0 = n * 100 + r0l;
    for (int i = t; i < cnt * 256; i += 256) x[i] = kfeat[(unsigned)r0 * 256u + i];
    __syncthreads();
    float ak[7], av[7]; float bk = ipb[256 + t], bv = ipb[512 + t];
#pragma unroll
    for (int rr = 0; rr < 7; rr++) { ak[rr] = bk; av[rr] = bv; }
    const float* wkr = ipw + (unsigned)(256 + t) * 256u;
    const float* wvr = ipw + (unsigned)(512 + t) * 256u;
    for (int j = 0; j < 256; j += 4) {
      float4 wk4 = *(const float4*)(wkr + j);
      float4 wv4 = *(const float4*)(wvr + j);
#pragma unroll
      for (int rr = 0; rr < 7; rr++) {
        float4 x4 = *(const float4*)(x + rr * 256 + j);
        ak[rr] = fmaf(x4.x, wk4.x, fmaf(x4.y, wk4.y, fmaf(x4.z, wk4.z, fmaf(x4.w, wk4.w, ak[rr]))));
        av[rr] = fmaf(x4.x, wv4.x, fmaf(x4.y, wv4.y, fmaf(x4.z, wv4.z, fmaf(x4.w, wv4.w, av[rr]))));
      }
    }
    for (int rr = 0; rr < 7; rr++) {
      if (rr < cnt) {
        ws[WS_KH + (unsigned)(r0 + rr) * 256u + t] = ak[rr];
        ws[WS_VH + (unsigned)(r0 + rr) * 256u + t] = av[rr];
      }
    }
  } else {
    // qe table: rows 0..3199, 4 rows per block
    int r = (bid - 579) * 4 + (t >> 6);
    int u = t & 63;
    float p0 = qpos[r * 2 + 0], p1 = qpos[r * 2 + 1];
    __bf16* qeb = (__bf16*)(ws + WS_QEB);
    bf16x4 o;
#pragma unroll
    for (int j = 0; j < 4; j++) {
      int col = u * 4 + j;
      int c = col >> 7, i = (col & 127) >> 1;
      float p = c ? p1 : p0;
      float inv = exp2f((float)i * (-13.287712379549449f / 64.0f));
      float v = p * inv;
      o[j] = (__bf16)((col & 1) ? __cosf(v) : __sinf(v));
    }
    *(bf16x4*)(qeb + r * 256 + u * 4) = o;
  }
}

// ---------------------------------------------------------------------------
// bias kernel v8: key-side fold (r4-validated math) + rot amortized 5x.
// Block = one (n,k) x 320 queries (5 tiles of 64), grid 1000, 256 thr.
// Prologue: rotate W1 by the block's key angles ONCE into af[8][4] regs
// (128 VGPR, resident). Inner loop per 64-q tile: 128 MFMA from LDS qe
// (XOR-swizzled, r4 pattern) -> hid relu/pack -> separate hid LDS -> GEMM2
// (w2 frags streamed per tile, disjoint lifetime with acc) -> bias store.
// Next tile's qe global loads issued before GEMM2 (latency hides under it).
// 2 barriers/tile. r4 failure mode fixed: rot VALU was 25x redundant
// (per-64q block); now once per 320 q. Peak regs ~235 < 256 @ 2 waves/SIMD.
// LDS: qe 32K + hid 32K + keb 512 = 66048 B -> 2 blocks/CU.
__global__ __launch_bounds__(256, 2) void bias_kernel(
    const float* __restrict__ pos_b1, const float* __restrict__ pos_b2,
    float* __restrict__ ws)
{
  __shared__ __align__(16) char qe_smem[32768];    // [64 q][512B] swizzled
  __shared__ __align__(16) char hid_smem[32768];   // [64 q][512B] swizzled
  __shared__ __align__(16) __bf16 keb_s[256];

  int bid = blockIdx.x;           // 0..999 = nk(200) x qgroup(5)
  int nk = bid / 5, g = bid - nk * 5;
  int n = nk / 100, k = nk - n * 100;
  int qbase = n * 1600 + g * 320;
  int t = threadIdx.x;
  int lane = t & 63, w = t >> 6;
  int l15 = lane & 15, quad = lane >> 4;

  const __bf16* keb = (const __bf16*)(ws + WS_KEB) + (unsigned)nk * 264u;
  const __bf16* qeb = (const __bf16*)(ws + WS_QEB);
  const __bf16* w1b = (const __bf16*)(ws + WS_W1B);
  const __bf16* w2pb = (const __bf16*)(ws + WS_W2PB);
  __bf16* biasb = (__bf16*)(ws + WS_BIASB);

  if (t < 32) *(bf16x8*)(keb_s + t * 8) = *(const bf16x8*)(keb + t * 8);

  // stage qe tile 0 (XOR swizzle byte ^= (row&7)<<4; r4-validated)
  int sr = t >> 2, ssub = t & 3, sswz = (sr & 7) << 4;
  {
    const __bf16* src = qeb + (unsigned)(qbase + sr) * 256u + ssub * 64;
    char* dst = qe_smem + sr * 512;
#pragma unroll
    for (int u = 0; u < 8; u++) {
      bf16x8 v = *(const bf16x8*)(src + u * 8);
      *(bf16x8*)(dst + ((ssub * 128 + u * 16) ^ sswz)) = v;
    }
  }

  // per-lane constant addressing (r4-validated)
  int xm = (l15 & 7) << 4;
  int colx[8];
#pragma unroll
  for (int kc = 0; kc < 8; kc++) colx[kc] = ((kc * 64 + quad * 16) ^ xm);
  const __bf16* w1p = w1b + (unsigned)(w * 64 + l15) * 256u + quad * 8;

  float b1a[4][4];
#pragma unroll
  for (int ct = 0; ct < 4; ct++)
#pragma unroll
    for (int r = 0; r < 4; r++) b1a[ct][r] = pos_b1[w * 64 + ct * 16 + quad * 4 + r];

  f32x4 zero4; zero4[0] = 0.f; zero4[1] = 0.f; zero4[2] = 0.f; zero4[3] = 0.f;

  __syncthreads();   // keb_s + qe tile0 ready

  // rotate W1 -> af regs, ONCE per block (key-side fold, r4-validated):
  //   PQ[c,2m]   = W1[c,2m+1]*sk - W1[c,2m]*ck
  //   PQ[c,2m+1] = W1[c,2m]*sk   + W1[c,2m+1]*ck
  bf16x8 af[8][4];
#pragma unroll
  for (int kc = 0; kc < 8; kc++) {
    bf16x8 ke8 = *(const bf16x8*)(keb_s + kc * 32 + quad * 8);
#pragma unroll
    for (int ct = 0; ct < 4; ct++) {
      bf16x8 w8 = *(const bf16x8*)(w1p + ct * 4096 + kc * 32);
      bf16x8 a;
#pragma unroll
      for (int p2 = 0; p2 < 4; p2++) {
        float we = (float)w8[2 * p2], wo = (float)w8[2 * p2 + 1];
        float sk = (float)ke8[2 * p2], ck = (float)ke8[2 * p2 + 1];
        a[2 * p2]     = (__bf16)fmaf(wo, sk, -(we * ck));
        a[2 * p2 + 1] = (__bf16)fmaf(we, sk, wo * ck);
      }
      af[kc][ct] = a;
    }
  }

#pragma unroll 1
  for (int tt = 0; tt < 5; tt++) {
    // GEMM1: wave w owns c-rows [64w, 64w+64). 128 MFMA, zero barriers.
    f32x4 acc[4][4];
#pragma unroll
    for (int ct = 0; ct < 4; ct++)
#pragma unroll
      for (int nt = 0; nt < 4; nt++) acc[ct][nt] = zero4;

#pragma unroll
    for (int kc = 0; kc < 8; kc++) {
#pragma unroll
      for (int nt = 0; nt < 4; nt++) {
        bf16x8 qf = *(const bf16x8*)(qe_smem + (nt * 16 + l15) * 512 + colx[kc]);
        acc[0][nt] = __builtin_amdgcn_mfma_f32_16x16x32_bf16(af[kc][0], qf, acc[0][nt], 0, 0, 0);
        acc[1][nt] = __builtin_amdgcn_mfma_f32_16x16x32_bf16(af[kc][1], qf, acc[1][nt], 0, 0, 0);
        acc[2][nt] = __builtin_amdgcn_mfma_f32_16x16x32_bf16(af[kc][2], qf, acc[2][nt], 0, 0, 0);
        acc[3][nt] = __builtin_amdgcn_mfma_f32_16x16x32_bf16(af[kc][3], qf, acc[3][nt], 0, 0, 0);
      }
    }

    // hid = relu(D1 + b1) -> bf16 -> hid_smem (lane: c=64w+ct*16+quad*4+r,
    // q=nt*16+l15; 8B writes, same XOR swizzle keyed on q row)
#pragma unroll
    for (int ct = 0; ct < 4; ct++) {
#pragma unroll
      for (int nt = 0; nt < 4; nt++) {
        int q = nt * 16 + l15;
        unsigned lo = packbf(fmaxf(acc[ct][nt][0] + b1a[ct][0], 0.f),
                             fmaxf(acc[ct][nt][1] + b1a[ct][1], 0.f));
        unsigned hi = packbf(fmaxf(acc[ct][nt][2] + b1a[ct][2], 0.f),
                             fmaxf(acc[ct][nt][3] + b1a[ct][3], 0.f));
        int cbyte = w * 128 + ct * 32 + quad * 8;
        char* p = hid_smem + q * 512 + (cbyte ^ ((q & 7) << 4));
        unsigned long long v = (unsigned long long)lo | ((unsigned long long)hi << 32);
        *(unsigned long long*)p = v;
      }
    }

    // W2 frags for GEMM2 (L2-hot; issued before barrier so latency overlaps)
    bf16x8 w2f[8];
#pragma unroll
    for (int kc = 0; kc < 8; kc++)
      w2f[kc] = *(const bf16x8*)(w2pb + (unsigned)l15 * 256u + kc * 32 + quad * 8);

    __syncthreads();   // hid visible to all; all qe reads complete

    // issue next tile's qe loads (land during GEMM2)
    bf16x8 qv[8];
    if (tt < 4) {
      const __bf16* src = qeb + (unsigned)(qbase + (tt + 1) * 64 + sr) * 256u + ssub * 64;
#pragma unroll
      for (int u = 0; u < 8; u++) qv[u] = *(const bf16x8*)(src + u * 8);
    }

    // GEMM2: wave w -> q rows [16w,16w+16). bias = W2pad @ hid + b2.
    {
      int row = w * 16 + l15;
      const char* hbase = hid_smem + row * 512;
      int hxm = (l15 & 7) << 4;
      f32x4 acc2 = zero4;
#pragma unroll
      for (int kc = 0; kc < 8; kc++) {
        bf16x8 hf = *(const bf16x8*)(hbase + ((kc * 64 + quad * 16) ^ hxm));
        acc2 = __builtin_amdgcn_mfma_f32_16x16x32_bf16(w2f[kc], hf, acc2, 0, 0, 0);
      }
      if (quad < 2) {
        int qg = qbase + tt * 64 + row;
        bf16x4 o;
#pragma unroll
        for (int r = 0; r < 4; r++) o[r] = (__bf16)(acc2[r] + pos_b2[quad * 4 + r]);
        *(bf16x4*)(biasb + (unsigned)qg * 896u + (unsigned)k * 8u + quad * 4) = o;
      }
    }

    // write staged qe (qe_smem free since the barrier) and sync for next tile
    if (tt < 4) {
      char* dst = qe_smem + sr * 512;
#pragma unroll
      for (int u = 0; u < 8; u++)
        *(bf16x8*)(dst + ((ssub * 128 + u * 16) ^ sswz)) = qv[u];
      __syncthreads();
    }
  }
}

// ---------------------------------------------------------------------------
// attn kernel: per block = 4 queries. scores -> softmax -> ctx/aw -> out_proj
// -> cat_pos -> embed. 256 threads.
__global__ __launch_bounds__(256, 4) void attn_kernel(
    const float* __restrict__ qfeat, const float* __restrict__ qpos,
    const float* __restrict__ kpos,
    const float* __restrict__ out_w, const float* __restrict__ out_b,
    const float* __restrict__ embed_b, const float* __restrict__ ptw,
    const float* __restrict__ ws, float* __restrict__ out)
{
  __shared__ float qh_s[4 * 8 * 36];
  __shared__ float attn_s[4 * 8 * 116];
  __shared__ float ctx_s[4 * 264];
  __shared__ float cat_s[4 * 264];
  __shared__ float aw_s[4 * 104];

  int bid = blockIdx.x;
  int qg0 = bid * 4;
  int n = bid / 400;
  int t = threadIdx.x;

  const __bf16* qhb = (const __bf16*)(ws + WS_QHB);
  const __bf16* biasb = (const __bf16*)(ws + WS_BIASB);
  const float* kh = ws + WS_KH;
  const float* vh = ws + WS_VH;
  const float* ewp = ws + WS_EWP;

  for (int i = t; i < 1024; i += 256) {
    int q = i >> 8, c = i & 255;
    qh_s[(q * 8 + (c >> 5)) * 36 + (c & 31)] = (float)qhb[(unsigned)(qg0 + q) * 256u + c];
  }
  __syncthreads();

  for (int i = 0; i < 4; i++) {
    int p = t + i * 256;
    if (p < 800) {
      int k = p >> 3, h = p & 7;
      const float4* kf = (const float4*)(kh + (unsigned)(n * 100 + k) * 256u + h * 32);
      float4 kv[8];
#pragma unroll
      for (int dd = 0; dd < 8; dd++) kv[dd] = kf[dd];
#pragma unroll
      for (int q = 0; q < 4; q++) {
        const float4* qf = (const float4*)(qh_s + (q * 8 + h) * 36);
        float s = (float)biasb[((unsigned)(qg0 + q) * 112u + k) * 8u + h];
#pragma unroll
        for (int dd = 0; dd < 8; dd++) {
          float4 qv = qf[dd];
          s += kv[dd].x * qv.x + kv[dd].y * qv.y + kv[dd].z * qv.z + kv[dd].w * qv.w;
        }
        attn_s[(q * 8 + h) * 116 + k] = s;
      }
    }
  }
  __syncthreads();

  {
    int q = t >> 6, h = (t >> 3) & 7, j = t & 7;
    float* row = attn_s + (q * 8 + h) * 116;
    float mx = -1e30f;
    for (int k = j; k < 100; k += 8) mx = fmaxf(mx, row[k]);
    mx = fmaxf(mx, __shfl_xor(mx, 1, 8));
    mx = fmaxf(mx, __shfl_xor(mx, 2, 8));
    mx = fmaxf(mx, __shfl_xor(mx, 4, 8));
    float sum = 0.f;
    for (int k = j; k < 100; k += 8) { float e = __expf(row[k] - mx); row[k] = e; sum += e; }
    sum += __shfl_xor(sum, 1, 8);
    sum += __shfl_xor(sum, 2, 8);
    sum += __shfl_xor(sum, 4, 8);
    float inv = 1.0f / sum;
    for (int k = j; k < 100; k += 8) row[k] *= inv;
  }
  __syncthreads();

  for (int p = t; p < 416; p += 256) {
    int q = p / 104, k = p % 104;
    if (k < 100) {
      float s = 0.f;
#pragma unroll
      for (int h = 0; h < 8; h++) s += attn_s[(q * 8 + h) * 116 + k];
      aw_s[q * 104 + k] = s * 0.125f;
    }
  }
  {
    int c = t, h = c >> 5;
    float a0 = 0.f, a1 = 0.f, a2 = 0.f, a3 = 0.f;
    const float* vp = vh + (unsigned)(n * 100) * 256u + c;
    const float* r0 = attn_s + (0 * 8 + h) * 116;
    const float* r1 = attn_s + (1 * 8 + h) * 116;
    const float* r2 = attn_s + (2 * 8 + h) * 116;
    const float* r3 = attn_s + (3 * 8 + h) * 116;
#pragma unroll 4
    for (int k = 0; k < 100; k++) {
      float vv = vp[(unsigned)k * 256u];
      a0 = fmaf(r0[k], vv, a0);
      a1 = fmaf(r1[k], vv, a1);
      a2 = fmaf(r2[k], vv, a2);
      a3 = fmaf(r3[k], vv, a3);
    }
    ctx_s[0 * 264 + c] = a0; ctx_s[1 * 264 + c] = a1;
    ctx_s[2 * 264 + c] = a2; ctx_s[3 * 264 + c] = a3;
  }
  __syncthreads();

  if (t < 8) {
    int q = t >> 1, cd = t & 1;
    float qp = qpos[(qg0 + q) * 2 + cd];
    float s = 0.f;
    for (int k = 0; k < 100; k++)
      s = fmaf(aw_s[q * 104 + k], kpos[(n * 100 + k) * 2 + cd] - qp, s);
    float so = __shfl_xor(s, 1, 2);
    if (cd == 0) cat_s[q * 264 + 256] = ptw[0] * s + ptw[1] * so;
    else         cat_s[q * 264 + 257] = ptw[2] * so + ptw[3] * s;
  }

  {
    int c = t, lane = t & 63;
    float ob = out_b[c];
    float acc0 = ob, acc1 = ob, acc2 = ob, acc3 = ob;
    const float* wr = out_w + (unsigned)c * 256u;
    for (int ch = 0; ch < 4; ch++) {
      float v0 = ctx_s[0 * 264 + ch * 64 + lane];
      float v1 = ctx_s[1 * 264 + ch * 64 + lane];
      float v2 = ctx_s[2 * 264 + ch * 64 + lane];
      float v3 = ctx_s[3 * 264 + ch * 64 + lane];
      const float* wp = wr + ch * 64;
#pragma unroll 4
      for (int j4 = 0; j4 < 16; j4++) {
        float4 w4 = *(const float4*)(wp + j4 * 4);
        int jb = j4 * 4;
        acc0 = fmaf(rdlane(v0, jb + 0), w4.x, acc0);
        acc1 = fmaf(rdlane(v1, jb + 0), w4.x, acc1);
        acc2 = fmaf(rdlane(v2, jb + 0), w4.x, acc2);
        acc3 = fmaf(rdlane(v3, jb + 0), w4.x, acc3);
        acc0 = fmaf(rdlane(v0, jb + 1), w4.y, acc0);
        acc1 = fmaf(rdlane(v1, jb + 1), w4.y, acc1);
        acc2 = fmaf(rdlane(v2, jb + 1), w4.y, acc2);
        acc3 = fmaf(rdlane(v3, jb + 1), w4.y, acc3);
        acc0 = fmaf(rdlane(v0, jb + 2), w4.z, acc0);
        acc1 = fmaf(rdlane(v1, jb + 2), w4.z, acc1);
        acc2 = fmaf(rdlane(v2, jb + 2), w4.z, acc2);
        acc3 = fmaf(rdlane(v3, jb + 2), w4.z, acc3);
        acc0 = fmaf(rdlane(v0, jb + 3), w4.w, acc0);
        acc1 = fmaf(rdlane(v1, jb + 3), w4.w, acc1);
        acc2 = fmaf(rdlane(v2, jb + 3), w4.w, acc2);
        acc3 = fmaf(rdlane(v3, jb + 3), w4.w, acc3);
      }
    }
    cat_s[0 * 264 + c] = fmaxf(qfeat[(unsigned)(qg0 + 0) * 256u + c] + acc0, 0.f);
    cat_s[1 * 264 + c] = fmaxf(qfeat[(unsigned)(qg0 + 1) * 256u + c] + acc1, 0.f);
    cat_s[2 * 264 + c] = fmaxf(qfeat[(unsigned)(qg0 + 2) * 256u + c] + acc2, 0.f);
    cat_s[3 * 264 + c] = fmaxf(qfeat[(unsigned)(qg0 + 3) * 256u + c] + acc3, 0.f);
  }
  __syncthreads();

  {
    int c = t, lane = t & 63;
    float eb = embed_b[c];
    float acc0 = eb, acc1 = eb, acc2 = eb, acc3 = eb;
    const float* er = ewp + (unsigned)c * 260u;
    for (int ch = 0; ch < 4; ch++) {
      float v0 = cat_s[0 * 264 + ch * 64 + lane];
      float v1 = cat_s[1 * 264 + ch * 64 + lane];
      float v2 = cat_s[2 * 264 + ch * 64 + lane];
      float v3 = cat_s[3 * 264 + ch * 64 + lane];
      const float* wp = er + ch * 64;
#pragma unroll 4
      for (int j4 = 0; j4 < 16; j4++) {
        float4 w4 = *(const float4*)(wp + j4 * 4);
        int jb = j4 * 4;
        acc0 = fmaf(rdlane(v0, jb + 0), w4.x, acc0);
        acc1 = fmaf(rdlane(v1, jb + 0), w4.x, acc1);
        acc2 = fmaf(rdlane(v2, jb + 0), w4.x, acc2);
        acc3 = fmaf(rdlane(v3, jb + 0), w4.x, acc3);
        acc0 = fmaf(rdlane(v0, jb + 1), w4.y, acc0);
        acc1 = fmaf(rdlane(v1, jb + 1), w4.y, acc1);
        acc2 = fmaf(rdlane(v2, jb + 1), w4.y, acc2);
        acc3 = fmaf(rdlane(v3, jb + 1), w4.y, acc3);
        acc0 = fmaf(rdlane(v0, jb + 2), w4.z, acc0);
        acc1 = fmaf(rdlane(v1, jb + 2), w4.z, acc1);
        acc2 = fmaf(rdlane(v2, jb + 2), w4.z, acc2);
        acc3 = fmaf(rdlane(v3, jb + 2), w4.z, acc3);
        acc0 = fmaf(rdlane(v0, jb + 3), w4.w, acc0);
        acc1 = fmaf(rdlane(v1, jb + 3), w4.w, acc1);
        acc2 = fmaf(rdlane(v2, jb + 3), w4.w, acc2);
        acc3 = fmaf(rdlane(v3, jb + 3), w4.w, acc3);
      }
    }
    float4 wt = *(const float4*)(er + 256);
    acc0 += cat_s[0 * 264 + 256] * wt.x + cat_s[0 * 264 + 257] * wt.y;
    acc1 += cat_s[1 * 264 + 256] * wt.x + cat_s[1 * 264 + 257] * wt.y;
    acc2 += cat_s[2 * 264 + 256] * wt.x + cat_s[2 * 264 + 257] * wt.y;
    acc3 += cat_s[3 * 264 + 256] * wt.x + cat_s[3 * 264 + 257] * wt.y;
    out[(unsigned)(qg0 + 0) * 256u + c] = fmaxf(acc0, 0.f);
    out[(unsigned)(qg0 + 1) * 256u + c] = fmaxf(acc1, 0.f);
    out[(unsigned)(qg0 + 2) * 256u + c] = fmaxf(acc2, 0.f);
    out[(unsigned)(qg0 + 3) * 256u + c] = fmaxf(acc3, 0.f);
  }
}

// ---------------------------------------------------------------------------
extern "C" void kernel_launch(void* const* d_in, const int* in_sizes, int n_in,
                              void* d_out, int out_size, void* d_ws, size_t ws_size,
                              hipStream_t stream)
{
  const float* query_feature  = (const float*)d_in[0];
  const float* query_position = (const float*)d_in[1];
  const float* key_feature    = (const float*)d_in[2];
  const float* key_position   = (const float*)d_in[3];
  const float* in_proj_w      = (const float*)d_in[4];
  const float* in_proj_b      = (const float*)d_in[5];
  const float* out_proj_w     = (const float*)d_in[6];
  const float* out_proj_b     = (const float*)d_in[7];
  const float* pos_w1         = (const float*)d_in[8];
  const float* pos_b1         = (const float*)d_in[9];
  const float* pos_w2         = (const float*)d_in[10];
  const float* pos_b2         = (const float*)d_in[11];
  const float* pos_trans_w    = (const float*)d_in[12];
  const float* embed_w        = (const float*)d_in[13];
  const float* embed_b        = (const float*)d_in[14];
  float* ws  = (float*)d_ws;
  float* out = (float*)d_out;

  hipLaunchKernelGGL(prep_kernel, dim3(1379), dim3(256), 0, stream,
                     query_feature, key_feature, key_position, query_position,
                     in_proj_w, in_proj_b, pos_w1, pos_w2, embed_w, ws);
  hipLaunchKernelGGL(bias_kernel, dim3(1000), dim3(256), 0, stream,
                     pos_b1, pos_b2, ws);
  hipLaunchKernelGGL(attn_kernel, dim3(800), dim3(256), 0, stream,
                     query_feature, query_position, key_position,
                     out_proj_w, out_proj_b, embed_b, pos_trans_w,
                     ws, out);
}

// Round 6
// 275.943 us; speedup vs baseline: 1.6173x; 1.0745x over previous
//
#include <hip/hip_runtime.h>
#include <math.h>

typedef __bf16 bf16x8 __attribute__((ext_vector_type(8)));
typedef __bf16 bf16x4 __attribute__((ext_vector_type(4)));
typedef float  f32x4  __attribute__((ext_vector_type(4)));

// N=2, Q=1600, K=100 (pad 112), C=256, h=8, d=32.

// ---- workspace layout (float offsets), total 2,482,976 f32 = 9.93 MB ----
#define WS_KH    0u        // [200][256] f32 k projection                 -> 51200
#define WS_VH    51200u    // [200][256] f32 v projection                 -> 102400
#define WS_EWP   102400u   // [256][260] f32 embed_w padded rows          -> 168960
#define WS_QHB   168960u   // bf16 [3200][256] scaled q projection        -> 578560
#define WS_BIASB 578560u   // bf16 [3200][112][8] rel-pos bias            -> 2012160
#define WS_KEB   2012160u  // bf16 [200][264] key sin/cos table (pad 264) -> 2038560
#define WS_W1B   2038560u  // bf16 [256][256] pos_w1                      -> 2071328
#define WS_W2PB  2071328u  // bf16 [16][256] pos_w2 padded                -> 2073376
#define WS_QEB   2073376u  // bf16 [3200][256] query sin/cos table        -> 2482976

__device__ __forceinline__ float rdlane(float v, int l) {
  return __uint_as_float(__builtin_amdgcn_readlane(__float_as_uint(v), l));
}

__device__ __forceinline__ unsigned packbf(float a, float b) {
  unsigned short ua = __builtin_bit_cast(unsigned short, (__bf16)a);
  unsigned short ub = __builtin_bit_cast(unsigned short, (__bf16)b);
  return (unsigned)ua | ((unsigned)ub << 16);
}

// ---------------------------------------------------------------------------
// prep: keb/qe tables + bf16 casts + embed_w pad + q/k/v projections (fused)
__global__ __launch_bounds__(256, 2) void prep_kernel(
    const float* __restrict__ qfeat, const float* __restrict__ kfeat,
    const float* __restrict__ kpos, const float* __restrict__ qpos,
    const float* __restrict__ ipw, const float* __restrict__ ipb,
    const float* __restrict__ pos_w1, const float* __restrict__ pos_w2,
    const float* __restrict__ embed_w, float* __restrict__ ws)
{
  __shared__ float x[8 * 256];
  int bid = blockIdx.x, t = threadIdx.x;

  if (bid < 50) {
    int r = bid * 4 + (t >> 6);
    int u = t & 63;
    float p0 = kpos[r * 2 + 0], p1 = kpos[r * 2 + 1];
    __bf16* keb = (__bf16*)(ws + WS_KEB);
    bf16x4 o;
#pragma unroll
    for (int j = 0; j < 4; j++) {
      int col = u * 4 + j;
      int c = col >> 7, i = (col & 127) >> 1;
      float p = c ? p1 : p0;
      float inv = exp2f((float)i * (-13.287712379549449f / 64.0f));
      float v = p * inv;
      o[j] = (__bf16)((col & 1) ? __cosf(v) : __sinf(v));
    }
    *(bf16x4*)(keb + r * 264 + u * 4) = o;
  } else if (bid < 114) {
    int idx = (bid - 50) * 1024 + t * 4;
    float4 v = *(const float4*)(pos_w1 + idx);
    bf16x4 o; o[0] = (__bf16)v.x; o[1] = (__bf16)v.y; o[2] = (__bf16)v.z; o[3] = (__bf16)v.w;
    *(bf16x4*)((__bf16*)(ws + WS_W1B) + idx) = o;
  } else if (bid == 114) {
    __bf16* w2pb = (__bf16*)(ws + WS_W2PB);
    for (int i = 0; i < 16; i++) {
      int idx = t * 16 + i;
      w2pb[idx] = (idx < 2048) ? (__bf16)pos_w2[idx] : (__bf16)0.0f;
    }
  } else if (bid < 147) {
    int r0 = (bid - 115) * 8;
    for (int rr = 0; rr < 8; rr++) {
      int r = r0 + rr;
      for (int j = t; j < 260; j += 256)
        ws[WS_EWP + r * 260 + j] = (j < 258) ? embed_w[r * 258 + j] : 0.0f;
    }
  } else if (bid < 547) {
    int r0 = (bid - 147) * 8;
    for (int i = t; i < 2048; i += 256) x[i] = qfeat[(unsigned)r0 * 256u + i];
    __syncthreads();
    float acc[8]; float bq = ipb[t];
#pragma unroll
    for (int rr = 0; rr < 8; rr++) acc[rr] = bq;
    const float* wrow = ipw + (unsigned)t * 256u;
    for (int j = 0; j < 256; j += 4) {
      float4 w4 = *(const float4*)(wrow + j);
#pragma unroll
      for (int rr = 0; rr < 8; rr++) {
        float4 x4 = *(const float4*)(x + rr * 256 + j);
        acc[rr] = fmaf(x4.x, w4.x, fmaf(x4.y, w4.y, fmaf(x4.z, w4.z, fmaf(x4.w, w4.w, acc[rr]))));
      }
    }
    __bf16* qhb = (__bf16*)(ws + WS_QHB);
#pragma unroll
    for (int rr = 0; rr < 8; rr++)
      qhb[(unsigned)(r0 + rr) * 256u + t] = (__bf16)(acc[rr] * 0.17677669529663687f);
  } else if (bid < 579) {
    int b2 = bid - 547; int n = b2 >> 4, tile = b2 & 15;
    int r0l = tile * 7; int cnt = 100 - r0l; if (cnt > 7) cnt = 7; if (cnt <= 0) return;
    int r0 = n * 100 + r0l;
    for (int i = t; i < cnt * 256; i += 256) x[i] = kfeat[(unsigned)r0 * 256u + i];
    __syncthreads();
    float ak[7], av[7]; float bk = ipb[256 + t], bv = ipb[512 + t];
#pragma unroll
    for (int rr = 0; rr < 7; rr++) { ak[rr] = bk; av[rr] = bv; }
    const float* wkr = ipw + (unsigned)(256 + t) * 256u;
    const float* wvr = ipw + (unsigned)(512 + t) * 256u;
    for (int j = 0; j < 256; j += 4) {
      float4 wk4 = *(const float4*)(wkr + j);
      float4 wv4 = *(const float4*)(wvr + j);
#pragma unroll
      for (int rr = 0; rr < 7; rr++) {
        float4 x4 = *(const float4*)(x + rr * 256 + j);
        ak[rr] = fmaf(x4.x, wk4.x, fmaf(x4.y, wk4.y, fmaf(x4.z, wk4.z, fmaf(x4.w, wk4.w, ak[rr]))));
        av[rr] = fmaf(x4.x, wv4.x, fmaf(x4.y, wv4.y, fmaf(x4.z, wv4.z, fmaf(x4.w, wv4.w, av[rr]))));
      }
    }
    for (int rr = 0; rr < 7; rr++) {
      if (rr < cnt) {
        ws[WS_KH + (unsigned)(r0 + rr) * 256u + t] = ak[rr];
        ws[WS_VH + (unsigned)(r0 + rr) * 256u + t] = av[rr];
      }
    }
  } else {
    // qe table: rows 0..3199, 4 rows per block
    int r = (bid - 579) * 4 + (t >> 6);
    int u = t & 63;
    float p0 = qpos[r * 2 + 0], p1 = qpos[r * 2 + 1];
    __bf16* qeb = (__bf16*)(ws + WS_QEB);
    bf16x4 o;
#pragma unroll
    for (int j = 0; j < 4; j++) {
      int col = u * 4 + j;
      int c = col >> 7, i = (col & 127) >> 1;
      float p = c ? p1 : p0;
      float inv = exp2f((float)i * (-13.287712379549449f / 64.0f));
      float v = p * inv;
      o[j] = (__bf16)((col & 1) ? __cosf(v) : __sinf(v));
    }
    *(bf16x4*)(qeb + r * 256 + u * 4) = o;
  }
}

// ---------------------------------------------------------------------------
// bias kernel v9: v8 structure (key-side fold, rot once/block, af resident)
// with the register budget FIXED: __launch_bounds__(256,1) -> 512 unified
// regs/wave. v8 spilled (WRITE_SIZE 151MB scratch) because af[8][4]=128 +
// acc=64 + staging overflowed the 256 budget at 2 waves/SIMD. Peak liveness
// ~260 fits in 512 with headroom -> zero spill. 1 wave/SIMD, 1 block/CU;
// latency hidden by ILP (4 indep nt ds_reads x 8 kc) not TLP.
// Also T14 async-STAGE: next tile's qe global loads issued at TOP of GEMM1
// (~1.5K cyc cover), LDS write after the barrier — with 1 wave/SIMD there is
// no other wave to hide the L2 latency, so placement matters.
// Block = one (n,k) x 320 q (5 tiles of 64), grid 1000, 256 thr / 4 waves.
// LDS: qe 32K + hid 32K + keb 512 = 66048 B.
__global__ __launch_bounds__(256, 1) void bias_kernel(
    const float* __restrict__ pos_b1, const float* __restrict__ pos_b2,
    float* __restrict__ ws)
{
  __shared__ __align__(16) char qe_smem[32768];    // [64 q][512B] swizzled
  __shared__ __align__(16) char hid_smem[32768];   // [64 q][512B] swizzled
  __shared__ __align__(16) __bf16 keb_s[256];

  int bid = blockIdx.x;           // 0..999 = nk(200) x qgroup(5)
  int nk = bid / 5, g = bid - nk * 5;
  int n = nk / 100, k = nk - n * 100;
  int qbase = n * 1600 + g * 320;
  int t = threadIdx.x;
  int lane = t & 63, w = t >> 6;
  int l15 = lane & 15, quad = lane >> 4;

  const __bf16* keb = (const __bf16*)(ws + WS_KEB) + (unsigned)nk * 264u;
  const __bf16* qeb = (const __bf16*)(ws + WS_QEB);
  const __bf16* w1b = (const __bf16*)(ws + WS_W1B);
  const __bf16* w2pb = (const __bf16*)(ws + WS_W2PB);
  __bf16* biasb = (__bf16*)(ws + WS_BIASB);

  if (t < 32) *(bf16x8*)(keb_s + t * 8) = *(const bf16x8*)(keb + t * 8);

  // stage qe tile 0 (XOR swizzle byte ^= (row&7)<<4; r4/r5-validated)
  int sr = t >> 2, ssub = t & 3, sswz = (sr & 7) << 4;
  {
    const __bf16* src = qeb + (unsigned)(qbase + sr) * 256u + ssub * 64;
    char* dst = qe_smem + sr * 512;
#pragma unroll
    for (int u = 0; u < 8; u++) {
      bf16x8 v = *(const bf16x8*)(src + u * 8);
      *(bf16x8*)(dst + ((ssub * 128 + u * 16) ^ sswz)) = v;
    }
  }

  // per-lane constant addressing (r4/r5-validated)
  int xm = (l15 & 7) << 4;
  int colx[8];
#pragma unroll
  for (int kc = 0; kc < 8; kc++) colx[kc] = ((kc * 64 + quad * 16) ^ xm);
  const __bf16* w1p = w1b + (unsigned)(w * 64 + l15) * 256u + quad * 8;

  float b1a[4][4];
#pragma unroll
  for (int ct = 0; ct < 4; ct++)
#pragma unroll
    for (int r = 0; r < 4; r++) b1a[ct][r] = pos_b1[w * 64 + ct * 16 + quad * 4 + r];

  f32x4 zero4; zero4[0] = 0.f; zero4[1] = 0.f; zero4[2] = 0.f; zero4[3] = 0.f;

  __syncthreads();   // keb_s + qe tile0 ready

  // rotate W1 -> af regs, ONCE per block (key-side fold, r4-validated):
  //   PQ[c,2m]   = W1[c,2m+1]*sk - W1[c,2m]*ck
  //   PQ[c,2m+1] = W1[c,2m]*sk   + W1[c,2m+1]*ck
  bf16x8 af[8][4];
#pragma unroll
  for (int kc = 0; kc < 8; kc++) {
    bf16x8 ke8 = *(const bf16x8*)(keb_s + kc * 32 + quad * 8);
#pragma unroll
    for (int ct = 0; ct < 4; ct++) {
      bf16x8 w8 = *(const bf16x8*)(w1p + ct * 4096 + kc * 32);
      bf16x8 a;
#pragma unroll
      for (int p2 = 0; p2 < 4; p2++) {
        float we = (float)w8[2 * p2], wo = (float)w8[2 * p2 + 1];
        float sk = (float)ke8[2 * p2], ck = (float)ke8[2 * p2 + 1];
        a[2 * p2]     = (__bf16)fmaf(wo, sk, -(we * ck));
        a[2 * p2 + 1] = (__bf16)fmaf(we, sk, wo * ck);
      }
      af[kc][ct] = a;
    }
  }

#pragma unroll 1
  for (int tt = 0; tt < 5; tt++) {
    // T14: issue next tile's qe global loads NOW; GEMM1 covers the latency.
    bf16x8 qv[8];
    if (tt < 4) {
      const __bf16* src = qeb + (unsigned)(qbase + (tt + 1) * 64 + sr) * 256u + ssub * 64;
#pragma unroll
      for (int u = 0; u < 8; u++) qv[u] = *(const bf16x8*)(src + u * 8);
    }

    // GEMM1: wave w owns c-rows [64w, 64w+64). 128 MFMA, zero barriers.
    f32x4 acc[4][4];
#pragma unroll
    for (int ct = 0; ct < 4; ct++)
#pragma unroll
      for (int nt = 0; nt < 4; nt++) acc[ct][nt] = zero4;

#pragma unroll
    for (int kc = 0; kc < 8; kc++) {
#pragma unroll
      for (int nt = 0; nt < 4; nt++) {
        bf16x8 qf = *(const bf16x8*)(qe_smem + (nt * 16 + l15) * 512 + colx[kc]);
        acc[0][nt] = __builtin_amdgcn_mfma_f32_16x16x32_bf16(af[kc][0], qf, acc[0][nt], 0, 0, 0);
        acc[1][nt] = __builtin_amdgcn_mfma_f32_16x16x32_bf16(af[kc][1], qf, acc[1][nt], 0, 0, 0);
        acc[2][nt] = __builtin_amdgcn_mfma_f32_16x16x32_bf16(af[kc][2], qf, acc[2][nt], 0, 0, 0);
        acc[3][nt] = __builtin_amdgcn_mfma_f32_16x16x32_bf16(af[kc][3], qf, acc[3][nt], 0, 0, 0);
      }
    }

    // hid = relu(D1 + b1) -> bf16 -> hid_smem (lane: c=64w+ct*16+quad*4+r,
    // q=nt*16+l15; 8B writes, same XOR swizzle keyed on q row)
#pragma unroll
    for (int ct = 0; ct < 4; ct++) {
#pragma unroll
      for (int nt = 0; nt < 4; nt++) {
        int q = nt * 16 + l15;
        unsigned lo = packbf(fmaxf(acc[ct][nt][0] + b1a[ct][0], 0.f),
                             fmaxf(acc[ct][nt][1] + b1a[ct][1], 0.f));
        unsigned hi = packbf(fmaxf(acc[ct][nt][2] + b1a[ct][2], 0.f),
                             fmaxf(acc[ct][nt][3] + b1a[ct][3], 0.f));
        int cbyte = w * 128 + ct * 32 + quad * 8;
        char* p = hid_smem + q * 512 + (cbyte ^ ((q & 7) << 4));
        unsigned long long v = (unsigned long long)lo | ((unsigned long long)hi << 32);
        *(unsigned long long*)p = v;
      }
    }

    // W2 frags for GEMM2 (L2-hot; issued before barrier so latency overlaps)
    bf16x8 w2f[8];
#pragma unroll
    for (int kc = 0; kc < 8; kc++)
      w2f[kc] = *(const bf16x8*)(w2pb + (unsigned)l15 * 256u + kc * 32 + quad * 8);

    __syncthreads();   // hid visible to all; all qe reads complete

    // write staged qe for the next tile (qe_smem free since the barrier)
    if (tt < 4) {
      char* dst = qe_smem + sr * 512;
#pragma unroll
      for (int u = 0; u < 8; u++)
        *(bf16x8*)(dst + ((ssub * 128 + u * 16) ^ sswz)) = qv[u];
    }

    // GEMM2: wave w -> q rows [16w,16w+16). bias = W2pad @ hid + b2.
    {
      int row = w * 16 + l15;
      const char* hbase = hid_smem + row * 512;
      int hxm = (l15 & 7) << 4;
      f32x4 acc2 = zero4;
#pragma unroll
      for (int kc = 0; kc < 8; kc++) {
        bf16x8 hf = *(const bf16x8*)(hbase + ((kc * 64 + quad * 16) ^ hxm));
        acc2 = __builtin_amdgcn_mfma_f32_16x16x32_bf16(w2f[kc], hf, acc2, 0, 0, 0);
      }
      if (quad < 2) {
        int qg = qbase + tt * 64 + row;
        bf16x4 o;
#pragma unroll
        for (int r = 0; r < 4; r++) o[r] = (__bf16)(acc2[r] + pos_b2[quad * 4 + r]);
        *(bf16x4*)(biasb + (unsigned)qg * 896u + (unsigned)k * 8u + quad * 4) = o;
      }
    }

    if (tt < 4) __syncthreads();   // qe writes visible; hid reads done
  }
}

// ---------------------------------------------------------------------------
// attn kernel: per block = 4 queries. scores -> softmax -> ctx/aw -> out_proj
// -> cat_pos -> embed. 256 threads.
__global__ __launch_bounds__(256, 4) void attn_kernel(
    const float* __restrict__ qfeat, const float* __restrict__ qpos,
    const float* __restrict__ kpos,
    const float* __restrict__ out_w, const float* __restrict__ out_b,
    const float* __restrict__ embed_b, const float* __restrict__ ptw,
    const float* __restrict__ ws, float* __restrict__ out)
{
  __shared__ float qh_s[4 * 8 * 36];
  __shared__ float attn_s[4 * 8 * 116];
  __shared__ float ctx_s[4 * 264];
  __shared__ float cat_s[4 * 264];
  __shared__ float aw_s[4 * 104];

  int bid = blockIdx.x;
  int qg0 = bid * 4;
  int n = bid / 400;
  int t = threadIdx.x;

  const __bf16* qhb = (const __bf16*)(ws + WS_QHB);
  const __bf16* biasb = (const __bf16*)(ws + WS_BIASB);
  const float* kh = ws + WS_KH;
  const float* vh = ws + WS_VH;
  const float* ewp = ws + WS_EWP;

  for (int i = t; i < 1024; i += 256) {
    int q = i >> 8, c = i & 255;
    qh_s[(q * 8 + (c >> 5)) * 36 + (c & 31)] = (float)qhb[(unsigned)(qg0 + q) * 256u + c];
  }
  __syncthreads();

  for (int i = 0; i < 4; i++) {
    int p = t + i * 256;
    if (p < 800) {
      int k = p >> 3, h = p & 7;
      const float4* kf = (const float4*)(kh + (unsigned)(n * 100 + k) * 256u + h * 32);
      float4 kv[8];
#pragma unroll
      for (int dd = 0; dd < 8; dd++) kv[dd] = kf[dd];
#pragma unroll
      for (int q = 0; q < 4; q++) {
        const float4* qf = (const float4*)(qh_s + (q * 8 + h) * 36);
        float s = (float)biasb[((unsigned)(qg0 + q) * 112u + k) * 8u + h];
#pragma unroll
        for (int dd = 0; dd < 8; dd++) {
          float4 qv = qf[dd];
          s += kv[dd].x * qv.x + kv[dd].y * qv.y + kv[dd].z * qv.z + kv[dd].w * qv.w;
        }
        attn_s[(q * 8 + h) * 116 + k] = s;
      }
    }
  }
  __syncthreads();

  {
    int q = t >> 6, h = (t >> 3) & 7, j = t & 7;
    float* row = attn_s + (q * 8 + h) * 116;
    float mx = -1e30f;
    for (int k = j; k < 100; k += 8) mx = fmaxf(mx, row[k]);
    mx = fmaxf(mx, __shfl_xor(mx, 1, 8));
    mx = fmaxf(mx, __shfl_xor(mx, 2, 8));
    mx = fmaxf(mx, __shfl_xor(mx, 4, 8));
    float sum = 0.f;
    for (int k = j; k < 100; k += 8) { float e = __expf(row[k] - mx); row[k] = e; sum += e; }
    sum += __shfl_xor(sum, 1, 8);
    sum += __shfl_xor(sum, 2, 8);
    sum += __shfl_xor(sum, 4, 8);
    float inv = 1.0f / sum;
    for (int k = j; k < 100; k += 8) row[k] *= inv;
  }
  __syncthreads();

  for (int p = t; p < 416; p += 256) {
    int q = p / 104, k = p % 104;
    if (k < 100) {
      float s = 0.f;
#pragma unroll
      for (int h = 0; h < 8; h++) s += attn_s[(q * 8 + h) * 116 + k];
      aw_s[q * 104 + k] = s * 0.125f;
    }
  }
  {
    int c = t, h = c >> 5;
    float a0 = 0.f, a1 = 0.f, a2 = 0.f, a3 = 0.f;
    const float* vp = vh + (unsigned)(n * 100) * 256u + c;
    const float* r0 = attn_s + (0 * 8 + h) * 116;
    const float* r1 = attn_s + (1 * 8 + h) * 116;
    const float* r2 = attn_s + (2 * 8 + h) * 116;
    const float* r3 = attn_s + (3 * 8 + h) * 116;
#pragma unroll 4
    for (int k = 0; k < 100; k++) {
      float vv = vp[(unsigned)k * 256u];
      a0 = fmaf(r0[k], vv, a0);
      a1 = fmaf(r1[k], vv, a1);
      a2 = fmaf(r2[k], vv, a2);
      a3 = fmaf(r3[k], vv, a3);
    }
    ctx_s[0 * 264 + c] = a0; ctx_s[1 * 264 + c] = a1;
    ctx_s[2 * 264 + c] = a2; ctx_s[3 * 264 + c] = a3;
  }
  __syncthreads();

  if (t < 8) {
    int q = t >> 1, cd = t & 1;
    float qp = qpos[(qg0 + q) * 2 + cd];
    float s = 0.f;
    for (int k = 0; k < 100; k++)
      s = fmaf(aw_s[q * 104 + k], kpos[(n * 100 + k) * 2 + cd] - qp, s);
    float so = __shfl_xor(s, 1, 2);
    if (cd == 0) cat_s[q * 264 + 256] = ptw[0] * s + ptw[1] * so;
    else         cat_s[q * 264 + 257] = ptw[2] * so + ptw[3] * s;
  }

  {
    int c = t, lane = t & 63;
    float ob = out_b[c];
    float acc0 = ob, acc1 = ob, acc2 = ob, acc3 = ob;
    const float* wr = out_w + (unsigned)c * 256u;
    for (int ch = 0; ch < 4; ch++) {
      float v0 = ctx_s[0 * 264 + ch * 64 + lane];
      float v1 = ctx_s[1 * 264 + ch * 64 + lane];
      float v2 = ctx_s[2 * 264 + ch * 64 + lane];
      float v3 = ctx_s[3 * 264 + ch * 64 + lane];
      const float* wp = wr + ch * 64;
#pragma unroll 4
      for (int j4 = 0; j4 < 16; j4++) {
        float4 w4 = *(const float4*)(wp + j4 * 4);
        int jb = j4 * 4;
        acc0 = fmaf(rdlane(v0, jb + 0), w4.x, acc0);
        acc1 = fmaf(rdlane(v1, jb + 0), w4.x, acc1);
        acc2 = fmaf(rdlane(v2, jb + 0), w4.x, acc2);
        acc3 = fmaf(rdlane(v3, jb + 0), w4.x, acc3);
        acc0 = fmaf(rdlane(v0, jb + 1), w4.y, acc0);
        acc1 = fmaf(rdlane(v1, jb + 1), w4.y, acc1);
        acc2 = fmaf(rdlane(v2, jb + 1), w4.y, acc2);
        acc3 = fmaf(rdlane(v3, jb + 1), w4.y, acc3);
        acc0 = fmaf(rdlane(v0, jb + 2), w4.z, acc0);
        acc1 = fmaf(rdlane(v1, jb + 2), w4.z, acc1);
        acc2 = fmaf(rdlane(v2, jb + 2), w4.z, acc2);
        acc3 = fmaf(rdlane(v3, jb + 2), w4.z, acc3);
        acc0 = fmaf(rdlane(v0, jb + 3), w4.w, acc0);
        acc1 = fmaf(rdlane(v1, jb + 3), w4.w, acc1);
        acc2 = fmaf(rdlane(v2, jb + 3), w4.w, acc2);
        acc3 = fmaf(rdlane(v3, jb + 3), w4.w, acc3);
      }
    }
    cat_s[0 * 264 + c] = fmaxf(qfeat[(unsigned)(qg0 + 0) * 256u + c] + acc0, 0.f);
    cat_s[1 * 264 + c] = fmaxf(qfeat[(unsigned)(qg0 + 1) * 256u + c] + acc1, 0.f);
    cat_s[2 * 264 + c] = fmaxf(qfeat[(unsigned)(qg0 + 2) * 256u + c] + acc2, 0.f);
    cat_s[3 * 264 + c] = fmaxf(qfeat[(unsigned)(qg0 + 3) * 256u + c] + acc3, 0.f);
  }
  __syncthreads();

  {
    int c = t, lane = t & 63;
    float eb = embed_b[c];
    float acc0 = eb, acc1 = eb, acc2 = eb, acc3 = eb;
    const float* er = ewp + (unsigned)c * 260u;
    for (int ch = 0; ch < 4; ch++) {
      float v0 = cat_s[0 * 264 + ch * 64 + lane];
      float v1 = cat_s[1 * 264 + ch * 64 + lane];
      float v2 = cat_s[2 * 264 + ch * 64 + lane];
      float v3 = cat_s[3 * 264 + ch * 64 + lane];
      const float* wp = er + ch * 64;
#pragma unroll 4
      for (int j4 = 0; j4 < 16; j4++) {
        float4 w4 = *(const float4*)(wp + j4 * 4);
        int jb = j4 * 4;
        acc0 = fmaf(rdlane(v0, jb + 0), w4.x, acc0);
        acc1 = fmaf(rdlane(v1, jb + 0), w4.x, acc1);
        acc2 = fmaf(rdlane(v2, jb + 0), w4.x, acc2);
        acc3 = fmaf(rdlane(v3, jb + 0), w4.x, acc3);
        acc0 = fmaf(rdlane(v0, jb + 1), w4.y, acc0);
        acc1 = fmaf(rdlane(v1, jb + 1), w4.y, acc1);
        acc2 = fmaf(rdlane(v2, jb + 1), w4.y, acc2);
        acc3 = fmaf(rdlane(v3, jb + 1), w4.y, acc3);
        acc0 = fmaf(rdlane(v0, jb + 2), w4.z, acc0);
        acc1 = fmaf(rdlane(v1, jb + 2), w4.z, acc1);
        acc2 = fmaf(rdlane(v2, jb + 2), w4.z, acc2);
        acc3 = fmaf(rdlane(v3, jb + 2), w4.z, acc3);
        acc0 = fmaf(rdlane(v0, jb + 3), w4.w, acc0);
        acc1 = fmaf(rdlane(v1, jb + 3), w4.w, acc1);
        acc2 = fmaf(rdlane(v2, jb + 3), w4.w, acc2);
        acc3 = fmaf(rdlane(v3, jb + 3), w4.w, acc3);
      }
    }
    float4 wt = *(const float4*)(er + 256);
    acc0 += cat_s[0 * 264 + 256] * wt.x + cat_s[0 * 264 + 257] * wt.y;
    acc1 += cat_s[1 * 264 + 256] * wt.x + cat_s[1 * 264 + 257] * wt.y;
    acc2 += cat_s[2 * 264 + 256] * wt.x + cat_s[2 * 264 + 257] * wt.y;
    acc3 += cat_s[3 * 264 + 256] * wt.x + cat_s[3 * 264 + 257] * wt.y;
    out[(unsigned)(qg0 + 0) * 256u + c] = fmaxf(acc0, 0.f);
    out[(unsigned)(qg0 + 1) * 256u + c] = fmaxf(acc1, 0.f);
    out[(unsigned)(qg0 + 2) * 256u + c] = fmaxf(acc2, 0.f);
    out[(unsigned)(qg0 + 3) * 256u + c] = fmaxf(acc3, 0.f);
  }
}

// ---------------------------------------------------------------------------
extern "C" void kernel_launch(void* const* d_in, const int* in_sizes, int n_in,
                              void* d_out, int out_size, void* d_ws, size_t ws_size,
                              hipStream_t stream)
{
  const float* query_feature  = (const float*)d_in[0];
  const float* query_position = (const float*)d_in[1];
  const float* key_feature    = (const float*)d_in[2];
  const float* key_position   = (const float*)d_in[3];
  const float* in_proj_w      = (const float*)d_in[4];
  const float* in_proj_b      = (const float*)d_in[5];
  const float* out_proj_w     = (const float*)d_in[6];
  const float* out_proj_b     = (const float*)d_in[7];
  const float* pos_w1         = (const float*)d_in[8];
  const float* pos_b1         = (const float*)d_in[9];
  const float* pos_w2         = (const float*)d_in[10];
  const float* pos_b2         = (const float*)d_in[11];
  const float* pos_trans_w    = (const float*)d_in[12];
  const float* embed_w        = (const float*)d_in[13];
  const float* embed_b        = (const float*)d_in[14];
  float* ws  = (float*)d_ws;
  float* out = (float*)d_out;

  hipLaunchKernelGGL(prep_kernel, dim3(1379), dim3(256), 0, stream,
                     query_feature, key_feature, key_position, query_position,
                     in_proj_w, in_proj_b, pos_w1, pos_w2, embed_w, ws);
  hipLaunchKernelGGL(bias_kernel, dim3(1000), dim3(256), 0, stream,
                     pos_b1, pos_b2, ws);
  hipLaunchKernelGGL(attn_kernel, dim3(800), dim3(256), 0, stream,
                     query_feature, query_position, key_position,
                     out_proj_w, out_proj_b, embed_b, pos_trans_w,
                     ws, out);
}

// Round 7
// 275.551 us; speedup vs baseline: 1.6196x; 1.0014x over previous
//
#include <hip/hip_runtime.h>
#include <math.h>

typedef __bf16 bf16x8 __attribute__((ext_vector_type(8)));
typedef __bf16 bf16x4 __attribute__((ext_vector_type(4)));
typedef float  f32x4  __attribute__((ext_vector_type(4)));

// N=2, Q=1600, K=100 (pad 112), C=256, h=8, d=32.

// ---- workspace layout (float offsets), total 2,482,976 f32 = 9.93 MB ----
#define WS_KH    0u        // [200][256] f32 k projection                 -> 51200
#define WS_VH    51200u    // [200][256] f32 v projection                 -> 102400
#define WS_EWP   102400u   // [256][260] f32 embed_w padded rows          -> 168960
#define WS_QHB   168960u   // bf16 [3200][256] scaled q projection        -> 578560
#define WS_BIASB 578560u   // bf16 [3200][112][8] rel-pos bias            -> 2012160
#define WS_KEB   2012160u  // bf16 [200][264] key sin/cos table (pad 264) -> 2038560
#define WS_W1B   2038560u  // bf16 [256][256] pos_w1                      -> 2071328
#define WS_W2PB  2071328u  // bf16 [16][256] pos_w2 padded                -> 2073376
#define WS_QEB   2073376u  // bf16 [3200][256] query sin/cos table        -> 2482976

__device__ __forceinline__ float rdlane(float v, int l) {
  return __uint_as_float(__builtin_amdgcn_readlane(__float_as_uint(v), l));
}

__device__ __forceinline__ unsigned packbf(float a, float b) {
  unsigned short ua = __builtin_bit_cast(unsigned short, (__bf16)a);
  unsigned short ub = __builtin_bit_cast(unsigned short, (__bf16)b);
  return (unsigned)ua | ((unsigned)ub << 16);
}

// ---------------------------------------------------------------------------
// prep: keb/qe tables + bf16 casts + embed_w pad + q/k/v projections (fused)
__global__ __launch_bounds__(256, 2) void prep_kernel(
    const float* __restrict__ qfeat, const float* __restrict__ kfeat,
    const float* __restrict__ kpos, const float* __restrict__ qpos,
    const float* __restrict__ ipw, const float* __restrict__ ipb,
    const float* __restrict__ pos_w1, const float* __restrict__ pos_w2,
    const float* __restrict__ embed_w, float* __restrict__ ws)
{
  __shared__ float x[8 * 256];
  int bid = blockIdx.x, t = threadIdx.x;

  if (bid < 50) {
    int r = bid * 4 + (t >> 6);
    int u = t & 63;
    float p0 = kpos[r * 2 + 0], p1 = kpos[r * 2 + 1];
    __bf16* keb = (__bf16*)(ws + WS_KEB);
    bf16x4 o;
#pragma unroll
    for (int j = 0; j < 4; j++) {
      int col = u * 4 + j;
      int c = col >> 7, i = (col & 127) >> 1;
      float p = c ? p1 : p0;
      float inv = exp2f((float)i * (-13.287712379549449f / 64.0f));
      float v = p * inv;
      o[j] = (__bf16)((col & 1) ? __cosf(v) : __sinf(v));
    }
    *(bf16x4*)(keb + r * 264 + u * 4) = o;
  } else if (bid < 114) {
    int idx = (bid - 50) * 1024 + t * 4;
    float4 v = *(const float4*)(pos_w1 + idx);
    bf16x4 o; o[0] = (__bf16)v.x; o[1] = (__bf16)v.y; o[2] = (__bf16)v.z; o[3] = (__bf16)v.w;
    *(bf16x4*)((__bf16*)(ws + WS_W1B) + idx) = o;
  } else if (bid == 114) {
    __bf16* w2pb = (__bf16*)(ws + WS_W2PB);
    for (int i = 0; i < 16; i++) {
      int idx = t * 16 + i;
      w2pb[idx] = (idx < 2048) ? (__bf16)pos_w2[idx] : (__bf16)0.0f;
    }
  } else if (bid < 147) {
    int r0 = (bid - 115) * 8;
    for (int rr = 0; rr < 8; rr++) {
      int r = r0 + rr;
      for (int j = t; j < 260; j += 256)
        ws[WS_EWP + r * 260 + j] = (j < 258) ? embed_w[r * 258 + j] : 0.0f;
    }
  } else if (bid < 547) {
    int r0 = (bid - 147) * 8;
    for (int i = t; i < 2048; i += 256) x[i] = qfeat[(unsigned)r0 * 256u + i];
    __syncthreads();
    float acc[8]; float bq = ipb[t];
#pragma unroll
    for (int rr = 0; rr < 8; rr++) acc[rr] = bq;
    const float* wrow = ipw + (unsigned)t * 256u;
    for (int j = 0; j < 256; j += 4) {
      float4 w4 = *(const float4*)(wrow + j);
#pragma unroll
      for (int rr = 0; rr < 8; rr++) {
        float4 x4 = *(const float4*)(x + rr * 256 + j);
        acc[rr] = fmaf(x4.x, w4.x, fmaf(x4.y, w4.y, fmaf(x4.z, w4.z, fmaf(x4.w, w4.w, acc[rr]))));
      }
    }
    __bf16* qhb = (__bf16*)(ws + WS_QHB);
#pragma unroll
    for (int rr = 0; rr < 8; rr++)
      qhb[(unsigned)(r0 + rr) * 256u + t] = (__bf16)(acc[rr] * 0.17677669529663687f);
  } else if (bid < 579) {
    int b2 = bid - 547; int n = b2 >> 4, tile = b2 & 15;
    int r0l = tile * 7; int cnt = 100 - r0l; if (cnt > 7) cnt = 7; if (cnt <= 0) return;
    int r0 = n * 100 + r0l;
    for (int i = t; i < cnt * 256; i += 256) x[i] = kfeat[(unsigned)r0 * 256u + i];
    __syncthreads();
    float ak[7], av[7]; float bk = ipb[256 + t], bv = ipb[512 + t];
#pragma unroll
    for (int rr = 0; rr < 7; rr++) { ak[rr] = bk; av[rr] = bv; }
    const float* wkr = ipw + (unsigned)(256 + t) * 256u;
    const float* wvr = ipw + (unsigned)(512 + t) * 256u;
    for (int j = 0; j < 256; j += 4) {
      float4 wk4 = *(const float4*)(wkr + j);
      float4 wv4 = *(const float4*)(wvr + j);
#pragma unroll
      for (int rr = 0; rr < 7; rr++) {
        float4 x4 = *(const float4*)(x + rr * 256 + j);
        ak[rr] = fmaf(x4.x, wk4.x, fmaf(x4.y, wk4.y, fmaf(x4.z, wk4.z, fmaf(x4.w, wk4.w, ak[rr]))));
        av[rr] = fmaf(x4.x, wv4.x, fmaf(x4.y, wv4.y, fmaf(x4.z, wv4.z, fmaf(x4.w, wv4.w, av[rr]))));
      }
    }
    for (int rr = 0; rr < 7; rr++) {
      if (rr < cnt) {
        ws[WS_KH + (unsigned)(r0 + rr) * 256u + t] = ak[rr];
        ws[WS_VH + (unsigned)(r0 + rr) * 256u + t] = av[rr];
      }
    }
  } else {
    // qe table: rows 0..3199, 4 rows per block
    int r = (bid - 579) * 4 + (t >> 6);
    int u = t & 63;
    float p0 = qpos[r * 2 + 0], p1 = qpos[r * 2 + 1];
    __bf16* qeb = (__bf16*)(ws + WS_QEB);
    bf16x4 o;
#pragma unroll
    for (int j = 0; j < 4; j++) {
      int col = u * 4 + j;
      int c = col >> 7, i = (col & 127) >> 1;
      float p = c ? p1 : p0;
      float inv = exp2f((float)i * (-13.287712379549449f / 64.0f));
      float v = p * inv;
      o[j] = (__bf16)((col & 1) ? __cosf(v) : __sinf(v));
    }
    *(bf16x4*)(qeb + r * 256 + u * 4) = o;
  }
}

// ---------------------------------------------------------------------------
// bias kernel v10: v9 math (key-side fold, rot once/block, af resident) with
// the latency-exposure FIXED: 512 thr / 8 waves. v9 at 1 wave/SIMD measured
// 100us vs ~6us of component work — pure exposed latency. Wave (wc=w&3,
// wq=w>>2): c-rows [64wc,64wc+64) (ct=4, so af[8][4]=128 regs and each LDS
// B-read still feeds 4 MFMAs — per-CU LDS traffic unchanged), q-half
// [32wq,32wq+32) (nt=2, acc 32 regs). Peak liveness ~220 < 256 ->
// launch_bounds(512,2) = 2 waves/SIMD (r1 lesson respected: budget 256, not
// 128). Rot duplicated 2x across wq (once/block, amortized over 5 tiles).
// Per tile: GEMM1 64 MFMA/wave barrier-free -> hid pack -> barrier ->
// all threads land prefetched qe + wq==0 waves run GEMM2 -> barrier.
// LDS: qe 32K + hid 32K + keb 512 = 66048 B. Grid 1000 (nk x 5 qgroups).
__global__ __launch_bounds__(512, 2) void bias_kernel(
    const float* __restrict__ pos_b1, const float* __restrict__ pos_b2,
    float* __restrict__ ws)
{
  __shared__ __align__(16) char qe_smem[32768];    // [64 q][512B] swizzled
  __shared__ __align__(16) char hid_smem[32768];   // [64 q][512B] swizzled
  __shared__ __align__(16) __bf16 keb_s[256];

  int bid = blockIdx.x;           // 0..999 = nk(200) x qgroup(5)
  int nk = bid / 5, g = bid - nk * 5;
  int n = nk / 100, k = nk - n * 100;
  int qbase = n * 1600 + g * 320;
  int t = threadIdx.x;
  int lane = t & 63, w = t >> 6;        // w 0..7
  int wc = w & 3, wq = w >> 2;          // c-quadrant, q-half
  int l15 = lane & 15, quad = lane >> 4;

  const __bf16* keb = (const __bf16*)(ws + WS_KEB) + (unsigned)nk * 264u;
  const __bf16* qeb = (const __bf16*)(ws + WS_QEB);
  const __bf16* w1b = (const __bf16*)(ws + WS_W1B);
  const __bf16* w2pb = (const __bf16*)(ws + WS_W2PB);
  __bf16* biasb = (__bf16*)(ws + WS_BIASB);

  if (t < 32) *(bf16x8*)(keb_s + t * 8) = *(const bf16x8*)(keb + t * 8);

  // stage qe tile 0: 512 thr, 64B each. sr=row, ssub=64B column chunk.
  int sr = t >> 3, ssub = t & 7, sswz = (sr & 7) << 4;
  {
    const __bf16* src = qeb + (unsigned)(qbase + sr) * 256u + ssub * 32;
    char* dst = qe_smem + sr * 512;
#pragma unroll
    for (int u = 0; u < 4; u++) {
      bf16x8 v = *(const bf16x8*)(src + u * 8);
      *(bf16x8*)(dst + ((ssub * 64 + u * 16) ^ sswz)) = v;
    }
  }

  // per-lane constant addressing (r4/r5/r6-validated swizzle pattern)
  int xm = (l15 & 7) << 4;
  int colx[8];
#pragma unroll
  for (int kc = 0; kc < 8; kc++) colx[kc] = ((kc * 64 + quad * 16) ^ xm);
  const __bf16* w1p = w1b + (unsigned)(wc * 64 + l15) * 256u + quad * 8;

  float b1a[4][4];
#pragma unroll
  for (int ct = 0; ct < 4; ct++)
#pragma unroll
    for (int r = 0; r < 4; r++) b1a[ct][r] = pos_b1[wc * 64 + ct * 16 + quad * 4 + r];

  f32x4 zero4; zero4[0] = 0.f; zero4[1] = 0.f; zero4[2] = 0.f; zero4[3] = 0.f;

  __syncthreads();   // keb_s + qe tile0 ready

  // rotate W1 -> af regs, ONCE per block (key-side fold, r4-validated):
  //   PQ[c,2m]   = W1[c,2m+1]*sk - W1[c,2m]*ck
  //   PQ[c,2m+1] = W1[c,2m]*sk   + W1[c,2m+1]*ck
  // (duplicated across the two wq halves — 2x VALU, paid once per block)
  bf16x8 af[8][4];
#pragma unroll
  for (int kc = 0; kc < 8; kc++) {
    bf16x8 ke8 = *(const bf16x8*)(keb_s + kc * 32 + quad * 8);
#pragma unroll
    for (int ct = 0; ct < 4; ct++) {
      bf16x8 w8 = *(const bf16x8*)(w1p + ct * 4096 + kc * 32);
      bf16x8 a;
#pragma unroll
      for (int p2 = 0; p2 < 4; p2++) {
        float we = (float)w8[2 * p2], wo = (float)w8[2 * p2 + 1];
        float sk = (float)ke8[2 * p2], ck = (float)ke8[2 * p2 + 1];
        a[2 * p2]     = (__bf16)fmaf(wo, sk, -(we * ck));
        a[2 * p2 + 1] = (__bf16)fmaf(we, sk, wo * ck);
      }
      af[kc][ct] = a;
    }
  }

#pragma unroll 1
  for (int tt = 0; tt < 5; tt++) {
    // T14: issue next tile's qe global loads NOW; GEMM1 covers the latency.
    bf16x8 qv[4];
    if (tt < 4) {
      const __bf16* src = qeb + (unsigned)(qbase + (tt + 1) * 64 + sr) * 256u + ssub * 32;
#pragma unroll
      for (int u = 0; u < 4; u++) qv[u] = *(const bf16x8*)(src + u * 8);
    }

    // GEMM1: wave (wc,wq) -> c [64wc,64wc+64) x q [32wq,32wq+32).
    // 64 MFMA/wave, zero barriers.
    f32x4 acc[4][2];
#pragma unroll
    for (int ct = 0; ct < 4; ct++)
#pragma unroll
      for (int nt = 0; nt < 2; nt++) acc[ct][nt] = zero4;

#pragma unroll
    for (int kc = 0; kc < 8; kc++) {
#pragma unroll
      for (int nt = 0; nt < 2; nt++) {
        int row = wq * 32 + nt * 16 + l15;
        bf16x8 qf = *(const bf16x8*)(qe_smem + row * 512 + colx[kc]);
        acc[0][nt] = __builtin_amdgcn_mfma_f32_16x16x32_bf16(af[kc][0], qf, acc[0][nt], 0, 0, 0);
        acc[1][nt] = __builtin_amdgcn_mfma_f32_16x16x32_bf16(af[kc][1], qf, acc[1][nt], 0, 0, 0);
        acc[2][nt] = __builtin_amdgcn_mfma_f32_16x16x32_bf16(af[kc][2], qf, acc[2][nt], 0, 0, 0);
        acc[3][nt] = __builtin_amdgcn_mfma_f32_16x16x32_bf16(af[kc][3], qf, acc[3][nt], 0, 0, 0);
      }
    }

    // hid = relu(D1 + b1) -> bf16 -> hid_smem (lane: c=64wc+ct*16+quad*4+r,
    // q=32wq+nt*16+l15; 8B writes, same XOR swizzle keyed on q row)
#pragma unroll
    for (int ct = 0; ct < 4; ct++) {
#pragma unroll
      for (int nt = 0; nt < 2; nt++) {
        int q = wq * 32 + nt * 16 + l15;
        unsigned lo = packbf(fmaxf(acc[ct][nt][0] + b1a[ct][0], 0.f),
                             fmaxf(acc[ct][nt][1] + b1a[ct][1], 0.f));
        unsigned hi = packbf(fmaxf(acc[ct][nt][2] + b1a[ct][2], 0.f),
                             fmaxf(acc[ct][nt][3] + b1a[ct][3], 0.f));
        int cbyte = wc * 128 + ct * 32 + quad * 8;
        char* p = hid_smem + q * 512 + (cbyte ^ ((q & 7) << 4));
        unsigned long long v = (unsigned long long)lo | ((unsigned long long)hi << 32);
        *(unsigned long long*)p = v;
      }
    }

    __syncthreads();   // hid visible to all; all qe reads complete

    // land prefetched qe for next tile (all threads; qe_smem free now)
    if (tt < 4) {
      char* dst = qe_smem + sr * 512;
#pragma unroll
      for (int u = 0; u < 4; u++)
        *(bf16x8*)(dst + ((ssub * 64 + u * 16) ^ sswz)) = qv[u];
    }

    // GEMM2 on the wq==0 waves (wc spans all 64 q rows): bias = W2pad@hid+b2.
    if (wq == 0) {
      bf16x8 w2f[8];
#pragma unroll
      for (int kc = 0; kc < 8; kc++)
        w2f[kc] = *(const bf16x8*)(w2pb + (unsigned)l15 * 256u + kc * 32 + quad * 8);
      int row = wc * 16 + l15;
      const char* hbase = hid_smem + row * 512;
      int hxm = (l15 & 7) << 4;
      f32x4 acc2 = zero4;
#pragma unroll
      for (int kc = 0; kc < 8; kc++) {
        bf16x8 hf = *(const bf16x8*)(hbase + ((kc * 64 + quad * 16) ^ hxm));
        acc2 = __builtin_amdgcn_mfma_f32_16x16x32_bf16(w2f[kc], hf, acc2, 0, 0, 0);
      }
      if (quad < 2) {
        int qg = qbase + tt * 64 + row;
        bf16x4 o;
#pragma unroll
        for (int r = 0; r < 4; r++) o[r] = (__bf16)(acc2[r] + pos_b2[quad * 4 + r]);
        *(bf16x4*)(biasb + (unsigned)qg * 896u + (unsigned)k * 8u + quad * 4) = o;
      }
    }

    if (tt < 4) __syncthreads();   // qe writes visible; hid reads done
  }
}

// ---------------------------------------------------------------------------
// attn kernel: per block = 4 queries. scores -> softmax -> ctx/aw -> out_proj
// -> cat_pos -> embed. 256 threads.
__global__ __launch_bounds__(256, 4) void attn_kernel(
    const float* __restrict__ qfeat, const float* __restrict__ qpos,
    const float* __restrict__ kpos,
    const float* __restrict__ out_w, const float* __restrict__ out_b,
    const float* __restrict__ embed_b, const float* __restrict__ ptw,
    const float* __restrict__ ws, float* __restrict__ out)
{
  __shared__ float qh_s[4 * 8 * 36];
  __shared__ float attn_s[4 * 8 * 116];
  __shared__ float ctx_s[4 * 264];
  __shared__ float cat_s[4 * 264];
  __shared__ float aw_s[4 * 104];

  int bid = blockIdx.x;
  int qg0 = bid * 4;
  int n = bid / 400;
  int t = threadIdx.x;

  const __bf16* qhb = (const __bf16*)(ws + WS_QHB);
  const __bf16* biasb = (const __bf16*)(ws + WS_BIASB);
  const float* kh = ws + WS_KH;
  const float* vh = ws + WS_VH;
  const float* ewp = ws + WS_EWP;

  for (int i = t; i < 1024; i += 256) {
    int q = i >> 8, c = i & 255;
    qh_s[(q * 8 + (c >> 5)) * 36 + (c & 31)] = (float)qhb[(unsigned)(qg0 + q) * 256u + c];
  }
  __syncthreads();

  for (int i = 0; i < 4; i++) {
    int p = t + i * 256;
    if (p < 800) {
      int k = p >> 3, h = p & 7;
      const float4* kf = (const float4*)(kh + (unsigned)(n * 100 + k) * 256u + h * 32);
      float4 kv[8];
#pragma unroll
      for (int dd = 0; dd < 8; dd++) kv[dd] = kf[dd];
#pragma unroll
      for (int q = 0; q < 4; q++) {
        const float4* qf = (const float4*)(qh_s + (q * 8 + h) * 36);
        float s = (float)biasb[((unsigned)(qg0 + q) * 112u + k) * 8u + h];
#pragma unroll
        for (int dd = 0; dd < 8; dd++) {
          float4 qv = qf[dd];
          s += kv[dd].x * qv.x + kv[dd].y * qv.y + kv[dd].z * qv.z + kv[dd].w * qv.w;
        }
        attn_s[(q * 8 + h) * 116 + k] = s;
      }
    }
  }
  __syncthreads();

  {
    int q = t >> 6, h = (t >> 3) & 7, j = t & 7;
    float* row = attn_s + (q * 8 + h) * 116;
    float mx = -1e30f;
    for (int k = j; k < 100; k += 8) mx = fmaxf(mx, row[k]);
    mx = fmaxf(mx, __shfl_xor(mx, 1, 8));
    mx = fmaxf(mx, __shfl_xor(mx, 2, 8));
    mx = fmaxf(mx, __shfl_xor(mx, 4, 8));
    float sum = 0.f;
    for (int k = j; k < 100; k += 8) { float e = __expf(row[k] - mx); row[k] = e; sum += e; }
    sum += __shfl_xor(sum, 1, 8);
    sum += __shfl_xor(sum, 2, 8);
    sum += __shfl_xor(sum, 4, 8);
    float inv = 1.0f / sum;
    for (int k = j; k < 100; k += 8) row[k] *= inv;
  }
  __syncthreads();

  for (int p = t; p < 416; p += 256) {
    int q = p / 104, k = p % 104;
    if (k < 100) {
      float s = 0.f;
#pragma unroll
      for (int h = 0; h < 8; h++) s += attn_s[(q * 8 + h) * 116 + k];
      aw_s[q * 104 + k] = s * 0.125f;
    }
  }
  {
    int c = t, h = c >> 5;
    float a0 = 0.f, a1 = 0.f, a2 = 0.f, a3 = 0.f;
    const float* vp = vh + (unsigned)(n * 100) * 256u + c;
    const float* r0 = attn_s + (0 * 8 + h) * 116;
    const float* r1 = attn_s + (1 * 8 + h) * 116;
    const float* r2 = attn_s + (2 * 8 + h) * 116;
    const float* r3 = attn_s + (3 * 8 + h) * 116;
#pragma unroll 4
    for (int k = 0; k < 100; k++) {
      float vv = vp[(unsigned)k * 256u];
      a0 = fmaf(r0[k], vv, a0);
      a1 = fmaf(r1[k], vv, a1);
      a2 = fmaf(r2[k], vv, a2);
      a3 = fmaf(r3[k], vv, a3);
    }
    ctx_s[0 * 264 + c] = a0; ctx_s[1 * 264 + c] = a1;
    ctx_s[2 * 264 + c] = a2; ctx_s[3 * 264 + c] = a3;
  }
  __syncthreads();

  if (t < 8) {
    int q = t >> 1, cd = t & 1;
    float qp = qpos[(qg0 + q) * 2 + cd];
    float s = 0.f;
    for (int k = 0; k < 100; k++)
      s = fmaf(aw_s[q * 104 + k], kpos[(n * 100 + k) * 2 + cd] - qp, s);
    float so = __shfl_xor(s, 1, 2);
    if (cd == 0) cat_s[q * 264 + 256] = ptw[0] * s + ptw[1] * so;
    else         cat_s[q * 264 + 257] = ptw[2] * so + ptw[3] * s;
  }

  {
    int c = t, lane = t & 63;
    float ob = out_b[c];
    float acc0 = ob, acc1 = ob, acc2 = ob, acc3 = ob;
    const float* wr = out_w + (unsigned)c * 256u;
    for (int ch = 0; ch < 4; ch++) {
      float v0 = ctx_s[0 * 264 + ch * 64 + lane];
      float v1 = ctx_s[1 * 264 + ch * 64 + lane];
      float v2 = ctx_s[2 * 264 + ch * 64 + lane];
      float v3 = ctx_s[3 * 264 + ch * 64 + lane];
      const float* wp = wr + ch * 64;
#pragma unroll 4
      for (int j4 = 0; j4 < 16; j4++) {
        float4 w4 = *(const float4*)(wp + j4 * 4);
        int jb = j4 * 4;
        acc0 = fmaf(rdlane(v0, jb + 0), w4.x, acc0);
        acc1 = fmaf(rdlane(v1, jb + 0), w4.x, acc1);
        acc2 = fmaf(rdlane(v2, jb + 0), w4.x, acc2);
        acc3 = fmaf(rdlane(v3, jb + 0), w4.x, acc3);
        acc0 = fmaf(rdlane(v0, jb + 1), w4.y, acc0);
        acc1 = fmaf(rdlane(v1, jb + 1), w4.y, acc1);
        acc2 = fmaf(rdlane(v2, jb + 1), w4.y, acc2);
        acc3 = fmaf(rdlane(v3, jb + 1), w4.y, acc3);
        acc0 = fmaf(rdlane(v0, jb + 2), w4.z, acc0);
        acc1 = fmaf(rdlane(v1, jb + 2), w4.z, acc1);
        acc2 = fmaf(rdlane(v2, jb + 2), w4.z, acc2);
        acc3 = fmaf(rdlane(v3, jb + 2), w4.z, acc3);
        acc0 = fmaf(rdlane(v0, jb + 3), w4.w, acc0);
        acc1 = fmaf(rdlane(v1, jb + 3), w4.w, acc1);
        acc2 = fmaf(rdlane(v2, jb + 3), w4.w, acc2);
        acc3 = fmaf(rdlane(v3, jb + 3), w4.w, acc3);
      }
    }
    cat_s[0 * 264 + c] = fmaxf(qfeat[(unsigned)(qg0 + 0) * 256u + c] + acc0, 0.f);
    cat_s[1 * 264 + c] = fmaxf(qfeat[(unsigned)(qg0 + 1) * 256u + c] + acc1, 0.f);
    cat_s[2 * 264 + c] = fmaxf(qfeat[(unsigned)(qg0 + 2) * 256u + c] + acc2, 0.f);
    cat_s[3 * 264 + c] = fmaxf(qfeat[(unsigned)(qg0 + 3) * 256u + c] + acc3, 0.f);
  }
  __syncthreads();

  {
    int c = t, lane = t & 63;
    float eb = embed_b[c];
    float acc0 = eb, acc1 = eb, acc2 = eb, acc3 = eb;
    const float* er = ewp + (unsigned)c * 260u;
    for (int ch = 0; ch < 4; ch++) {
      float v0 = cat_s[0 * 264 + ch * 64 + lane];
      float v1 = cat_s[1 * 264 + ch * 64 + lane];
      float v2 = cat_s[2 * 264 + ch * 64 + lane];
      float v3 = cat_s[3 * 264 + ch * 64 + lane];
      const float* wp = er + ch * 64;
#pragma unroll 4
      for (int j4 = 0; j4 < 16; j4++) {
        float4 w4 = *(const float4*)(wp + j4 * 4);
        int jb = j4 * 4;
        acc0 = fmaf(rdlane(v0, jb + 0), w4.x, acc0);
        acc1 = fmaf(rdlane(v1, jb + 0), w4.x, acc1);
        acc2 = fmaf(rdlane(v2, jb + 0), w4.x, acc2);
        acc3 = fmaf(rdlane(v3, jb + 0), w4.x, acc3);
        acc0 = fmaf(rdlane(v0, jb + 1), w4.y, acc0);
        acc1 = fmaf(rdlane(v1, jb + 1), w4.y, acc1);
        acc2 = fmaf(rdlane(v2, jb + 1), w4.y, acc2);
        acc3 = fmaf(rdlane(v3, jb + 1), w4.y, acc3);
        acc0 = fmaf(rdlane(v0, jb + 2), w4.z, acc0);
        acc1 = fmaf(rdlane(v1, jb + 2), w4.z, acc1);
        acc2 = fmaf(rdlane(v2, jb + 2), w4.z, acc2);
        acc3 = fmaf(rdlane(v3, jb + 2), w4.z, acc3);
        acc0 = fmaf(rdlane(v0, jb + 3), w4.w, acc0);
        acc1 = fmaf(rdlane(v1, jb + 3), w4.w, acc1);
        acc2 = fmaf(rdlane(v2, jb + 3), w4.w, acc2);
        acc3 = fmaf(rdlane(v3, jb + 3), w4.w, acc3);
      }
    }
    float4 wt = *(const float4*)(er + 256);
    acc0 += cat_s[0 * 264 + 256] * wt.x + cat_s[0 * 264 + 257] * wt.y;
    acc1 += cat_s[1 * 264 + 256] * wt.x + cat_s[1 * 264 + 257] * wt.y;
    acc2 += cat_s[2 * 264 + 256] * wt.x + cat_s[2 * 264 + 257] * wt.y;
    acc3 += cat_s[3 * 264 + 256] * wt.x + cat_s[3 * 264 + 257] * wt.y;
    out[(unsigned)(qg0 + 0) * 256u + c] = fmaxf(acc0, 0.f);
    out[(unsigned)(qg0 + 1) * 256u + c] = fmaxf(acc1, 0.f);
    out[(unsigned)(qg0 + 2) * 256u + c] = fmaxf(acc2, 0.f);
    out[(unsigned)(qg0 + 3) * 256u + c] = fmaxf(acc3, 0.f);
  }
}

// ---------------------------------------------------------------------------
extern "C" void kernel_launch(void* const* d_in, const int* in_sizes, int n_in,
                              void* d_out, int out_size, void* d_ws, size_t ws_size,
                              hipStream_t stream)
{
  const float* query_feature  = (const float*)d_in[0];
  const float* query_position = (const float*)d_in[1];
  const float* key_feature    = (const float*)d_in[2];
  const float* key_position   = (const float*)d_in[3];
  const float* in_proj_w      = (const float*)d_in[4];
  const float* in_proj_b      = (const float*)d_in[5];
  const float* out_proj_w     = (const float*)d_in[6];
  const float* out_proj_b     = (const float*)d_in[7];
  const float* pos_w1         = (const float*)d_in[8];
  const float* pos_b1         = (const float*)d_in[9];
  const float* pos_w2         = (const float*)d_in[10];
  const float* pos_b2         = (const float*)d_in[11];
  const float* pos_trans_w    = (const float*)d_in[12];
  const float* embed_w        = (const float*)d_in[13];
  const float* embed_b        = (const float*)d_in[14];
  float* ws  = (float*)d_ws;
  float* out = (float*)d_out;

  hipLaunchKernelGGL(prep_kernel, dim3(1379), dim3(256), 0, stream,
                     query_feature, key_feature, key_position, query_position,
                     in_proj_w, in_proj_b, pos_w1, pos_w2, embed_w, ws);
  hipLaunchKernelGGL(bias_kernel, dim3(1000), dim3(512), 0, stream,
                     pos_b1, pos_b2, ws);
  hipLaunchKernelGGL(attn_kernel, dim3(800), dim3(256), 0, stream,
                     query_feature, query_position, key_position,
                     out_proj_w, out_proj_b, embed_b, pos_trans_w,
                     ws, out);
}

// Round 8
// 271.319 us; speedup vs baseline: 1.6449x; 1.0156x over previous
//
#include <hip/hip_runtime.h>
#include <math.h>

typedef __bf16 bf16x8 __attribute__((ext_vector_type(8)));
typedef __bf16 bf16x4 __attribute__((ext_vector_type(4)));
typedef float  f32x4  __attribute__((ext_vector_type(4)));

// N=2, Q=1600, K=100 (pad 112), C=256, h=8, d=32.

// ---- workspace layout (float offsets), total 2,482,976 f32 = 9.93 MB ----
#define WS_KH    0u        // [200][256] f32 k projection                 -> 51200
#define WS_VH    51200u    // [200][256] f32 v projection                 -> 102400
#define WS_EWP   102400u   // [256][260] f32 embed_w padded rows          -> 168960
#define WS_QHB   168960u   // bf16 [3200][256] scaled q projection        -> 578560
#define WS_BIASB 578560u   // bf16 [3200][112][8] rel-pos bias            -> 2012160
#define WS_KEB   2012160u  // bf16 [200][264] key sin/cos table (pad 264) -> 2038560
#define WS_W1B   2038560u  // bf16 [256][256] pos_w1                      -> 2071328
#define WS_W2PB  2071328u  // bf16 [16][256] pos_w2 padded                -> 2073376
#define WS_QEB   2073376u  // bf16 [3200][256] query sin/cos table        -> 2482976

__device__ __forceinline__ float rdlane(float v, int l) {
  return __uint_as_float(__builtin_amdgcn_readlane(__float_as_uint(v), l));
}

__device__ __forceinline__ unsigned packbf(float a, float b) {
  unsigned short ua = __builtin_bit_cast(unsigned short, (__bf16)a);
  unsigned short ub = __builtin_bit_cast(unsigned short, (__bf16)b);
  return (unsigned)ua | ((unsigned)ub << 16);
}

// ---------------------------------------------------------------------------
// prep: keb/qe tables + bf16 casts + embed_w pad + q/k/v projections (fused)
__global__ __launch_bounds__(256, 2) void prep_kernel(
    const float* __restrict__ qfeat, const float* __restrict__ kfeat,
    const float* __restrict__ kpos, const float* __restrict__ qpos,
    const float* __restrict__ ipw, const float* __restrict__ ipb,
    const float* __restrict__ pos_w1, const float* __restrict__ pos_w2,
    const float* __restrict__ embed_w, float* __restrict__ ws)
{
  __shared__ float x[8 * 256];
  int bid = blockIdx.x, t = threadIdx.x;

  if (bid < 50) {
    int r = bid * 4 + (t >> 6);
    int u = t & 63;
    float p0 = kpos[r * 2 + 0], p1 = kpos[r * 2 + 1];
    __bf16* keb = (__bf16*)(ws + WS_KEB);
    bf16x4 o;
#pragma unroll
    for (int j = 0; j < 4; j++) {
      int col = u * 4 + j;
      int c = col >> 7, i = (col & 127) >> 1;
      float p = c ? p1 : p0;
      float inv = exp2f((float)i * (-13.287712379549449f / 64.0f));
      float v = p * inv;
      o[j] = (__bf16)((col & 1) ? __cosf(v) : __sinf(v));
    }
    *(bf16x4*)(keb + r * 264 + u * 4) = o;
  } else if (bid < 114) {
    int idx = (bid - 50) * 1024 + t * 4;
    float4 v = *(const float4*)(pos_w1 + idx);
    bf16x4 o; o[0] = (__bf16)v.x; o[1] = (__bf16)v.y; o[2] = (__bf16)v.z; o[3] = (__bf16)v.w;
    *(bf16x4*)((__bf16*)(ws + WS_W1B) + idx) = o;
  } else if (bid == 114) {
    __bf16* w2pb = (__bf16*)(ws + WS_W2PB);
    for (int i = 0; i < 16; i++) {
      int idx = t * 16 + i;
      w2pb[idx] = (idx < 2048) ? (__bf16)pos_w2[idx] : (__bf16)0.0f;
    }
  } else if (bid < 147) {
    int r0 = (bid - 115) * 8;
    for (int rr = 0; rr < 8; rr++) {
      int r = r0 + rr;
      for (int j = t; j < 260; j += 256)
        ws[WS_EWP + r * 260 + j] = (j < 258) ? embed_w[r * 258 + j] : 0.0f;
    }
  } else if (bid < 547) {
    int r0 = (bid - 147) * 8;
    for (int i = t; i < 2048; i += 256) x[i] = qfeat[(unsigned)r0 * 256u + i];
    __syncthreads();
    float acc[8]; float bq = ipb[t];
#pragma unroll
    for (int rr = 0; rr < 8; rr++) acc[rr] = bq;
    const float* wrow = ipw + (unsigned)t * 256u;
    for (int j = 0; j < 256; j += 4) {
      float4 w4 = *(const float4*)(wrow + j);
#pragma unroll
      for (int rr = 0; rr < 8; rr++) {
        float4 x4 = *(const float4*)(x + rr * 256 + j);
        acc[rr] = fmaf(x4.x, w4.x, fmaf(x4.y, w4.y, fmaf(x4.z, w4.z, fmaf(x4.w, w4.w, acc[rr]))));
      }
    }
    __bf16* qhb = (__bf16*)(ws + WS_QHB);
#pragma unroll
    for (int rr = 0; rr < 8; rr++)
      qhb[(unsigned)(r0 + rr) * 256u + t] = (__bf16)(acc[rr] * 0.17677669529663687f);
  } else if (bid < 579) {
    int b2 = bid - 547; int n = b2 >> 4, tile = b2 & 15;
    int r0l = tile * 7; int cnt = 100 - r0l; if (cnt > 7) cnt = 7; if (cnt <= 0) return;
    int r0 = n * 100 + r0l;
    for (int i = t; i < cnt * 256; i += 256) x[i] = kfeat[(unsigned)r0 * 256u + i];
    __syncthreads();
    float ak[7], av[7]; float bk = ipb[256 + t], bv = ipb[512 + t];
#pragma unroll
    for (int rr = 0; rr < 7; rr++) { ak[rr] = bk; av[rr] = bv; }
    const float* wkr = ipw + (unsigned)(256 + t) * 256u;
    const float* wvr = ipw + (unsigned)(512 + t) * 256u;
    for (int j = 0; j < 256; j += 4) {
      float4 wk4 = *(const float4*)(wkr + j);
      float4 wv4 = *(const float4*)(wvr + j);
#pragma unroll
      for (int rr = 0; rr < 7; rr++) {
        float4 x4 = *(const float4*)(x + rr * 256 + j);
        ak[rr] = fmaf(x4.x, wk4.x, fmaf(x4.y, wk4.y, fmaf(x4.z, wk4.z, fmaf(x4.w, wk4.w, ak[rr]))));
        av[rr] = fmaf(x4.x, wv4.x, fmaf(x4.y, wv4.y, fmaf(x4.z, wv4.z, fmaf(x4.w, wv4.w, av[rr]))));
      }
    }
    for (int rr = 0; rr < 7; rr++) {
      if (rr < cnt) {
        ws[WS_KH + (unsigned)(r0 + rr) * 256u + t] = ak[rr];
        ws[WS_VH + (unsigned)(r0 + rr) * 256u + t] = av[rr];
      }
    }
  } else {
    // qe table: rows 0..3199, 4 rows per block
    int r = (bid - 579) * 4 + (t >> 6);
    int u = t & 63;
    float p0 = qpos[r * 2 + 0], p1 = qpos[r * 2 + 1];
    __bf16* qeb = (__bf16*)(ws + WS_QEB);
    bf16x4 o;
#pragma unroll
    for (int j = 0; j < 4; j++) {
      int col = u * 4 + j;
      int c = col >> 7, i = (col & 127) >> 1;
      float p = c ? p1 : p0;
      float inv = exp2f((float)i * (-13.287712379549449f / 64.0f));
      float v = p * inv;
      o[j] = (__bf16)((col & 1) ? __cosf(v) : __sinf(v));
    }
    *(bf16x4*)(qeb + r * 256 + u * 4) = o;
  }
}

// ---------------------------------------------------------------------------
// bias kernel v11: v10 math, barrier-drain FIXED. Cross-round evidence
// (r4/r6/r7: per-tile cost sticky at 5-6.7us regardless of wave structure,
// MfmaUtil x dur == 18us MFMA floor always): the stall is the compiler's
// `s_waitcnt vmcnt(0)` before every s_barrier, draining per-tile biasb
// global STORES (ack ~500-900cy) + per-tile w2f loads + qe prefetch, 10x
// per block. Fix: (1) bias results accumulate in REGISTERS (1 ull/tile,
// statically indexed via fully-unrolled phase loop — rule #20), stored once
// at kernel end -> no store drains mid-kernel. (2) ONE barrier per tile via
// double-buffered qe AND hid: phase tt = { issue qe loads(tt+1) | GEMM2(tt-1)
// on wq==0 | GEMM1(tt) | hid->LDS | land qe(tt+1) } -> barrier. GEMM2 of a
// tile rides in the NEXT phase, overlapped with other waves' GEMM1.
// 8 waves (wc=w&3 c-quadrant, wq=w>>2 q-half), launch_bounds(512,2).
// LDS: qe 2x32K + hid 2x32K + keb 512 = 131584 B (1 block/CU).
__global__ __launch_bounds__(512, 2) void bias_kernel(
    const float* __restrict__ pos_b1, const float* __restrict__ pos_b2,
    float* __restrict__ ws)
{
  __shared__ __align__(16) char qe_smem[2][32768];    // [64 q][512B] swizzled
  __shared__ __align__(16) char hid_smem[2][32768];   // [64 q][512B] swizzled
  __shared__ __align__(16) __bf16 keb_s[256];

  int bid = blockIdx.x;           // 0..999 = nk(200) x qgroup(5)
  int nk = bid / 5, g = bid - nk * 5;
  int n = nk / 100, k = nk - n * 100;
  int qbase = n * 1600 + g * 320;
  int t = threadIdx.x;
  int lane = t & 63, w = t >> 6;        // w 0..7
  int wc = w & 3, wq = w >> 2;          // c-quadrant, q-half
  int l15 = lane & 15, quad = lane >> 4;

  const __bf16* keb = (const __bf16*)(ws + WS_KEB) + (unsigned)nk * 264u;
  const __bf16* qeb = (const __bf16*)(ws + WS_QEB);
  const __bf16* w1b = (const __bf16*)(ws + WS_W1B);
  const __bf16* w2pb = (const __bf16*)(ws + WS_W2PB);
  __bf16* biasb = (__bf16*)(ws + WS_BIASB);

  if (t < 32) *(bf16x8*)(keb_s + t * 8) = *(const bf16x8*)(keb + t * 8);

  // qe staging pattern (r7-validated): 512 thr, 64B each; sr=row, ssub=chunk.
  int sr = t >> 3, ssub = t & 7, sswz = (sr & 7) << 4;
  {
    const __bf16* src = qeb + (unsigned)(qbase + sr) * 256u + ssub * 32;
    char* dst = qe_smem[0] + sr * 512;
#pragma unroll
    for (int u = 0; u < 4; u++) {
      bf16x8 v = *(const bf16x8*)(src + u * 8);
      *(bf16x8*)(dst + ((ssub * 64 + u * 16) ^ sswz)) = v;
    }
  }

  // per-lane constant addressing (r4..r7-validated swizzle pattern)
  int xm = (l15 & 7) << 4;
  int colx[8];
#pragma unroll
  for (int kc = 0; kc < 8; kc++) colx[kc] = ((kc * 64 + quad * 16) ^ xm);
  const __bf16* w1p = w1b + (unsigned)(wc * 64 + l15) * 256u + quad * 8;

  float b1a[4][4];
#pragma unroll
  for (int ct = 0; ct < 4; ct++)
#pragma unroll
    for (int r = 0; r < 4; r++) b1a[ct][r] = pos_b1[wc * 64 + ct * 16 + quad * 4 + r];
  float b2v[4];
#pragma unroll
  for (int r = 0; r < 4; r++) b2v[r] = pos_b2[(quad * 4 + r) & 7];

  f32x4 zero4; zero4[0] = 0.f; zero4[1] = 0.f; zero4[2] = 0.f; zero4[3] = 0.f;

  __syncthreads();   // keb_s + qe tile0 ready

  // rotate W1 -> af regs, ONCE per block (key-side fold, r4-validated)
  bf16x8 af[8][4];
#pragma unroll
  for (int kc = 0; kc < 8; kc++) {
    bf16x8 ke8 = *(const bf16x8*)(keb_s + kc * 32 + quad * 8);
#pragma unroll
    for (int ct = 0; ct < 4; ct++) {
      bf16x8 w8 = *(const bf16x8*)(w1p + ct * 4096 + kc * 32);
      bf16x8 a;
#pragma unroll
      for (int p2 = 0; p2 < 4; p2++) {
        float we = (float)w8[2 * p2], wo = (float)w8[2 * p2 + 1];
        float sk = (float)ke8[2 * p2], ck = (float)ke8[2 * p2 + 1];
        a[2 * p2]     = (__bf16)fmaf(wo, sk, -(we * ck));
        a[2 * p2 + 1] = (__bf16)fmaf(we, sk, wo * ck);
      }
      af[kc][ct] = a;
    }
  }

  unsigned long long bias_pk[5];   // statically indexed (full unroll below)

  // GEMM2 for tile tg, reading hid_smem[tg&1] -> bias_pk[tg]. wq==0 only.
  auto gemm2 = [&](int tg) {
    bf16x8 w2f[8];
#pragma unroll
    for (int kc = 0; kc < 8; kc++)
      w2f[kc] = *(const bf16x8*)(w2pb + (unsigned)l15 * 256u + kc * 32 + quad * 8);
    int row = wc * 16 + l15;
    const char* hbase = hid_smem[tg & 1] + row * 512;
    int hxm = (l15 & 7) << 4;
    f32x4 acc2 = zero4;
#pragma unroll
    for (int kc = 0; kc < 8; kc++) {
      bf16x8 hf = *(const bf16x8*)(hbase + ((kc * 64 + quad * 16) ^ hxm));
      acc2 = __builtin_amdgcn_mfma_f32_16x16x32_bf16(w2f[kc], hf, acc2, 0, 0, 0);
    }
    unsigned lo = packbf(acc2[0] + b2v[0], acc2[1] + b2v[1]);
    unsigned hi = packbf(acc2[2] + b2v[2], acc2[3] + b2v[3]);
    return (unsigned long long)lo | ((unsigned long long)hi << 32);
  };

#pragma unroll
  for (int tt = 0; tt < 5; tt++) {
    // issue next tile's qe global loads (land at end of this phase)
    bf16x8 qv[4];
    if (tt < 4) {
      const __bf16* src = qeb + (unsigned)(qbase + (tt + 1) * 64 + sr) * 256u + ssub * 32;
#pragma unroll
      for (int u = 0; u < 4; u++) qv[u] = *(const bf16x8*)(src + u * 8);
    }

    // deferred GEMM2 for previous tile (wq==0 waves; others head into GEMM1)
    if (tt > 0 && wq == 0) bias_pk[tt - 1] = gemm2(tt - 1);

    // GEMM1: wave (wc,wq) -> c [64wc,+64) x q [32wq,+32). 64 MFMA.
    f32x4 acc[4][2];
#pragma unroll
    for (int ct = 0; ct < 4; ct++)
#pragma unroll
      for (int nt = 0; nt < 2; nt++) acc[ct][nt] = zero4;

#pragma unroll
    for (int kc = 0; kc < 8; kc++) {
#pragma unroll
      for (int nt = 0; nt < 2; nt++) {
        int row = wq * 32 + nt * 16 + l15;
        bf16x8 qf = *(const bf16x8*)(qe_smem[tt & 1] + row * 512 + colx[kc]);
        acc[0][nt] = __builtin_amdgcn_mfma_f32_16x16x32_bf16(af[kc][0], qf, acc[0][nt], 0, 0, 0);
        acc[1][nt] = __builtin_amdgcn_mfma_f32_16x16x32_bf16(af[kc][1], qf, acc[1][nt], 0, 0, 0);
        acc[2][nt] = __builtin_amdgcn_mfma_f32_16x16x32_bf16(af[kc][2], qf, acc[2][nt], 0, 0, 0);
        acc[3][nt] = __builtin_amdgcn_mfma_f32_16x16x32_bf16(af[kc][3], qf, acc[3][nt], 0, 0, 0);
      }
    }

    // hid = relu(D1+b1) -> bf16 -> hid_smem[tt&1] (8B writes, q-row swizzle)
#pragma unroll
    for (int ct = 0; ct < 4; ct++) {
#pragma unroll
      for (int nt = 0; nt < 2; nt++) {
        int q = wq * 32 + nt * 16 + l15;
        unsigned lo = packbf(fmaxf(acc[ct][nt][0] + b1a[ct][0], 0.f),
                             fmaxf(acc[ct][nt][1] + b1a[ct][1], 0.f));
        unsigned hi = packbf(fmaxf(acc[ct][nt][2] + b1a[ct][2], 0.f),
                             fmaxf(acc[ct][nt][3] + b1a[ct][3], 0.f));
        int cbyte = wc * 128 + ct * 32 + quad * 8;
        char* p = hid_smem[tt & 1] + q * 512 + (cbyte ^ ((q & 7) << 4));
        *(unsigned long long*)p = (unsigned long long)lo | ((unsigned long long)hi << 32);
      }
    }

    // land prefetched qe into the other buffer (reads of it start next phase)
    if (tt < 4) {
      char* dst = qe_smem[(tt + 1) & 1] + sr * 512;
#pragma unroll
      for (int u = 0; u < 4; u++)
        *(bf16x8*)(dst + ((ssub * 64 + u * 16) ^ sswz)) = qv[u];
    }

    __syncthreads();   // ONE barrier/tile; no stores outstanding
  }

  // final deferred GEMM2 + the only global stores of the kernel
  if (wq == 0) {
    bias_pk[4] = gemm2(4);
    if (quad < 2) {
      int row = wc * 16 + l15;
#pragma unroll
      for (int tg = 0; tg < 5; tg++) {
        int qg = qbase + tg * 64 + row;
        *(unsigned long long*)(biasb + (unsigned)qg * 896u + (unsigned)k * 8u + quad * 4)
            = bias_pk[tg];
      }
    }
  }
}

// ---------------------------------------------------------------------------
// attn kernel: per block = 4 queries. scores -> softmax -> ctx/aw -> out_proj
// -> cat_pos -> embed. 256 threads.
__global__ __launch_bounds__(256, 4) void attn_kernel(
    const float* __restrict__ qfeat, const float* __restrict__ qpos,
    const float* __restrict__ kpos,
    const float* __restrict__ out_w, const float* __restrict__ out_b,
    const float* __restrict__ embed_b, const float* __restrict__ ptw,
    const float* __restrict__ ws, float* __restrict__ out)
{
  __shared__ float qh_s[4 * 8 * 36];
  __shared__ float attn_s[4 * 8 * 116];
  __shared__ float ctx_s[4 * 264];
  __shared__ float cat_s[4 * 264];
  __shared__ float aw_s[4 * 104];

  int bid = blockIdx.x;
  int qg0 = bid * 4;
  int n = bid / 400;
  int t = threadIdx.x;

  const __bf16* qhb = (const __bf16*)(ws + WS_QHB);
  const __bf16* biasb = (const __bf16*)(ws + WS_BIASB);
  const float* kh = ws + WS_KH;
  const float* vh = ws + WS_VH;
  const float* ewp = ws + WS_EWP;

  for (int i = t; i < 1024; i += 256) {
    int q = i >> 8, c = i & 255;
    qh_s[(q * 8 + (c >> 5)) * 36 + (c & 31)] = (float)qhb[(unsigned)(qg0 + q) * 256u + c];
  }
  __syncthreads();

  for (int i = 0; i < 4; i++) {
    int p = t + i * 256;
    if (p < 800) {
      int k = p >> 3, h = p & 7;
      const float4* kf = (const float4*)(kh + (unsigned)(n * 100 + k) * 256u + h * 32);
      float4 kv[8];
#pragma unroll
      for (int dd = 0; dd < 8; dd++) kv[dd] = kf[dd];
#pragma unroll
      for (int q = 0; q < 4; q++) {
        const float4* qf = (const float4*)(qh_s + (q * 8 + h) * 36);
        float s = (float)biasb[((unsigned)(qg0 + q) * 112u + k) * 8u + h];
#pragma unroll
        for (int dd = 0; dd < 8; dd++) {
          float4 qv = qf[dd];
          s += kv[dd].x * qv.x + kv[dd].y * qv.y + kv[dd].z * qv.z + kv[dd].w * qv.w;
        }
        attn_s[(q * 8 + h) * 116 + k] = s;
      }
    }
  }
  __syncthreads();

  {
    int q = t >> 6, h = (t >> 3) & 7, j = t & 7;
    float* row = attn_s + (q * 8 + h) * 116;
    float mx = -1e30f;
    for (int k = j; k < 100; k += 8) mx = fmaxf(mx, row[k]);
    mx = fmaxf(mx, __shfl_xor(mx, 1, 8));
    mx = fmaxf(mx, __shfl_xor(mx, 2, 8));
    mx = fmaxf(mx, __shfl_xor(mx, 4, 8));
    float sum = 0.f;
    for (int k = j; k < 100; k += 8) { float e = __expf(row[k] - mx); row[k] = e; sum += e; }
    sum += __shfl_xor(sum, 1, 8);
    sum += __shfl_xor(sum, 2, 8);
    sum += __shfl_xor(sum, 4, 8);
    float inv = 1.0f / sum;
    for (int k = j; k < 100; k += 8) row[k] *= inv;
  }
  __syncthreads();

  for (int p = t; p < 416; p += 256) {
    int q = p / 104, k = p % 104;
    if (k < 100) {
      float s = 0.f;
#pragma unroll
      for (int h = 0; h < 8; h++) s += attn_s[(q * 8 + h) * 116 + k];
      aw_s[q * 104 + k] = s * 0.125f;
    }
  }
  {
    int c = t, h = c >> 5;
    float a0 = 0.f, a1 = 0.f, a2 = 0.f, a3 = 0.f;
    const float* vp = vh + (unsigned)(n * 100) * 256u + c;
    const float* r0 = attn_s + (0 * 8 + h) * 116;
    const float* r1 = attn_s + (1 * 8 + h) * 116;
    const float* r2 = attn_s + (2 * 8 + h) * 116;
    const float* r3 = attn_s + (3 * 8 + h) * 116;
#pragma unroll 4
    for (int k = 0; k < 100; k++) {
      float vv = vp[(unsigned)k * 256u];
      a0 = fmaf(r0[k], vv, a0);
      a1 = fmaf(r1[k], vv, a1);
      a2 = fmaf(r2[k], vv, a2);
      a3 = fmaf(r3[k], vv, a3);
    }
    ctx_s[0 * 264 + c] = a0; ctx_s[1 * 264 + c] = a1;
    ctx_s[2 * 264 + c] = a2; ctx_s[3 * 264 + c] = a3;
  }
  __syncthreads();

  if (t < 8) {
    int q = t >> 1, cd = t & 1;
    float qp = qpos[(qg0 + q) * 2 + cd];
    float s = 0.f;
    for (int k = 0; k < 100; k++)
      s = fmaf(aw_s[q * 104 + k], kpos[(n * 100 + k) * 2 + cd] - qp, s);
    float so = __shfl_xor(s, 1, 2);
    if (cd == 0) cat_s[q * 264 + 256] = ptw[0] * s + ptw[1] * so;
    else         cat_s[q * 264 + 257] = ptw[2] * so + ptw[3] * s;
  }

  {
    int c = t, lane = t & 63;
    float ob = out_b[c];
    float acc0 = ob, acc1 = ob, acc2 = ob, acc3 = ob;
    const float* wr = out_w + (unsigned)c * 256u;
    for (int ch = 0; ch < 4; ch++) {
      float v0 = ctx_s[0 * 264 + ch * 64 + lane];
      float v1 = ctx_s[1 * 264 + ch * 64 + lane];
      float v2 = ctx_s[2 * 264 + ch * 64 + lane];
      float v3 = ctx_s[3 * 264 + ch * 64 + lane];
      const float* wp = wr + ch * 64;
#pragma unroll 4
      for (int j4 = 0; j4 < 16; j4++) {
        float4 w4 = *(const float4*)(wp + j4 * 4);
        int jb = j4 * 4;
        acc0 = fmaf(rdlane(v0, jb + 0), w4.x, acc0);
        acc1 = fmaf(rdlane(v1, jb + 0), w4.x, acc1);
        acc2 = fmaf(rdlane(v2, jb + 0), w4.x, acc2);
        acc3 = fmaf(rdlane(v3, jb + 0), w4.x, acc3);
        acc0 = fmaf(rdlane(v0, jb + 1), w4.y, acc0);
        acc1 = fmaf(rdlane(v1, jb + 1), w4.y, acc1);
        acc2 = fmaf(rdlane(v2, jb + 1), w4.y, acc2);
        acc3 = fmaf(rdlane(v3, jb + 1), w4.y, acc3);
        acc0 = fmaf(rdlane(v0, jb + 2), w4.z, acc0);
        acc1 = fmaf(rdlane(v1, jb + 2), w4.z, acc1);
        acc2 = fmaf(rdlane(v2, jb + 2), w4.z, acc2);
        acc3 = fmaf(rdlane(v3, jb + 2), w4.z, acc3);
        acc0 = fmaf(rdlane(v0, jb + 3), w4.w, acc0);
        acc1 = fmaf(rdlane(v1, jb + 3), w4.w, acc1);
        acc2 = fmaf(rdlane(v2, jb + 3), w4.w, acc2);
        acc3 = fmaf(rdlane(v3, jb + 3), w4.w, acc3);
      }
    }
    cat_s[0 * 264 + c] = fmaxf(qfeat[(unsigned)(qg0 + 0) * 256u + c] + acc0, 0.f);
    cat_s[1 * 264 + c] = fmaxf(qfeat[(unsigned)(qg0 + 1) * 256u + c] + acc1, 0.f);
    cat_s[2 * 264 + c] = fmaxf(qfeat[(unsigned)(qg0 + 2) * 256u + c] + acc2, 0.f);
    cat_s[3 * 264 + c] = fmaxf(qfeat[(unsigned)(qg0 + 3) * 256u + c] + acc3, 0.f);
  }
  __syncthreads();

  {
    int c = t, lane = t & 63;
    float eb = embed_b[c];
    float acc0 = eb, acc1 = eb, acc2 = eb, acc3 = eb;
    const float* er = ewp + (unsigned)c * 260u;
    for (int ch = 0; ch < 4; ch++) {
      float v0 = cat_s[0 * 264 + ch * 64 + lane];
      float v1 = cat_s[1 * 264 + ch * 64 + lane];
      float v2 = cat_s[2 * 264 + ch * 64 + lane];
      float v3 = cat_s[3 * 264 + ch * 64 + lane];
      const float* wp = er + ch * 64;
#pragma unroll 4
      for (int j4 = 0; j4 < 16; j4++) {
        float4 w4 = *(const float4*)(wp + j4 * 4);
        int jb = j4 * 4;
        acc0 = fmaf(rdlane(v0, jb + 0), w4.x, acc0);
        acc1 = fmaf(rdlane(v1, jb + 0), w4.x, acc1);
        acc2 = fmaf(rdlane(v2, jb + 0), w4.x, acc2);
        acc3 = fmaf(rdlane(v3, jb + 0), w4.x, acc3);
        acc0 = fmaf(rdlane(v0, jb + 1), w4.y, acc0);
        acc1 = fmaf(rdlane(v1, jb + 1), w4.y, acc1);
        acc2 = fmaf(rdlane(v2, jb + 1), w4.y, acc2);
        acc3 = fmaf(rdlane(v3, jb + 1), w4.y, acc3);
        acc0 = fmaf(rdlane(v0, jb + 2), w4.z, acc0);
        acc1 = fmaf(rdlane(v1, jb + 2), w4.z, acc1);
        acc2 = fmaf(rdlane(v2, jb + 2), w4.z, acc2);
        acc3 = fmaf(rdlane(v3, jb + 2), w4.z, acc3);
        acc0 = fmaf(rdlane(v0, jb + 3), w4.w, acc0);
        acc1 = fmaf(rdlane(v1, jb + 3), w4.w, acc1);
        acc2 = fmaf(rdlane(v2, jb + 3), w4.w, acc2);
        acc3 = fmaf(rdlane(v3, jb + 3), w4.w, acc3);
      }
    }
    float4 wt = *(const float4*)(er + 256);
    acc0 += cat_s[0 * 264 + 256] * wt.x + cat_s[0 * 264 + 257] * wt.y;
    acc1 += cat_s[1 * 264 + 256] * wt.x + cat_s[1 * 264 + 257] * wt.y;
    acc2 += cat_s[2 * 264 + 256] * wt.x + cat_s[2 * 264 + 257] * wt.y;
    acc3 += cat_s[3 * 264 + 256] * wt.x + cat_s[3 * 264 + 257] * wt.y;
    out[(unsigned)(qg0 + 0) * 256u + c] = fmaxf(acc0, 0.f);
    out[(unsigned)(qg0 + 1) * 256u + c] = fmaxf(acc1, 0.f);
    out[(unsigned)(qg0 + 2) * 256u + c] = fmaxf(acc2, 0.f);
    out[(unsigned)(qg0 + 3) * 256u + c] = fmaxf(acc3, 0.f);
  }
}

// ---------------------------------------------------------------------------
extern "C" void kernel_launch(void* const* d_in, const int* in_sizes, int n_in,
                              void* d_out, int out_size, void* d_ws, size_t ws_size,
                              hipStream_t stream)
{
  const float* query_feature  = (const float*)d_in[0];
  const float* query_position = (const float*)d_in[1];
  const float* key_feature    = (const float*)d_in[2];
  const float* key_position   = (const float*)d_in[3];
  const float* in_proj_w      = (const float*)d_in[4];
  const float* in_proj_b      = (const float*)d_in[5];
  const float* out_proj_w     = (const float*)d_in[6];
  const float* out_proj_b     = (const float*)d_in[7];
  const float* pos_w1         = (const float*)d_in[8];
  const float* pos_b1         = (const float*)d_in[9];
  const float* pos_w2         = (const float*)d_in[10];
  const float* pos_b2         = (const float*)d_in[11];
  const float* pos_trans_w    = (const float*)d_in[12];
  const float* embed_w        = (const float*)d_in[13];
  const float* embed_b        = (const float*)d_in[14];
  float* ws  = (float*)d_ws;
  float* out = (float*)d_out;

  hipLaunchKernelGGL(prep_kernel, dim3(1379), dim3(256), 0, stream,
                     query_feature, key_feature, key_position, query_position,
                     in_proj_w, in_proj_b, pos_w1, pos_w2, embed_w, ws);
  hipLaunchKernelGGL(bias_kernel, dim3(1000), dim3(512), 0, stream,
                     pos_b1, pos_b2, ws);
  hipLaunchKernelGGL(attn_kernel, dim3(800), dim3(256), 0, stream,
                     query_feature, query_position, key_position,
                     out_proj_w, out_proj_b, embed_b, pos_trans_w,
                     ws, out);
}